// Round 13
// baseline (1005.028 us; speedup 1.0000x reference)
//
#include <hip/hip_runtime.h>

#define DEV __device__ __forceinline__

typedef __bf16 bf16x8 __attribute__((ext_vector_type(8)));
typedef float  f32x4  __attribute__((ext_vector_type(4)));
typedef unsigned short u16x8 __attribute__((ext_vector_type(8)));
typedef unsigned short u16x4 __attribute__((ext_vector_type(4)));

DEV float b2f(unsigned short u) {
    unsigned int t = ((unsigned int)u) << 16;
    return __uint_as_float(t);
}
DEV unsigned short f2b(float f) {
    unsigned int u = __float_as_uint(f);
    unsigned int r = (u + 0x7FFFu + ((u >> 16) & 1u)) >> 16;
    return (unsigned short)r;
}

DEV void gload_lds16(const unsigned short* g, void* l) {
    __builtin_amdgcn_global_load_lds(
        (const __attribute__((address_space(1))) void*)(const void*)g,
        (__attribute__((address_space(3))) void*)l, 16, 0, 0);
}

// dest window-row -> source/dest token index (roll by SS=3, window 7x7, 56x56, 64 win/batch)
DEV size_t win_to_tok(int row) {
    int w = row / 49, t = row - w * 49;
    int b  = w >> 6, widx = w & 63;
    int wi = widx >> 3, wj = widx & 7;
    int ti = t / 7, tj = t - ti * 7;
    int hh = wi * 7 + ti + 3; if (hh >= 56) hh -= 56;
    int ww = wj * 7 + tj + 3; if (ww >= 56) ww -= 56;
    return (size_t)b * 3136 + (size_t)hh * 56 + ww;
}

// ---------------- weight prep: fp32 [K][N] -> bf16 [N][K] ----------------
__global__ void wprep(const float* __restrict__ src, unsigned short* __restrict__ dst,
                      int K, int N) {
    int idx = blockIdx.x * 256 + threadIdx.x;
    if (idx >= K * N) return;
    int k = idx / N, n = idx - k * N;
    dst[(size_t)n * K + k] = f2b(src[idx]);
}

// ---------------- bias table: [cls 4][h 12][row 64][col 64] fp32 ----------------
__global__ void btab_build(const int* __restrict__ rel_idx, const float* __restrict__ rpb,
                           float* __restrict__ tab) {
    int idx = blockIdx.x * 256 + threadIdx.x;
    if (idx >= 4 * 12 * 64 * 64) return;
    int col = idx & 63, row = (idx >> 6) & 63;
    int h = (idx >> 12) % 12, cls = idx / (12 * 4096);
    float v;
    if (row >= 49 || col >= 49) {
        v = -10000.f;
    } else {
        v = rpb[rel_idx[row * 49 + col] * 12 + h];
        int ti = row / 7, tj = row - (row / 7) * 7;
        int si = col / 7, sj = col - (col / 7) * 7;
        int lq = ((cls & 2) ? (ti < 4 ? 1 : 2) : 0) * 3 + ((cls & 1) ? (tj < 4 ? 1 : 2) : 0);
        int lk = ((cls & 2) ? (si < 4 ? 1 : 2) : 0) * 3 + ((cls & 1) ? (sj < 4 ? 1 : 2) : 0);
        if (lq != lk) v -= 100.f;
    }
    tab[idx] = v;
}

// ---------------- LayerNorm (+optional shifted-window gather), fp32 -> bf16 ----------------
template <int REMAP>
__global__ __launch_bounds__(256) void ln_kernel(const float* __restrict__ x,
                                                 const float* __restrict__ g,
                                                 const float* __restrict__ b,
                                                 unsigned short* __restrict__ out,
                                                 int rows) {
    int r = blockIdx.x * 4 + (threadIdx.x >> 6);
    int lane = threadIdx.x & 63;
    if (r >= rows) return;
    size_t src = REMAP ? win_to_tok(r) : (size_t)r;
    const float* xp = x + src * 384;
    float v[6];
    float s = 0.f;
#pragma unroll
    for (int i = 0; i < 6; ++i) { v[i] = xp[i * 64 + lane]; s += v[i]; }
#pragma unroll
    for (int off = 32; off; off >>= 1) s += __shfl_xor(s, off, 64);
    float mu = s * (1.f / 384.f);
    float q = 0.f;
#pragma unroll
    for (int i = 0; i < 6; ++i) { float d = v[i] - mu; q += d * d; }
#pragma unroll
    for (int off = 32; off; off >>= 1) q += __shfl_xor(q, off, 64);
    float inv = rsqrtf(q * (1.f / 384.f) + 1e-5f);
    unsigned short* op = out + (size_t)r * 384;
#pragma unroll
    for (int i = 0; i < 6; ++i) {
        int c = i * 64 + lane;
        op[c] = f2b((v[i] - mu) * inv * g[c] + b[c]);
    }
}

// ---------------- GEMM: single-barrier ring (NBUF >= DEPTH+2) ----------------
// One barrier per K-step. Proof of safety: stage at iter t writes slot (t+DEPTH)%NBUF,
// last read at iter t-2 (NBUF=DEPTH+2); barrier(t-1) orders after every wave's
// lgkmcnt(0)-retired t-2 reads. Counted vmcnt keeps DEPTH tiles in flight.
// Swapped-operand MFMA: lane&15 = C-row, (lane>>4)*4+r = C-col -> vectorized stores.
// MODE 0: out bf16 = C (QKV) | 1: resid+C+bias remap fp32 (proj) | 2: gelu (FFN1) | 3: resid+C+bias (FFN2)
template <int MODE, int NBUF, int DEPTH, int MINW>
__global__ __launch_bounds__(256, MINW) void gemm_kernel(const unsigned short* __restrict__ A,
                                                         const unsigned short* __restrict__ Bt,
                                                         int M, int N, int K,
                                                         const float* __restrict__ bias,
                                                         const float* __restrict__ resid,
                                                         unsigned short* __restrict__ outb,
                                                         float* __restrict__ outf) {
    static_assert(NBUF >= DEPTH + 2, "single-barrier ring needs NBUF >= DEPTH+2");
    __shared__ unsigned short As[NBUF][128 * 32];
    __shared__ unsigned short Bs[NBUF][128 * 32];
    const int tid = threadIdx.x;
    const int wid = tid >> 6, lane = tid & 63;
    const int ntile = N >> 7;

    int bid = blockIdx.x;
    int nwg = gridDim.x;
    int swb = ((nwg & 7) == 0) ? ((bid & 7) * (nwg >> 3) + (bid >> 3)) : bid;
    const int mt = swb / ntile, nt = swb - mt * ntile;
    const int wr = wid >> 1, wc = wid & 1;

    f32x4 acc[4][4] = {};

    const int rA   = lane >> 2;
    const int kofs = (((lane & 3) ^ ((lane >> 3) & 3)) << 3);
    const unsigned short* Abase = A  + (size_t)(mt * 128) * K;
    const unsigned short* Bbase = Bt + (size_t)(nt * 128) * K;

    auto stage = [&](int buf, int k0) {
#pragma unroll
        for (int j = 0; j < 2; ++j) {
            int c = wid * 2 + j;
            gload_lds16(Abase + (size_t)(c * 16 + rA) * K + k0 + kofs, &As[buf][c * 512]);
            gload_lds16(Bbase + (size_t)(c * 16 + rA) * K + k0 + kofs, &Bs[buf][c * 512]);
        }
    };

    const int sr  = ((lane & 15) >> 1) & 3;
    const int cbA = (((lane >> 4) ^ sr) << 3);
    const int rowA = wr * 64 + (lane & 15);
    const int rowB = wc * 64 + (lane & 15);

    const int nk = K >> 5;
    stage(0, 0);
    if (DEPTH >= 2 && nk > 1) stage(1, 32);

    for (int t = 0; t < nk; ++t) {
        const int cur = t % NBUF;
        if (t + DEPTH < nk) {
            stage((t + DEPTH) % NBUF, (t + DEPTH) << 5);
            if constexpr (DEPTH == 1) {
                asm volatile("s_waitcnt vmcnt(4)" ::: "memory");
            } else {
                asm volatile("s_waitcnt vmcnt(8)" ::: "memory");
            }
        } else if (DEPTH >= 2 && t + 1 < nk) {
            asm volatile("s_waitcnt vmcnt(4)" ::: "memory");
        } else {
            asm volatile("s_waitcnt vmcnt(0)" ::: "memory");
        }
        __builtin_amdgcn_s_barrier();   // tile t resident; also releases slot for next stage

        bf16x8 a[4], b[4];
#pragma unroll
        for (int m = 0; m < 4; ++m)
            a[m] = *(const bf16x8*)&As[cur][(rowA + m * 16) * 32 + cbA];
#pragma unroll
        for (int n = 0; n < 4; ++n)
            b[n] = *(const bf16x8*)&Bs[cur][(rowB + n * 16) * 32 + cbA];
#pragma unroll
        for (int m = 0; m < 4; ++m)
#pragma unroll
            for (int n = 0; n < 4; ++n)
                acc[m][n] = __builtin_amdgcn_mfma_f32_16x16x32_bf16(b[n], a[m], acc[m][n], 0, 0, 0);

        asm volatile("s_waitcnt lgkmcnt(0)" ::: "memory");   // my reads retired (before next barrier)
    }

    const int row0 = mt * 128 + wr * 64;
    const int col0 = nt * 128 + wc * 64;
    const int rl = lane & 15;
    const int cq = (lane >> 4) << 2;
#pragma unroll
    for (int m = 0; m < 4; ++m) {
        int row = row0 + m * 16 + rl;
        size_t tok = 0;
        if constexpr (MODE == 1) tok = win_to_tok(row);
#pragma unroll
        for (int n = 0; n < 4; ++n) {
            int col = col0 + n * 16 + cq;
            f32x4 v = acc[m][n];
            if constexpr (MODE == 0) {
                u16x4 pk;
#pragma unroll
                for (int r = 0; r < 4; ++r) pk[r] = f2b(v[r]);
                *(u16x4*)&outb[(size_t)row * N + col] = pk;
            } else if constexpr (MODE == 1) {
                size_t o = tok * 384 + col;
                f32x4 rv = *(const f32x4*)&resid[o];
                f32x4 bb = *(const f32x4*)&bias[col];
                f32x4 ov = rv + v + bb;
                *(f32x4*)&outf[o] = ov;
            } else if constexpr (MODE == 2) {
                f32x4 bb = *(const f32x4*)&bias[col];
                u16x4 pk;
#pragma unroll
                for (int r = 0; r < 4; ++r) {
                    float t2 = v[r] + bb[r];
                    float y  = 0.7978845608028654f * (t2 + 0.044715f * t2 * t2 * t2);
                    float u  = __expf(-2.0f * fabsf(y));
                    float th = (1.f - u) / (1.f + u);
                    pk[r] = f2b(0.5f * t2 * (1.f + copysignf(th, t2)));
                }
                *(u16x4*)&outb[(size_t)row * N + col] = pk;
            } else {
                size_t o = (size_t)row * N + col;
                f32x4 rv = *(const f32x4*)&resid[o];
                f32x4 bb = *(const f32x4*)&bias[col];
                f32x4 ov = rv + v + bb;
                *(f32x4*)&outf[o] = ov;
            }
        }
    }
}

// ---------------- MFMA attention (swapped operands: lane-local softmax rows) ----------------
__global__ __launch_bounds__(256, 2) void attn_kernel(const unsigned short* __restrict__ QKV,
                                                      const float* __restrict__ Btab,
                                                      unsigned short* __restrict__ O) {
    __shared__ char lds[65536];
    char* Kl = lds;              // [hh][m 64][4 chunks x16B]
    char* Vl = lds + 16384;      // [hh][d 32][8 chunks x16B] (V^T)
    char* Pl = lds + 32768;      // [wave][row 64][8 chunks]

    const int w   = blockIdx.x;
    const int tid = threadIdx.x, wid = tid >> 6, lane = tid & 63;
    const int fr  = lane & 15, kq = lane >> 4;
    const size_t base = (size_t)w * 49 * 1152;
    const int widx = w & 63, wi = widx >> 3, wj = widx & 7;
    const int cls = ((wi == 7) ? 2 : 0) | ((wj == 7) ? 1 : 0);
    const float* tb = Btab + (size_t)cls * 12 * 4096;
    constexpr float SCL = 0.17677669529663687f;

    for (int R = 0; R < 3; ++R) {
        if (R) __syncthreads();
        {
            f32x4 z = {};
#pragma unroll
            for (int j = 0; j < 8; ++j) *(f32x4*)(lds + j * 4096 + tid * 16) = z;
        }
        __syncthreads();
        {
            int hh = tid >> 6, h = R * 4 + hh;
#pragma unroll
            for (int it = 0; it < 4; ++it) {
                int i = (tid & 63) + it * 64;
                if (i < 196) {
                    int m = i >> 2, c = i & 3;
                    u16x8 kv = *(const u16x8*)&QKV[base + (size_t)m * 1152 + 384 + h * 32 + c * 8];
                    *(u16x8*)(Kl + hh * 4096 + m * 64 + (c ^ ((m >> 1) & 3)) * 16) = kv;
                    u16x8 vv = *(const u16x8*)&QKV[base + (size_t)m * 1152 + 768 + h * 32 + c * 8];
#pragma unroll
                    for (int j = 0; j < 8; ++j) {
                        int d = c * 8 + j;
                        *(unsigned short*)(Vl + hh * 4096 + d * 128 +
                                           (((m >> 3) ^ (d & 7)) * 16) + (m & 7) * 2) = vv[j];
                    }
                }
            }
        }
        __syncthreads();

        const int h = R * 4 + wid;
        const float* tbh = tb + h * 4096;

        bf16x8 aq[4], bk[4];
#pragma unroll
        for (int mi = 0; mi < 4; ++mi) {
            int row = mi * 16 + fr; if (row > 48) row = 48;
            aq[mi] = *(const bf16x8*)&QKV[base + (size_t)row * 1152 + h * 32 + kq * 8];
        }
#pragma unroll
        for (int ni = 0; ni < 4; ++ni) {
            int rk = ni * 16 + fr;
            bk[ni] = *(const bf16x8*)(Kl + wid * 4096 + rk * 64 + ((kq ^ ((rk >> 1) & 3)) * 16));
        }
        f32x4 s[4][4] = {};
#pragma unroll
        for (int mi = 0; mi < 4; ++mi)
#pragma unroll
            for (int ni = 0; ni < 4; ++ni)
                s[mi][ni] = __builtin_amdgcn_mfma_f32_16x16x32_bf16(bk[ni], aq[mi], s[mi][ni], 0, 0, 0);

        float linv_[4];
#pragma unroll
        for (int mi = 0; mi < 4; ++mi) {
            int row = mi * 16 + fr;
            const float* tr = tbh + row * 64 + kq * 4;
            f32x4 sv[4];
            float mx = -1e30f;
#pragma unroll
            for (int ni = 0; ni < 4; ++ni) {
                f32x4 bb = *(const f32x4*)&tr[ni * 16];
                sv[ni] = s[mi][ni] * SCL + bb;
                mx = fmaxf(mx, fmaxf(fmaxf(sv[ni][0], sv[ni][1]), fmaxf(sv[ni][2], sv[ni][3])));
            }
            mx = fmaxf(mx, __shfl_xor(mx, 16, 64));
            mx = fmaxf(mx, __shfl_xor(mx, 32, 64));
            float sm = 0.f;
#pragma unroll
            for (int ni = 0; ni < 4; ++ni)
#pragma unroll
                for (int r = 0; r < 4; ++r) { sv[ni][r] = __expf(sv[ni][r] - mx); sm += sv[ni][r]; }
            sm += __shfl_xor(sm, 16, 64);
            sm += __shfl_xor(sm, 32, 64);
            linv_[mi] = 1.f / sm;
#pragma unroll
            for (int ni = 0; ni < 4; ++ni) {
                int colb = ni * 16 + kq * 4;
                int phys = (colb >> 3) ^ (row & 7);
                u16x4 pk;
#pragma unroll
                for (int r = 0; r < 4; ++r) pk[r] = f2b(sv[ni][r]);
                *(u16x4*)(Pl + wid * 8192 + row * 128 + phys * 16 + (colb & 7) * 2) = pk;
            }
        }
        asm volatile("s_waitcnt lgkmcnt(0)" ::: "memory");
        __builtin_amdgcn_sched_barrier(0);

        f32x4 oacc[4][2] = {};
#pragma unroll
        for (int sl = 0; sl < 2; ++sl) {
            bf16x8 bv[2];
#pragma unroll
            for (int ni = 0; ni < 2; ++ni) {
                int d = ni * 16 + fr;
                bv[ni] = *(const bf16x8*)(Vl + wid * 4096 + d * 128 + (((sl * 4 + kq) ^ (d & 7)) * 16));
            }
#pragma unroll
            for (int mi = 0; mi < 4; ++mi) {
                int row = mi * 16 + fr;
                bf16x8 ap = *(const bf16x8*)(Pl + wid * 8192 + row * 128 + (((sl * 4 + kq) ^ (row & 7)) * 16));
#pragma unroll
                for (int ni = 0; ni < 2; ++ni)
                    oacc[mi][ni] = __builtin_amdgcn_mfma_f32_16x16x32_bf16(bv[ni], ap, oacc[mi][ni], 0, 0, 0);
            }
        }

#pragma unroll
        for (int mi = 0; mi < 4; ++mi) {
            int row = mi * 16 + fr;
            if (row < 49) {
                float li = linv_[mi];
                unsigned short* op = O + (size_t)(w * 49 + row) * 384 + h * 32 + kq * 4;
#pragma unroll
                for (int ni = 0; ni < 2; ++ni) {
                    u16x4 pk;
#pragma unroll
                    for (int r = 0; r < 4; ++r) pk[r] = f2b(oacc[mi][ni][r] * li);
                    *(u16x4*)&op[ni * 16] = pk;
                }
            }
        }
    }
}

extern "C" void kernel_launch(void* const* d_in, const int* in_sizes, int n_in,
                              void* d_out, int out_size, void* d_ws, size_t ws_size,
                              hipStream_t stream) {
    const float* x     = (const float*)d_in[0];
    const int*   rel   = (const int*)  d_in[3];
    const float* rpb   = (const float*)d_in[4];
    const float* qkvw  = (const float*)d_in[5];
    const float* projw = (const float*)d_in[6];
    const float* projb = (const float*)d_in[7];
    const float* n1g   = (const float*)d_in[8];
    const float* n1b   = (const float*)d_in[9];
    const float* n2g   = (const float*)d_in[10];
    const float* n2b   = (const float*)d_in[11];
    const float* w1    = (const float*)d_in[12];
    const float* b1    = (const float*)d_in[13];
    const float* w2    = (const float*)d_in[14];
    const float* b2    = (const float*)d_in[15];
    float* out = (float*)d_out;

    const int T = in_sizes[0] / 384;   // 100352

    char* ws = (char*)d_ws;
    size_t off = 0;
    auto alloc = [&](size_t bytes) {
        char* p = ws + off;
        off += (bytes + 255) & ~(size_t)255;
        return p;
    };
    unsigned short* WqT  = (unsigned short*)alloc((size_t)1152 * 384 * 2);
    unsigned short* WpT  = (unsigned short*)alloc((size_t)384 * 384 * 2);
    unsigned short* W1T  = (unsigned short*)alloc((size_t)1536 * 384 * 2);
    unsigned short* W2T  = (unsigned short*)alloc((size_t)384 * 1536 * 2);
    float*          Btab = (float*)        alloc((size_t)4 * 12 * 4096 * 4);
    unsigned short* slotA = (unsigned short*)alloc((size_t)T * 384 * 2);   // X1 -> O -> X2
    unsigned short* slotB = (unsigned short*)alloc((size_t)T * 1536 * 2);  // QKV -> F

    unsigned short* X1  = slotA;
    unsigned short* O   = slotA;
    unsigned short* X2  = slotA;
    unsigned short* QKV = slotB;
    unsigned short* F   = slotB;
    float*          Hh  = out;

    wprep<<<dim3((1152 * 384 + 255) / 256), 256, 0, stream>>>(qkvw, WqT, 384, 1152);
    wprep<<<dim3((384 * 384 + 255) / 256),  256, 0, stream>>>(projw, WpT, 384, 384);
    wprep<<<dim3((384 * 1536 + 255) / 256), 256, 0, stream>>>(w1, W1T, 384, 1536);
    wprep<<<dim3((1536 * 384 + 255) / 256), 256, 0, stream>>>(w2, W2T, 1536, 384);
    btab_build<<<dim3((4 * 12 * 4096 + 255) / 256), 256, 0, stream>>>(rel, rpb, Btab);

    // LN1 + shifted-window gather -> X1 (bf16, window-token order)
    ln_kernel<1><<<dim3(T / 4), 256, 0, stream>>>(x, n1g, n1b, X1, T);
    // QKV projection (single-barrier ring: NBUF=3, DEPTH=1, 48 KB -> 3 blocks/CU)
    gemm_kernel<0, 3, 1, 4><<<dim3((T / 128) * (1152 / 128)), 256, 0, stream>>>(
        X1, WqT, T, 1152, 384, nullptr, nullptr, QKV, nullptr);
    // MFMA windowed attention
    attn_kernel<<<dim3(T / 49), 256, 0, stream>>>(QKV, Btab, O);
    // proj + bias + un-window/un-roll + residual -> Hh (= d_out, fp32)
    gemm_kernel<1, 3, 1, 4><<<dim3((T / 128) * (384 / 128)), 256, 0, stream>>>(
        O, WpT, T, 384, 384, projb, x, nullptr, Hh);
    // LN2 -> X2 (bf16, overwrites slotA)
    ln_kernel<0><<<dim3(T / 4), 256, 0, stream>>>(Hh, n2g, n2b, X2, T);
    // FFN1 + bias + GELU -> F (bf16, overwrites slotB)
    gemm_kernel<2, 3, 1, 4><<<dim3((T / 128) * (1536 / 128)), 256, 0, stream>>>(
        X2, W1T, T, 1536, 384, b1, nullptr, F, nullptr);
    // FFN2 + bias + residual -> out (fp32, in-place RMW; NBUF=4, DEPTH=2 for HBM-streamed A)
    gemm_kernel<3, 4, 2, 2><<<dim3((T / 128) * (384 / 128)), 256, 0, stream>>>(
        F, W2T, T, 384, 1536, b2, Hh, nullptr, out);
}

// Round 14
// 941.742 us; speedup vs baseline: 1.0672x; 1.0672x over previous
//
#include <hip/hip_runtime.h>

#define DEV __device__ __forceinline__

typedef __bf16 bf16x8 __attribute__((ext_vector_type(8)));
typedef float  f32x4  __attribute__((ext_vector_type(4)));
typedef unsigned short u16x8 __attribute__((ext_vector_type(8)));
typedef unsigned short u16x4 __attribute__((ext_vector_type(4)));

DEV float b2f(unsigned short u) {
    unsigned int t = ((unsigned int)u) << 16;
    return __uint_as_float(t);
}
DEV unsigned short f2b(float f) {
    unsigned int u = __float_as_uint(f);
    unsigned int r = (u + 0x7FFFu + ((u >> 16) & 1u)) >> 16;
    return (unsigned short)r;
}

DEV void gload_lds16(const unsigned short* g, void* l) {
    __builtin_amdgcn_global_load_lds(
        (const __attribute__((address_space(1))) void*)(const void*)g,
        (__attribute__((address_space(3))) void*)l, 16, 0, 0);
}

// dest window-row -> source/dest token index (roll by SS=3, window 7x7, 56x56, 64 win/batch)
DEV size_t win_to_tok(int row) {
    int w = row / 49, t = row - w * 49;
    int b  = w >> 6, widx = w & 63;
    int wi = widx >> 3, wj = widx & 7;
    int ti = t / 7, tj = t - ti * 7;
    int hh = wi * 7 + ti + 3; if (hh >= 56) hh -= 56;
    int ww = wj * 7 + tj + 3; if (ww >= 56) ww -= 56;
    return (size_t)b * 3136 + (size_t)hh * 56 + ww;
}

// ---------------- weight prep: fp32 [K][N] -> bf16 [N][K] ----------------
__global__ void wprep(const float* __restrict__ src, unsigned short* __restrict__ dst,
                      int K, int N) {
    int idx = blockIdx.x * 256 + threadIdx.x;
    if (idx >= K * N) return;
    int k = idx / N, n = idx - k * N;
    dst[(size_t)n * K + k] = f2b(src[idx]);
}

// ---------------- bias table: [cls 4][h 12][row 64][col 64] fp32 ----------------
__global__ void btab_build(const int* __restrict__ rel_idx, const float* __restrict__ rpb,
                           float* __restrict__ tab) {
    int idx = blockIdx.x * 256 + threadIdx.x;
    if (idx >= 4 * 12 * 64 * 64) return;
    int col = idx & 63, row = (idx >> 6) & 63;
    int h = (idx >> 12) % 12, cls = idx / (12 * 4096);
    float v;
    if (row >= 49 || col >= 49) {
        v = -10000.f;
    } else {
        v = rpb[rel_idx[row * 49 + col] * 12 + h];
        int ti = row / 7, tj = row - (row / 7) * 7;
        int si = col / 7, sj = col - (col / 7) * 7;
        int lq = ((cls & 2) ? (ti < 4 ? 1 : 2) : 0) * 3 + ((cls & 1) ? (tj < 4 ? 1 : 2) : 0);
        int lk = ((cls & 2) ? (si < 4 ? 1 : 2) : 0) * 3 + ((cls & 1) ? (sj < 4 ? 1 : 2) : 0);
        if (lq != lk) v -= 100.f;
    }
    tab[idx] = v;
}

// ---------------- LayerNorm (+optional shifted-window gather), fp32 -> bf16 ----------------
template <int REMAP>
__global__ __launch_bounds__(256) void ln_kernel(const float* __restrict__ x,
                                                 const float* __restrict__ g,
                                                 const float* __restrict__ b,
                                                 unsigned short* __restrict__ out,
                                                 int rows) {
    int r = blockIdx.x * 4 + (threadIdx.x >> 6);
    int lane = threadIdx.x & 63;
    if (r >= rows) return;
    size_t src = REMAP ? win_to_tok(r) : (size_t)r;
    const float* xp = x + src * 384;
    float v[6];
    float s = 0.f;
#pragma unroll
    for (int i = 0; i < 6; ++i) { v[i] = xp[i * 64 + lane]; s += v[i]; }
#pragma unroll
    for (int off = 32; off; off >>= 1) s += __shfl_xor(s, off, 64);
    float mu = s * (1.f / 384.f);
    float q = 0.f;
#pragma unroll
    for (int i = 0; i < 6; ++i) { float d = v[i] - mu; q += d * d; }
#pragma unroll
    for (int off = 32; off; off >>= 1) q += __shfl_xor(q, off, 64);
    float inv = rsqrtf(q * (1.f / 384.f) + 1e-5f);
    unsigned short* op = out + (size_t)r * 384;
#pragma unroll
    for (int i = 0; i < 6; ++i) {
        int c = i * 64 + lane;
        op[c] = f2b((v[i] - mu) * inv * g[c] + b[c]);
    }
}

// ---------------- GEMM (R12-best: two-barrier ring, swapped-operand epilogue) ----------------
// MODE 0: out bf16 = C (QKV) | 1: resid+C+bias remap fp32 (proj) | 2: gelu (FFN1) | 3: resid+C+bias (FFN2)
template <int MODE, int DEPTH, int MINW>
__global__ __launch_bounds__(256, MINW) void gemm_kernel(const unsigned short* __restrict__ A,
                                                         const unsigned short* __restrict__ Bt,
                                                         int M, int N, int K,
                                                         const float* __restrict__ bias,
                                                         const float* __restrict__ resid,
                                                         unsigned short* __restrict__ outb,
                                                         float* __restrict__ outf) {
    constexpr int NBUF = DEPTH + 1;
    __shared__ unsigned short As[NBUF][128 * 32];
    __shared__ unsigned short Bs[NBUF][128 * 32];
    const int tid = threadIdx.x;
    const int wid = tid >> 6, lane = tid & 63;
    const int ntile = N >> 7;

    int bid = blockIdx.x;
    int nwg = gridDim.x;
    int swb = ((nwg & 7) == 0) ? ((bid & 7) * (nwg >> 3) + (bid >> 3)) : bid;
    const int mt = swb / ntile, nt = swb - mt * ntile;
    const int wr = wid >> 1, wc = wid & 1;

    f32x4 acc[4][4] = {};

    const int rA   = lane >> 2;
    const int kofs = (((lane & 3) ^ ((lane >> 3) & 3)) << 3);
    const unsigned short* Abase = A  + (size_t)(mt * 128) * K;
    const unsigned short* Bbase = Bt + (size_t)(nt * 128) * K;

    auto stage = [&](int buf, int k0) {
#pragma unroll
        for (int j = 0; j < 2; ++j) {
            int c = wid * 2 + j;
            gload_lds16(Abase + (size_t)(c * 16 + rA) * K + k0 + kofs, &As[buf][c * 512]);
            gload_lds16(Bbase + (size_t)(c * 16 + rA) * K + k0 + kofs, &Bs[buf][c * 512]);
        }
    };

    const int sr  = ((lane & 15) >> 1) & 3;
    const int cbA = (((lane >> 4) ^ sr) << 3);
    const int rowA = wr * 64 + (lane & 15);
    const int rowB = wc * 64 + (lane & 15);

    const int nk = K >> 5;
    stage(0, 0);
    if (DEPTH >= 2 && nk > 1) stage(1, 32);
    if (DEPTH >= 3 && nk > 2) stage(2, 64);

    for (int t = 0; t < nk; ++t) {
        const int cur = t % NBUF;
        if (t + DEPTH < nk) {
            stage((t + DEPTH) % NBUF, (t + DEPTH) << 5);
            if constexpr (DEPTH == 1) {
                asm volatile("s_waitcnt vmcnt(4)" ::: "memory");
            } else {
                asm volatile("s_waitcnt vmcnt(12)" ::: "memory");
            }
        } else if (DEPTH >= 3 && t + 2 < nk) {
            asm volatile("s_waitcnt vmcnt(8)" ::: "memory");
        } else if (t + 1 < nk) {
            asm volatile("s_waitcnt vmcnt(4)" ::: "memory");
        } else {
            asm volatile("s_waitcnt vmcnt(0)" ::: "memory");
        }
        __builtin_amdgcn_s_barrier();

        bf16x8 a[4], b[4];
#pragma unroll
        for (int m = 0; m < 4; ++m)
            a[m] = *(const bf16x8*)&As[cur][(rowA + m * 16) * 32 + cbA];
#pragma unroll
        for (int n = 0; n < 4; ++n)
            b[n] = *(const bf16x8*)&Bs[cur][(rowB + n * 16) * 32 + cbA];
#pragma unroll
        for (int m = 0; m < 4; ++m)
#pragma unroll
            for (int n = 0; n < 4; ++n)
                acc[m][n] = __builtin_amdgcn_mfma_f32_16x16x32_bf16(b[n], a[m], acc[m][n], 0, 0, 0);

        asm volatile("s_waitcnt lgkmcnt(0)" ::: "memory");
        __builtin_amdgcn_s_barrier();
    }

    const int row0 = mt * 128 + wr * 64;
    const int col0 = nt * 128 + wc * 64;
    const int rl = lane & 15;
    const int cq = (lane >> 4) << 2;
#pragma unroll
    for (int m = 0; m < 4; ++m) {
        int row = row0 + m * 16 + rl;
        size_t tok = 0;
        if constexpr (MODE == 1) tok = win_to_tok(row);
#pragma unroll
        for (int n = 0; n < 4; ++n) {
            int col = col0 + n * 16 + cq;
            f32x4 v = acc[m][n];
            if constexpr (MODE == 0) {
                u16x4 pk;
#pragma unroll
                for (int r = 0; r < 4; ++r) pk[r] = f2b(v[r]);
                *(u16x4*)&outb[(size_t)row * N + col] = pk;
            } else if constexpr (MODE == 1) {
                size_t o = tok * 384 + col;
                f32x4 rv = *(const f32x4*)&resid[o];
                f32x4 bb = *(const f32x4*)&bias[col];
                f32x4 ov = rv + v + bb;
                *(f32x4*)&outf[o] = ov;
            } else if constexpr (MODE == 2) {
                f32x4 bb = *(const f32x4*)&bias[col];
                u16x4 pk;
#pragma unroll
                for (int r = 0; r < 4; ++r) {
                    float t2 = v[r] + bb[r];
                    float y  = 0.7978845608028654f * (t2 + 0.044715f * t2 * t2 * t2);
                    float u  = __expf(-2.0f * fabsf(y));
                    float th = (1.f - u) / (1.f + u);
                    pk[r] = f2b(0.5f * t2 * (1.f + copysignf(th, t2)));
                }
                *(u16x4*)&outb[(size_t)row * N + col] = pk;
            } else {
                size_t o = (size_t)row * N + col;
                f32x4 rv = *(const f32x4*)&resid[o];
                f32x4 bb = *(const f32x4*)&bias[col];
                f32x4 ov = rv + v + bb;
                *(f32x4*)&outf[o] = ov;
            }
        }
    }
}

// ---------------- GEMM single-barrier ring (FFN2 only: NBUF=4, DEPTH=2) ----------------
template <int MODE, int NBUF, int DEPTH, int MINW>
__global__ __launch_bounds__(256, MINW) void gemm_sb_kernel(const unsigned short* __restrict__ A,
                                                            const unsigned short* __restrict__ Bt,
                                                            int M, int N, int K,
                                                            const float* __restrict__ bias,
                                                            const float* __restrict__ resid,
                                                            unsigned short* __restrict__ outb,
                                                            float* __restrict__ outf) {
    static_assert(NBUF >= DEPTH + 2, "single-barrier ring needs NBUF >= DEPTH+2");
    __shared__ unsigned short As[NBUF][128 * 32];
    __shared__ unsigned short Bs[NBUF][128 * 32];
    const int tid = threadIdx.x;
    const int wid = tid >> 6, lane = tid & 63;
    const int ntile = N >> 7;

    int bid = blockIdx.x;
    int nwg = gridDim.x;
    int swb = ((nwg & 7) == 0) ? ((bid & 7) * (nwg >> 3) + (bid >> 3)) : bid;
    const int mt = swb / ntile, nt = swb - mt * ntile;
    const int wr = wid >> 1, wc = wid & 1;

    f32x4 acc[4][4] = {};

    const int rA   = lane >> 2;
    const int kofs = (((lane & 3) ^ ((lane >> 3) & 3)) << 3);
    const unsigned short* Abase = A  + (size_t)(mt * 128) * K;
    const unsigned short* Bbase = Bt + (size_t)(nt * 128) * K;

    auto stage = [&](int buf, int k0) {
#pragma unroll
        for (int j = 0; j < 2; ++j) {
            int c = wid * 2 + j;
            gload_lds16(Abase + (size_t)(c * 16 + rA) * K + k0 + kofs, &As[buf][c * 512]);
            gload_lds16(Bbase + (size_t)(c * 16 + rA) * K + k0 + kofs, &Bs[buf][c * 512]);
        }
    };

    const int sr  = ((lane & 15) >> 1) & 3;
    const int cbA = (((lane >> 4) ^ sr) << 3);
    const int rowA = wr * 64 + (lane & 15);
    const int rowB = wc * 64 + (lane & 15);

    const int nk = K >> 5;
    stage(0, 0);
    if (DEPTH >= 2 && nk > 1) stage(1, 32);

    for (int t = 0; t < nk; ++t) {
        const int cur = t % NBUF;
        if (t + DEPTH < nk) {
            stage((t + DEPTH) % NBUF, (t + DEPTH) << 5);
            if constexpr (DEPTH == 1) {
                asm volatile("s_waitcnt vmcnt(4)" ::: "memory");
            } else {
                asm volatile("s_waitcnt vmcnt(8)" ::: "memory");
            }
        } else if (DEPTH >= 2 && t + 1 < nk) {
            asm volatile("s_waitcnt vmcnt(4)" ::: "memory");
        } else {
            asm volatile("s_waitcnt vmcnt(0)" ::: "memory");
        }
        __builtin_amdgcn_s_barrier();   // tile t resident; also releases ring slot

        bf16x8 a[4], b[4];
#pragma unroll
        for (int m = 0; m < 4; ++m)
            a[m] = *(const bf16x8*)&As[cur][(rowA + m * 16) * 32 + cbA];
#pragma unroll
        for (int n = 0; n < 4; ++n)
            b[n] = *(const bf16x8*)&Bs[cur][(rowB + n * 16) * 32 + cbA];
#pragma unroll
        for (int m = 0; m < 4; ++m)
#pragma unroll
            for (int n = 0; n < 4; ++n)
                acc[m][n] = __builtin_amdgcn_mfma_f32_16x16x32_bf16(b[n], a[m], acc[m][n], 0, 0, 0);

        asm volatile("s_waitcnt lgkmcnt(0)" ::: "memory");
    }

    const int row0 = mt * 128 + wr * 64;
    const int col0 = nt * 128 + wc * 64;
    const int rl = lane & 15;
    const int cq = (lane >> 4) << 2;
#pragma unroll
    for (int m = 0; m < 4; ++m) {
        int row = row0 + m * 16 + rl;
#pragma unroll
        for (int n = 0; n < 4; ++n) {
            int col = col0 + n * 16 + cq;
            f32x4 v = acc[m][n];
            size_t o = (size_t)row * N + col;
            f32x4 rv = *(const f32x4*)&resid[o];
            f32x4 bb = *(const f32x4*)&bias[col];
            f32x4 ov = rv + v + bb;
            *(f32x4*)&outf[o] = ov;
        }
    }
}

// ---------------- MFMA attention (swapped operands: lane-local softmax rows) ----------------
__global__ __launch_bounds__(256, 2) void attn_kernel(const unsigned short* __restrict__ QKV,
                                                      const float* __restrict__ Btab,
                                                      unsigned short* __restrict__ O) {
    __shared__ char lds[65536];
    char* Kl = lds;              // [hh][m 64][4 chunks x16B]
    char* Vl = lds + 16384;      // [hh][d 32][8 chunks x16B] (V^T)
    char* Pl = lds + 32768;      // [wave][row 64][8 chunks]

    const int w   = blockIdx.x;
    const int tid = threadIdx.x, wid = tid >> 6, lane = tid & 63;
    const int fr  = lane & 15, kq = lane >> 4;
    const size_t base = (size_t)w * 49 * 1152;
    const int widx = w & 63, wi = widx >> 3, wj = widx & 7;
    const int cls = ((wi == 7) ? 2 : 0) | ((wj == 7) ? 1 : 0);
    const float* tb = Btab + (size_t)cls * 12 * 4096;
    constexpr float SCL = 0.17677669529663687f;

    for (int R = 0; R < 3; ++R) {
        if (R) __syncthreads();
        {
            f32x4 z = {};
#pragma unroll
            for (int j = 0; j < 8; ++j) *(f32x4*)(lds + j * 4096 + tid * 16) = z;
        }
        __syncthreads();
        {
            int hh = tid >> 6, h = R * 4 + hh;
#pragma unroll
            for (int it = 0; it < 4; ++it) {
                int i = (tid & 63) + it * 64;
                if (i < 196) {
                    int m = i >> 2, c = i & 3;
                    u16x8 kv = *(const u16x8*)&QKV[base + (size_t)m * 1152 + 384 + h * 32 + c * 8];
                    *(u16x8*)(Kl + hh * 4096 + m * 64 + (c ^ ((m >> 1) & 3)) * 16) = kv;
                    u16x8 vv = *(const u16x8*)&QKV[base + (size_t)m * 1152 + 768 + h * 32 + c * 8];
#pragma unroll
                    for (int j = 0; j < 8; ++j) {
                        int d = c * 8 + j;
                        *(unsigned short*)(Vl + hh * 4096 + d * 128 +
                                           (((m >> 3) ^ (d & 7)) * 16) + (m & 7) * 2) = vv[j];
                    }
                }
            }
        }
        __syncthreads();

        const int h = R * 4 + wid;
        const float* tbh = tb + h * 4096;

        bf16x8 aq[4], bk[4];
#pragma unroll
        for (int mi = 0; mi < 4; ++mi) {
            int row = mi * 16 + fr; if (row > 48) row = 48;
            aq[mi] = *(const bf16x8*)&QKV[base + (size_t)row * 1152 + h * 32 + kq * 8];
        }
#pragma unroll
        for (int ni = 0; ni < 4; ++ni) {
            int rk = ni * 16 + fr;
            bk[ni] = *(const bf16x8*)(Kl + wid * 4096 + rk * 64 + ((kq ^ ((rk >> 1) & 3)) * 16));
        }
        f32x4 s[4][4] = {};
#pragma unroll
        for (int mi = 0; mi < 4; ++mi)
#pragma unroll
            for (int ni = 0; ni < 4; ++ni)
                s[mi][ni] = __builtin_amdgcn_mfma_f32_16x16x32_bf16(bk[ni], aq[mi], s[mi][ni], 0, 0, 0);

        float linv_[4];
#pragma unroll
        for (int mi = 0; mi < 4; ++mi) {
            int row = mi * 16 + fr;
            const float* tr = tbh + row * 64 + kq * 4;
            f32x4 sv[4];
            float mx = -1e30f;
#pragma unroll
            for (int ni = 0; ni < 4; ++ni) {
                f32x4 bb = *(const f32x4*)&tr[ni * 16];
                sv[ni] = s[mi][ni] * SCL + bb;
                mx = fmaxf(mx, fmaxf(fmaxf(sv[ni][0], sv[ni][1]), fmaxf(sv[ni][2], sv[ni][3])));
            }
            mx = fmaxf(mx, __shfl_xor(mx, 16, 64));
            mx = fmaxf(mx, __shfl_xor(mx, 32, 64));
            float sm = 0.f;
#pragma unroll
            for (int ni = 0; ni < 4; ++ni)
#pragma unroll
                for (int r = 0; r < 4; ++r) { sv[ni][r] = __expf(sv[ni][r] - mx); sm += sv[ni][r]; }
            sm += __shfl_xor(sm, 16, 64);
            sm += __shfl_xor(sm, 32, 64);
            linv_[mi] = 1.f / sm;
#pragma unroll
            for (int ni = 0; ni < 4; ++ni) {
                int colb = ni * 16 + kq * 4;
                int phys = (colb >> 3) ^ (row & 7);
                u16x4 pk;
#pragma unroll
                for (int r = 0; r < 4; ++r) pk[r] = f2b(sv[ni][r]);
                *(u16x4*)(Pl + wid * 8192 + row * 128 + phys * 16 + (colb & 7) * 2) = pk;
            }
        }
        asm volatile("s_waitcnt lgkmcnt(0)" ::: "memory");
        __builtin_amdgcn_sched_barrier(0);

        f32x4 oacc[4][2] = {};
#pragma unroll
        for (int sl = 0; sl < 2; ++sl) {
            bf16x8 bv[2];
#pragma unroll
            for (int ni = 0; ni < 2; ++ni) {
                int d = ni * 16 + fr;
                bv[ni] = *(const bf16x8*)(Vl + wid * 4096 + d * 128 + (((sl * 4 + kq) ^ (d & 7)) * 16));
            }
#pragma unroll
            for (int mi = 0; mi < 4; ++mi) {
                int row = mi * 16 + fr;
                bf16x8 ap = *(const bf16x8*)(Pl + wid * 8192 + row * 128 + (((sl * 4 + kq) ^ (row & 7)) * 16));
#pragma unroll
                for (int ni = 0; ni < 2; ++ni)
                    oacc[mi][ni] = __builtin_amdgcn_mfma_f32_16x16x32_bf16(bv[ni], ap, oacc[mi][ni], 0, 0, 0);
            }
        }

#pragma unroll
        for (int mi = 0; mi < 4; ++mi) {
            int row = mi * 16 + fr;
            if (row < 49) {
                float li = linv_[mi];
                unsigned short* op = O + (size_t)(w * 49 + row) * 384 + h * 32 + kq * 4;
#pragma unroll
                for (int ni = 0; ni < 2; ++ni) {
                    u16x4 pk;
#pragma unroll
                    for (int r = 0; r < 4; ++r) pk[r] = f2b(oacc[mi][ni][r] * li);
                    *(u16x4*)&op[ni * 16] = pk;
                }
            }
        }
    }
}

extern "C" void kernel_launch(void* const* d_in, const int* in_sizes, int n_in,
                              void* d_out, int out_size, void* d_ws, size_t ws_size,
                              hipStream_t stream) {
    const float* x     = (const float*)d_in[0];
    const int*   rel   = (const int*)  d_in[3];
    const float* rpb   = (const float*)d_in[4];
    const float* qkvw  = (const float*)d_in[5];
    const float* projw = (const float*)d_in[6];
    const float* projb = (const float*)d_in[7];
    const float* n1g   = (const float*)d_in[8];
    const float* n1b   = (const float*)d_in[9];
    const float* n2g   = (const float*)d_in[10];
    const float* n2b   = (const float*)d_in[11];
    const float* w1    = (const float*)d_in[12];
    const float* b1    = (const float*)d_in[13];
    const float* w2    = (const float*)d_in[14];
    const float* b2    = (const float*)d_in[15];
    float* out = (float*)d_out;

    const int T = in_sizes[0] / 384;   // 100352

    char* ws = (char*)d_ws;
    size_t off = 0;
    auto alloc = [&](size_t bytes) {
        char* p = ws + off;
        off += (bytes + 255) & ~(size_t)255;
        return p;
    };
    unsigned short* WqT  = (unsigned short*)alloc((size_t)1152 * 384 * 2);
    unsigned short* WpT  = (unsigned short*)alloc((size_t)384 * 384 * 2);
    unsigned short* W1T  = (unsigned short*)alloc((size_t)1536 * 384 * 2);
    unsigned short* W2T  = (unsigned short*)alloc((size_t)384 * 1536 * 2);
    float*          Btab = (float*)        alloc((size_t)4 * 12 * 4096 * 4);
    unsigned short* slotA = (unsigned short*)alloc((size_t)T * 384 * 2);   // X1 -> O -> X2
    unsigned short* slotB = (unsigned short*)alloc((size_t)T * 1536 * 2);  // QKV -> F

    unsigned short* X1  = slotA;
    unsigned short* O   = slotA;
    unsigned short* X2  = slotA;
    unsigned short* QKV = slotB;
    unsigned short* F   = slotB;
    float*          Hh  = out;

    wprep<<<dim3((1152 * 384 + 255) / 256), 256, 0, stream>>>(qkvw, WqT, 384, 1152);
    wprep<<<dim3((384 * 384 + 255) / 256),  256, 0, stream>>>(projw, WpT, 384, 384);
    wprep<<<dim3((384 * 1536 + 255) / 256), 256, 0, stream>>>(w1, W1T, 384, 1536);
    wprep<<<dim3((1536 * 384 + 255) / 256), 256, 0, stream>>>(w2, W2T, 1536, 384);
    btab_build<<<dim3((4 * 12 * 4096 + 255) / 256), 256, 0, stream>>>(rel, rpb, Btab);

    // LN1 + shifted-window gather -> X1 (bf16, window-token order)
    ln_kernel<1><<<dim3(T / 4), 256, 0, stream>>>(x, n1g, n1b, X1, T);
    // QKV projection (R12: two-barrier, DEPTH=1, MINW=4)
    gemm_kernel<0, 1, 4><<<dim3((T / 128) * (1152 / 128)), 256, 0, stream>>>(
        X1, WqT, T, 1152, 384, nullptr, nullptr, QKV, nullptr);
    // MFMA windowed attention
    attn_kernel<<<dim3(T / 49), 256, 0, stream>>>(QKV, Btab, O);
    // proj + bias + un-window/un-roll + residual -> Hh (= d_out, fp32)
    gemm_kernel<1, 1, 4><<<dim3((T / 128) * (384 / 128)), 256, 0, stream>>>(
        O, WpT, T, 384, 384, projb, x, nullptr, Hh);
    // LN2 -> X2 (bf16, overwrites slotA)
    ln_kernel<0><<<dim3(T / 4), 256, 0, stream>>>(Hh, n2g, n2b, X2, T);
    // FFN1 + bias + GELU -> F (R12: two-barrier, DEPTH=1, MINW=4)
    gemm_kernel<2, 1, 4><<<dim3((T / 128) * (1536 / 128)), 256, 0, stream>>>(
        X2, W1T, T, 1536, 384, b1, nullptr, F, nullptr);
    // FFN2 + bias + residual -> out (A/B: single-barrier ring NBUF=4, DEPTH=2)
    gemm_sb_kernel<3, 4, 2, 2><<<dim3((T / 128) * (384 / 128)), 256, 0, stream>>>(
        F, W2T, T, 384, 1536, b2, Hh, nullptr, out);
}

// Round 15
// 859.961 us; speedup vs baseline: 1.1687x; 1.0951x over previous
//
#include <hip/hip_runtime.h>

#define DEV __device__ __forceinline__

typedef __bf16 bf16x8 __attribute__((ext_vector_type(8)));
typedef float  f32x4  __attribute__((ext_vector_type(4)));
typedef unsigned short u16x8 __attribute__((ext_vector_type(8)));
typedef unsigned short u16x4 __attribute__((ext_vector_type(4)));

DEV float b2f(unsigned short u) {
    unsigned int t = ((unsigned int)u) << 16;
    return __uint_as_float(t);
}
DEV unsigned short f2b(float f) {
    unsigned int u = __float_as_uint(f);
    unsigned int r = (u + 0x7FFFu + ((u >> 16) & 1u)) >> 16;
    return (unsigned short)r;
}

DEV void gload_lds16(const unsigned short* g, void* l) {
    __builtin_amdgcn_global_load_lds(
        (const __attribute__((address_space(1))) void*)(const void*)g,
        (__attribute__((address_space(3))) void*)l, 16, 0, 0);
}

// dest window-row -> source/dest token index (roll by SS=3, window 7x7, 56x56, 64 win/batch)
DEV size_t win_to_tok(int row) {
    int w = row / 49, t = row - w * 49;
    int b  = w >> 6, widx = w & 63;
    int wi = widx >> 3, wj = widx & 7;
    int ti = t / 7, tj = t - ti * 7;
    int hh = wi * 7 + ti + 3; if (hh >= 56) hh -= 56;
    int ww = wj * 7 + tj + 3; if (ww >= 56) ww -= 56;
    return (size_t)b * 3136 + (size_t)hh * 56 + ww;
}

// ---------------- weight prep: fp32 [K][N] -> bf16 [N][K] ----------------
__global__ void wprep(const float* __restrict__ src, unsigned short* __restrict__ dst,
                      int K, int N) {
    int idx = blockIdx.x * 256 + threadIdx.x;
    if (idx >= K * N) return;
    int k = idx / N, n = idx - k * N;
    dst[(size_t)n * K + k] = f2b(src[idx]);
}

// ---------------- weight prep: fp32 [K][N] -> fp8 e4m3 [N][K] ----------------
__global__ void wprep8(const float* __restrict__ src, unsigned char* __restrict__ dst,
                       int K, int N) {
    int idx = blockIdx.x * 256 + threadIdx.x;
    if (idx >= K * N) return;
    int k = idx / N, n = idx - k * N;
    int p = __builtin_amdgcn_cvt_pk_fp8_f32(src[idx], src[idx], 0, false);
    dst[(size_t)n * K + k] = (unsigned char)(p & 0xff);
}

// ---------------- bias table: [cls 4][h 12][row 64][col 64] fp32 ----------------
__global__ void btab_build(const int* __restrict__ rel_idx, const float* __restrict__ rpb,
                           float* __restrict__ tab) {
    int idx = blockIdx.x * 256 + threadIdx.x;
    if (idx >= 4 * 12 * 64 * 64) return;
    int col = idx & 63, row = (idx >> 6) & 63;
    int h = (idx >> 12) % 12, cls = idx / (12 * 4096);
    float v;
    if (row >= 49 || col >= 49) {
        v = -10000.f;
    } else {
        v = rpb[rel_idx[row * 49 + col] * 12 + h];
        int ti = row / 7, tj = row - (row / 7) * 7;
        int si = col / 7, sj = col - (col / 7) * 7;
        int lq = ((cls & 2) ? (ti < 4 ? 1 : 2) : 0) * 3 + ((cls & 1) ? (tj < 4 ? 1 : 2) : 0);
        int lk = ((cls & 2) ? (si < 4 ? 1 : 2) : 0) * 3 + ((cls & 1) ? (sj < 4 ? 1 : 2) : 0);
        if (lq != lk) v -= 100.f;
    }
    tab[idx] = v;
}

// ---------------- LayerNorm (+optional shifted-window gather), fp32 -> bf16 ----------------
template <int REMAP>
__global__ __launch_bounds__(256) void ln_kernel(const float* __restrict__ x,
                                                 const float* __restrict__ g,
                                                 const float* __restrict__ b,
                                                 unsigned short* __restrict__ out,
                                                 int rows) {
    int r = blockIdx.x * 4 + (threadIdx.x >> 6);
    int lane = threadIdx.x & 63;
    if (r >= rows) return;
    size_t src = REMAP ? win_to_tok(r) : (size_t)r;
    const float* xp = x + src * 384;
    float v[6];
    float s = 0.f;
#pragma unroll
    for (int i = 0; i < 6; ++i) { v[i] = xp[i * 64 + lane]; s += v[i]; }
#pragma unroll
    for (int off = 32; off; off >>= 1) s += __shfl_xor(s, off, 64);
    float mu = s * (1.f / 384.f);
    float q = 0.f;
#pragma unroll
    for (int i = 0; i < 6; ++i) { float d = v[i] - mu; q += d * d; }
#pragma unroll
    for (int off = 32; off; off >>= 1) q += __shfl_xor(q, off, 64);
    float inv = rsqrtf(q * (1.f / 384.f) + 1e-5f);
    unsigned short* op = out + (size_t)r * 384;
#pragma unroll
    for (int i = 0; i < 6; ++i) {
        int c = i * 64 + lane;
        op[c] = f2b((v[i] - mu) * inv * g[c] + b[c]);
    }
}

// ---------------- GEMM (R12-best: two-barrier ring, swapped-operand epilogue) ----------------
// MODE 0: out bf16 = C (QKV) | 1: resid+C+bias remap fp32 (proj)
// MODE 4: out fp8 e4m3 = gelu(C + bias)  (FFN1; outb reinterpreted as byte buffer, N=bytes/row)
template <int MODE, int DEPTH, int MINW>
__global__ __launch_bounds__(256, MINW) void gemm_kernel(const unsigned short* __restrict__ A,
                                                         const unsigned short* __restrict__ Bt,
                                                         int M, int N, int K,
                                                         const float* __restrict__ bias,
                                                         const float* __restrict__ resid,
                                                         unsigned short* __restrict__ outb,
                                                         float* __restrict__ outf) {
    constexpr int NBUF = DEPTH + 1;
    __shared__ unsigned short As[NBUF][128 * 32];
    __shared__ unsigned short Bs[NBUF][128 * 32];
    const int tid = threadIdx.x;
    const int wid = tid >> 6, lane = tid & 63;
    const int ntile = N >> 7;

    int bid = blockIdx.x;
    int nwg = gridDim.x;
    int swb = ((nwg & 7) == 0) ? ((bid & 7) * (nwg >> 3) + (bid >> 3)) : bid;
    const int mt = swb / ntile, nt = swb - mt * ntile;
    const int wr = wid >> 1, wc = wid & 1;

    f32x4 acc[4][4] = {};

    const int rA   = lane >> 2;
    const int kofs = (((lane & 3) ^ ((lane >> 3) & 3)) << 3);
    const unsigned short* Abase = A  + (size_t)(mt * 128) * K;
    const unsigned short* Bbase = Bt + (size_t)(nt * 128) * K;

    auto stage = [&](int buf, int k0) {
#pragma unroll
        for (int j = 0; j < 2; ++j) {
            int c = wid * 2 + j;
            gload_lds16(Abase + (size_t)(c * 16 + rA) * K + k0 + kofs, &As[buf][c * 512]);
            gload_lds16(Bbase + (size_t)(c * 16 + rA) * K + k0 + kofs, &Bs[buf][c * 512]);
        }
    };

    const int sr  = ((lane & 15) >> 1) & 3;
    const int cbA = (((lane >> 4) ^ sr) << 3);
    const int rowA = wr * 64 + (lane & 15);
    const int rowB = wc * 64 + (lane & 15);

    const int nk = K >> 5;
    stage(0, 0);
    if (DEPTH >= 2 && nk > 1) stage(1, 32);
    if (DEPTH >= 3 && nk > 2) stage(2, 64);

    for (int t = 0; t < nk; ++t) {
        const int cur = t % NBUF;
        if (t + DEPTH < nk) {
            stage((t + DEPTH) % NBUF, (t + DEPTH) << 5);
            if constexpr (DEPTH == 1) {
                asm volatile("s_waitcnt vmcnt(4)" ::: "memory");
            } else {
                asm volatile("s_waitcnt vmcnt(12)" ::: "memory");
            }
        } else if (DEPTH >= 3 && t + 2 < nk) {
            asm volatile("s_waitcnt vmcnt(8)" ::: "memory");
        } else if (t + 1 < nk) {
            asm volatile("s_waitcnt vmcnt(4)" ::: "memory");
        } else {
            asm volatile("s_waitcnt vmcnt(0)" ::: "memory");
        }
        __builtin_amdgcn_s_barrier();

        bf16x8 a[4], b[4];
#pragma unroll
        for (int m = 0; m < 4; ++m)
            a[m] = *(const bf16x8*)&As[cur][(rowA + m * 16) * 32 + cbA];
#pragma unroll
        for (int n = 0; n < 4; ++n)
            b[n] = *(const bf16x8*)&Bs[cur][(rowB + n * 16) * 32 + cbA];
#pragma unroll
        for (int m = 0; m < 4; ++m)
#pragma unroll
            for (int n = 0; n < 4; ++n)
                acc[m][n] = __builtin_amdgcn_mfma_f32_16x16x32_bf16(b[n], a[m], acc[m][n], 0, 0, 0);

        asm volatile("s_waitcnt lgkmcnt(0)" ::: "memory");
        __builtin_amdgcn_s_barrier();
    }

    const int row0 = mt * 128 + wr * 64;
    const int col0 = nt * 128 + wc * 64;
    const int rl = lane & 15;
    const int cq = (lane >> 4) << 2;
#pragma unroll
    for (int m = 0; m < 4; ++m) {
        int row = row0 + m * 16 + rl;
        size_t tok = 0;
        if constexpr (MODE == 1) tok = win_to_tok(row);
#pragma unroll
        for (int n = 0; n < 4; ++n) {
            int col = col0 + n * 16 + cq;
            f32x4 v = acc[m][n];
            if constexpr (MODE == 0) {
                u16x4 pk;
#pragma unroll
                for (int r = 0; r < 4; ++r) pk[r] = f2b(v[r]);
                *(u16x4*)&outb[(size_t)row * N + col] = pk;
            } else if constexpr (MODE == 1) {
                size_t o = tok * 384 + col;
                f32x4 rv = *(const f32x4*)&resid[o];
                f32x4 bb = *(const f32x4*)&bias[col];
                f32x4 ov = rv + v + bb;
                *(f32x4*)&outf[o] = ov;
            } else {   // MODE 4: gelu -> fp8
                f32x4 bb = *(const f32x4*)&bias[col];
                float g4[4];
#pragma unroll
                for (int r = 0; r < 4; ++r) {
                    float t2 = v[r] + bb[r];
                    float y  = 0.7978845608028654f * (t2 + 0.044715f * t2 * t2 * t2);
                    float u  = __expf(-2.0f * fabsf(y));
                    float th = (1.f - u) / (1.f + u);
                    g4[r] = 0.5f * t2 * (1.f + copysignf(th, t2));
                }
                int pk = 0;
                pk = __builtin_amdgcn_cvt_pk_fp8_f32(g4[0], g4[1], pk, false);
                pk = __builtin_amdgcn_cvt_pk_fp8_f32(g4[2], g4[3], pk, true);
                *(int*)((char*)outb + (size_t)row * N + col) = pk;
            }
        }
    }
}

// ---------------- FFN2 fp8 GEMM: single-barrier ring, BK=64 ----------------
// C[M][N] = A8[M][K]fp8 x Bt8[N][K]fp8 + resid + bias (fp32 out).
// Row = 64 fp8 bytes = 8 slots of 8B; pair-granular XOR swizzle: phys pair = p ^ ((row>>1)&3)
// (within-pair order preserved -> 16B gload_lds source stays contiguous).
template <int NBUF, int DEPTH, int MINW>
__global__ __launch_bounds__(256, MINW) void gemm_f8_kernel(const unsigned char* __restrict__ A,
                                                            const unsigned char* __restrict__ Bt,
                                                            int M, int N, int K,
                                                            const float* __restrict__ bias,
                                                            const float* __restrict__ resid,
                                                            float* __restrict__ outf) {
    static_assert(NBUF >= DEPTH + 2, "single-barrier ring needs NBUF >= DEPTH+2");
    __shared__ unsigned char As[NBUF][128 * 64];   // 8 KB each
    __shared__ unsigned char Bs[NBUF][128 * 64];
    const int tid = threadIdx.x;
    const int wid = tid >> 6, lane = tid & 63;
    const int ntile = N >> 7;

    int bid = blockIdx.x;
    int nwg = gridDim.x;
    int swb = ((nwg & 7) == 0) ? ((bid & 7) * (nwg >> 3) + (bid >> 3)) : bid;
    const int mt = swb / ntile, nt = swb - mt * ntile;
    const int wr = wid >> 1, wc = wid & 1;

    f32x4 acc[4][4] = {};

    const int srow = tid >> 2;                       // 0..63
    const unsigned char* Abase = A  + (size_t)(mt * 128) * K;
    const unsigned char* Bbase = Bt + (size_t)(nt * 128) * K;

    auto stage = [&](int buf, int k0) {
#pragma unroll
        for (int j = 0; j < 2; ++j) {
            int r  = j * 64 + srow;
            int gp = (tid & 3) ^ ((r >> 1) & 3);     // pre-swizzled global pair
            gload_lds16((const unsigned short*)(Abase + (size_t)r * K + k0 + gp * 16),
                        &As[buf][j * 4096 + tid * 16]);
            gload_lds16((const unsigned short*)(Bbase + (size_t)r * K + k0 + gp * 16),
                        &Bs[buf][j * 4096 + tid * 16]);
        }
    };

    const int fr = lane & 15, kq = lane >> 4;
    const int rowA = wr * 64 + fr;
    const int rowB = wc * 64 + fr;
    auto ldf8 = [&](const unsigned char* base, int row, int ks) -> long {
        int slot = ks * 4 + kq;
        int phys = ((((slot >> 1) ^ ((row >> 1) & 3)) << 1) | (slot & 1));
        return *(const long*)(base + row * 64 + phys * 8);
    };

    const int nk = K >> 6;   // BK=64 -> 24 steps for K=1536
    stage(0, 0);
    if (nk > 1) stage(1, 64);

    for (int t = 0; t < nk; ++t) {
        const int cur = t % NBUF;
        if (t + DEPTH < nk) {
            stage((t + DEPTH) % NBUF, (t + DEPTH) << 6);
            asm volatile("s_waitcnt vmcnt(8)" ::: "memory");
        } else if (t + 1 < nk) {
            asm volatile("s_waitcnt vmcnt(4)" ::: "memory");
        } else {
            asm volatile("s_waitcnt vmcnt(0)" ::: "memory");
        }
        __builtin_amdgcn_s_barrier();   // tile t resident; also releases ring slot

        long a[4][2], b[4][2];
#pragma unroll
        for (int m = 0; m < 4; ++m) {
            a[m][0] = ldf8(As[cur], rowA + m * 16, 0);
            a[m][1] = ldf8(As[cur], rowA + m * 16, 1);
        }
#pragma unroll
        for (int n = 0; n < 4; ++n) {
            b[n][0] = ldf8(Bs[cur], rowB + n * 16, 0);
            b[n][1] = ldf8(Bs[cur], rowB + n * 16, 1);
        }
#pragma unroll
        for (int ks = 0; ks < 2; ++ks)
#pragma unroll
            for (int m = 0; m < 4; ++m)
#pragma unroll
                for (int n = 0; n < 4; ++n)
                    acc[m][n] = __builtin_amdgcn_mfma_f32_16x16x32_fp8_fp8(b[n][ks], a[m][ks], acc[m][n], 0, 0, 0);

        asm volatile("s_waitcnt lgkmcnt(0)" ::: "memory");
    }

    const int row0 = mt * 128 + wr * 64;
    const int col0 = nt * 128 + wc * 64;
    const int rl = lane & 15;
    const int cq = (lane >> 4) << 2;
#pragma unroll
    for (int m = 0; m < 4; ++m) {
        int row = row0 + m * 16 + rl;
#pragma unroll
        for (int n = 0; n < 4; ++n) {
            int col = col0 + n * 16 + cq;
            f32x4 v = acc[m][n];
            size_t o = (size_t)row * N + col;
            f32x4 rv = *(const f32x4*)&resid[o];
            f32x4 bb = *(const f32x4*)&bias[col];
            f32x4 ov = rv + v + bb;
            *(f32x4*)&outf[o] = ov;
        }
    }
}

// ---------------- MFMA attention (swapped operands: lane-local softmax rows) ----------------
__global__ __launch_bounds__(256, 2) void attn_kernel(const unsigned short* __restrict__ QKV,
                                                      const float* __restrict__ Btab,
                                                      unsigned short* __restrict__ O) {
    __shared__ char lds[65536];
    char* Kl = lds;              // [hh][m 64][4 chunks x16B]
    char* Vl = lds + 16384;      // [hh][d 32][8 chunks x16B] (V^T)
    char* Pl = lds + 32768;      // [wave][row 64][8 chunks]

    const int w   = blockIdx.x;
    const int tid = threadIdx.x, wid = tid >> 6, lane = tid & 63;
    const int fr  = lane & 15, kq = lane >> 4;
    const size_t base = (size_t)w * 49 * 1152;
    const int widx = w & 63, wi = widx >> 3, wj = widx & 7;
    const int cls = ((wi == 7) ? 2 : 0) | ((wj == 7) ? 1 : 0);
    const float* tb = Btab + (size_t)cls * 12 * 4096;
    constexpr float SCL = 0.17677669529663687f;

    for (int R = 0; R < 3; ++R) {
        if (R) __syncthreads();
        {
            f32x4 z = {};
#pragma unroll
            for (int j = 0; j < 8; ++j) *(f32x4*)(lds + j * 4096 + tid * 16) = z;
        }
        __syncthreads();
        {
            int hh = tid >> 6, h = R * 4 + hh;
#pragma unroll
            for (int it = 0; it < 4; ++it) {
                int i = (tid & 63) + it * 64;
                if (i < 196) {
                    int m = i >> 2, c = i & 3;
                    u16x8 kv = *(const u16x8*)&QKV[base + (size_t)m * 1152 + 384 + h * 32 + c * 8];
                    *(u16x8*)(Kl + hh * 4096 + m * 64 + (c ^ ((m >> 1) & 3)) * 16) = kv;
                    u16x8 vv = *(const u16x8*)&QKV[base + (size_t)m * 1152 + 768 + h * 32 + c * 8];
#pragma unroll
                    for (int j = 0; j < 8; ++j) {
                        int d = c * 8 + j;
                        *(unsigned short*)(Vl + hh * 4096 + d * 128 +
                                           (((m >> 3) ^ (d & 7)) * 16) + (m & 7) * 2) = vv[j];
                    }
                }
            }
        }
        __syncthreads();

        const int h = R * 4 + wid;
        const float* tbh = tb + h * 4096;

        bf16x8 aq[4], bk[4];
#pragma unroll
        for (int mi = 0; mi < 4; ++mi) {
            int row = mi * 16 + fr; if (row > 48) row = 48;
            aq[mi] = *(const bf16x8*)&QKV[base + (size_t)row * 1152 + h * 32 + kq * 8];
        }
#pragma unroll
        for (int ni = 0; ni < 4; ++ni) {
            int rk = ni * 16 + fr;
            bk[ni] = *(const bf16x8*)(Kl + wid * 4096 + rk * 64 + ((kq ^ ((rk >> 1) & 3)) * 16));
        }
        f32x4 s[4][4] = {};
#pragma unroll
        for (int mi = 0; mi < 4; ++mi)
#pragma unroll
            for (int ni = 0; ni < 4; ++ni)
                s[mi][ni] = __builtin_amdgcn_mfma_f32_16x16x32_bf16(bk[ni], aq[mi], s[mi][ni], 0, 0, 0);

        float linv_[4];
#pragma unroll
        for (int mi = 0; mi < 4; ++mi) {
            int row = mi * 16 + fr;
            const float* tr = tbh + row * 64 + kq * 4;
            f32x4 sv[4];
            float mx = -1e30f;
#pragma unroll
            for (int ni = 0; ni < 4; ++ni) {
                f32x4 bb = *(const f32x4*)&tr[ni * 16];
                sv[ni] = s[mi][ni] * SCL + bb;
                mx = fmaxf(mx, fmaxf(fmaxf(sv[ni][0], sv[ni][1]), fmaxf(sv[ni][2], sv[ni][3])));
            }
            mx = fmaxf(mx, __shfl_xor(mx, 16, 64));
            mx = fmaxf(mx, __shfl_xor(mx, 32, 64));
            float sm = 0.f;
#pragma unroll
            for (int ni = 0; ni < 4; ++ni)
#pragma unroll
                for (int r = 0; r < 4; ++r) { sv[ni][r] = __expf(sv[ni][r] - mx); sm += sv[ni][r]; }
            sm += __shfl_xor(sm, 16, 64);
            sm += __shfl_xor(sm, 32, 64);
            linv_[mi] = 1.f / sm;
#pragma unroll
            for (int ni = 0; ni < 4; ++ni) {
                int colb = ni * 16 + kq * 4;
                int phys = (colb >> 3) ^ (row & 7);
                u16x4 pk;
#pragma unroll
                for (int r = 0; r < 4; ++r) pk[r] = f2b(sv[ni][r]);
                *(u16x4*)(Pl + wid * 8192 + row * 128 + phys * 16 + (colb & 7) * 2) = pk;
            }
        }
        asm volatile("s_waitcnt lgkmcnt(0)" ::: "memory");
        __builtin_amdgcn_sched_barrier(0);

        f32x4 oacc[4][2] = {};
#pragma unroll
        for (int sl = 0; sl < 2; ++sl) {
            bf16x8 bv[2];
#pragma unroll
            for (int ni = 0; ni < 2; ++ni) {
                int d = ni * 16 + fr;
                bv[ni] = *(const bf16x8*)(Vl + wid * 4096 + d * 128 + (((sl * 4 + kq) ^ (d & 7)) * 16));
            }
#pragma unroll
            for (int mi = 0; mi < 4; ++mi) {
                int row = mi * 16 + fr;
                bf16x8 ap = *(const bf16x8*)(Pl + wid * 8192 + row * 128 + (((sl * 4 + kq) ^ (row & 7)) * 16));
#pragma unroll
                for (int ni = 0; ni < 2; ++ni)
                    oacc[mi][ni] = __builtin_amdgcn_mfma_f32_16x16x32_bf16(bv[ni], ap, oacc[mi][ni], 0, 0, 0);
            }
        }

#pragma unroll
        for (int mi = 0; mi < 4; ++mi) {
            int row = mi * 16 + fr;
            if (row < 49) {
                float li = linv_[mi];
                unsigned short* op = O + (size_t)(w * 49 + row) * 384 + h * 32 + kq * 4;
#pragma unroll
                for (int ni = 0; ni < 2; ++ni) {
                    u16x4 pk;
#pragma unroll
                    for (int r = 0; r < 4; ++r) pk[r] = f2b(oacc[mi][ni][r] * li);
                    *(u16x4*)&op[ni * 16] = pk;
                }
            }
        }
    }
}

extern "C" void kernel_launch(void* const* d_in, const int* in_sizes, int n_in,
                              void* d_out, int out_size, void* d_ws, size_t ws_size,
                              hipStream_t stream) {
    const float* x     = (const float*)d_in[0];
    const int*   rel   = (const int*)  d_in[3];
    const float* rpb   = (const float*)d_in[4];
    const float* qkvw  = (const float*)d_in[5];
    const float* projw = (const float*)d_in[6];
    const float* projb = (const float*)d_in[7];
    const float* n1g   = (const float*)d_in[8];
    const float* n1b   = (const float*)d_in[9];
    const float* n2g   = (const float*)d_in[10];
    const float* n2b   = (const float*)d_in[11];
    const float* w1    = (const float*)d_in[12];
    const float* b1    = (const float*)d_in[13];
    const float* w2    = (const float*)d_in[14];
    const float* b2    = (const float*)d_in[15];
    float* out = (float*)d_out;

    const int T = in_sizes[0] / 384;   // 100352

    char* ws = (char*)d_ws;
    size_t off = 0;
    auto alloc = [&](size_t bytes) {
        char* p = ws + off;
        off += (bytes + 255) & ~(size_t)255;
        return p;
    };
    unsigned short* WqT  = (unsigned short*)alloc((size_t)1152 * 384 * 2);
    unsigned short* WpT  = (unsigned short*)alloc((size_t)384 * 384 * 2);
    unsigned short* W1T  = (unsigned short*)alloc((size_t)1536 * 384 * 2);
    unsigned char*  W2T8 = (unsigned char*) alloc((size_t)384 * 1536);
    float*          Btab = (float*)         alloc((size_t)4 * 12 * 4096 * 4);
    unsigned short* slotA = (unsigned short*)alloc((size_t)T * 384 * 2);   // X1 -> O -> X2
    unsigned short* slotB = (unsigned short*)alloc((size_t)T * 1536 * 2);  // QKV -> F8

    unsigned short* X1  = slotA;
    unsigned short* O   = slotA;
    unsigned short* X2  = slotA;
    unsigned short* QKV = slotB;
    unsigned char*  F8  = (unsigned char*)slotB;
    float*          Hh  = out;

    wprep<<<dim3((1152 * 384 + 255) / 256), 256, 0, stream>>>(qkvw, WqT, 384, 1152);
    wprep<<<dim3((384 * 384 + 255) / 256),  256, 0, stream>>>(projw, WpT, 384, 384);
    wprep<<<dim3((384 * 1536 + 255) / 256), 256, 0, stream>>>(w1, W1T, 384, 1536);
    wprep8<<<dim3((1536 * 384 + 255) / 256), 256, 0, stream>>>(w2, W2T8, 1536, 384);
    btab_build<<<dim3((4 * 12 * 4096 + 255) / 256), 256, 0, stream>>>(rel, rpb, Btab);

    // LN1 + shifted-window gather -> X1 (bf16, window-token order)
    ln_kernel<1><<<dim3(T / 4), 256, 0, stream>>>(x, n1g, n1b, X1, T);
    // QKV projection (two-barrier, DEPTH=1, MINW=4)
    gemm_kernel<0, 1, 4><<<dim3((T / 128) * (1152 / 128)), 256, 0, stream>>>(
        X1, WqT, T, 1152, 384, nullptr, nullptr, QKV, nullptr);
    // MFMA windowed attention
    attn_kernel<<<dim3(T / 49), 256, 0, stream>>>(QKV, Btab, O);
    // proj + bias + un-window/un-roll + residual -> Hh (= d_out, fp32)
    gemm_kernel<1, 1, 4><<<dim3((T / 128) * (384 / 128)), 256, 0, stream>>>(
        O, WpT, T, 384, 384, projb, x, nullptr, Hh);
    // LN2 -> X2 (bf16, overwrites slotA)
    ln_kernel<0><<<dim3(T / 4), 256, 0, stream>>>(Hh, n2g, n2b, X2, T);
    // FFN1 + bias + GELU -> F8 (fp8 e4m3, overwrites slotB; N = 1536 bytes/row)
    gemm_kernel<4, 1, 4><<<dim3((T / 128) * (1536 / 128)), 256, 0, stream>>>(
        X2, W1T, T, 1536, 384, b1, nullptr, (unsigned short*)F8, nullptr);
    // FFN2 (fp8, BK=64, single-barrier ring) + bias + residual -> out (in-place RMW)
    gemm_f8_kernel<4, 2, 2><<<dim3((T / 128) * (384 / 128)), 256, 0, stream>>>(
        F8, W2T8, T, 384, 1536, b2, Hh, out);
}

// Round 16
// 696.205 us; speedup vs baseline: 1.4436x; 1.2352x over previous
//
#include <hip/hip_runtime.h>

#define DEV __device__ __forceinline__

typedef __bf16 bf16x8 __attribute__((ext_vector_type(8)));
typedef float  f32x4  __attribute__((ext_vector_type(4)));
typedef unsigned short u16x8 __attribute__((ext_vector_type(8)));
typedef unsigned short u16x4 __attribute__((ext_vector_type(4)));

DEV float b2f(unsigned short u) {
    unsigned int t = ((unsigned int)u) << 16;
    return __uint_as_float(t);
}
DEV unsigned short f2b(float f) {
    unsigned int u = __float_as_uint(f);
    unsigned int r = (u + 0x7FFFu + ((u >> 16) & 1u)) >> 16;
    return (unsigned short)r;
}
DEV unsigned char f2f8(float f) {
    return (unsigned char)(__builtin_amdgcn_cvt_pk_fp8_f32(f, f, 0, false) & 0xff);
}

DEV void gload_lds16(const void* g, void* l) {
    __builtin_amdgcn_global_load_lds(
        (const __attribute__((address_space(1))) void*)g,
        (__attribute__((address_space(3))) void*)l, 16, 0, 0);
}

// dest window-row -> source/dest token index (roll by SS=3, window 7x7, 56x56, 64 win/batch)
DEV size_t win_to_tok(int row) {
    int w = row / 49, t = row - w * 49;
    int b  = w >> 6, widx = w & 63;
    int wi = widx >> 3, wj = widx & 7;
    int ti = t / 7, tj = t - ti * 7;
    int hh = wi * 7 + ti + 3; if (hh >= 56) hh -= 56;
    int ww = wj * 7 + tj + 3; if (ww >= 56) ww -= 56;
    return (size_t)b * 3136 + (size_t)hh * 56 + ww;
}

// ---------------- weight prep: fp32 [K][N] -> fp8 e4m3 [N][K] ----------------
__global__ void wprep8(const float* __restrict__ src, unsigned char* __restrict__ dst,
                       int K, int N) {
    int idx = blockIdx.x * 256 + threadIdx.x;
    if (idx >= K * N) return;
    int k = idx / N, n = idx - k * N;
    dst[(size_t)n * K + k] = f2f8(src[idx]);
}

// ---------------- bias table: [cls 4][h 12][row 64][col 64] fp32 ----------------
__global__ void btab_build(const int* __restrict__ rel_idx, const float* __restrict__ rpb,
                           float* __restrict__ tab) {
    int idx = blockIdx.x * 256 + threadIdx.x;
    if (idx >= 4 * 12 * 64 * 64) return;
    int col = idx & 63, row = (idx >> 6) & 63;
    int h = (idx >> 12) % 12, cls = idx / (12 * 4096);
    float v;
    if (row >= 49 || col >= 49) {
        v = -10000.f;
    } else {
        v = rpb[rel_idx[row * 49 + col] * 12 + h];
        int ti = row / 7, tj = row - (row / 7) * 7;
        int si = col / 7, sj = col - (col / 7) * 7;
        int lq = ((cls & 2) ? (ti < 4 ? 1 : 2) : 0) * 3 + ((cls & 1) ? (tj < 4 ? 1 : 2) : 0);
        int lk = ((cls & 2) ? (si < 4 ? 1 : 2) : 0) * 3 + ((cls & 1) ? (sj < 4 ? 1 : 2) : 0);
        if (lq != lk) v -= 100.f;
    }
    tab[idx] = v;
}

// ---------------- LayerNorm (+optional shifted-window gather), fp32 -> fp8 ----------------
template <int REMAP>
__global__ __launch_bounds__(256) void ln_kernel(const float* __restrict__ x,
                                                 const float* __restrict__ g,
                                                 const float* __restrict__ b,
                                                 unsigned char* __restrict__ out,
                                                 int rows) {
    int r = blockIdx.x * 4 + (threadIdx.x >> 6);
    int lane = threadIdx.x & 63;
    if (r >= rows) return;
    size_t src = REMAP ? win_to_tok(r) : (size_t)r;
    const float* xp = x + src * 384;
    float v[6];
    float s = 0.f;
#pragma unroll
    for (int i = 0; i < 6; ++i) { v[i] = xp[i * 64 + lane]; s += v[i]; }
#pragma unroll
    for (int off = 32; off; off >>= 1) s += __shfl_xor(s, off, 64);
    float mu = s * (1.f / 384.f);
    float q = 0.f;
#pragma unroll
    for (int i = 0; i < 6; ++i) { float d = v[i] - mu; q += d * d; }
#pragma unroll
    for (int off = 32; off; off >>= 1) q += __shfl_xor(q, off, 64);
    float inv = rsqrtf(q * (1.f / 384.f) + 1e-5f);
    unsigned char* op = out + (size_t)r * 384;
#pragma unroll
    for (int i = 0; i < 6; ++i) {
        int c = i * 64 + lane;
        op[c] = f2f8((v[i] - mu) * inv * g[c] + b[c]);
    }
}

// ---------------- fp8 GEMM: C[M][N] = A8[M][K] x Bt8[N][K], BK=64 ----------------
// SB=0: two-barrier ring (NBUF=DEPTH+1)  — best for short-K (R12/R13 A/B)
// SB=1: single-barrier ring (NBUF>=DEPTH+2) — best for long-K (R14 A/B)
// Pair-granular XOR swizzle: phys pair = p ^ ((row>>1)&3), within-pair order kept
// (16B gload_lds source stays contiguous). Swapped-operand MFMA -> vectorized stores.
// MODE 0: out bf16 (QKV) | 1: resid+C+bias, win_to_tok remap, fp32 (proj)
// MODE 2: fp8 = gelu_sigmoid(C+bias) (FFN1) | 3: resid+C+bias fp32 (FFN2)
template <int MODE, int NBUF, int DEPTH, int SB, int MINW>
__global__ __launch_bounds__(256, MINW) void gemm_f8_kernel(const unsigned char* __restrict__ A,
                                                            const unsigned char* __restrict__ Bt,
                                                            int M, int N, int K,
                                                            const float* __restrict__ bias,
                                                            const float* __restrict__ resid,
                                                            unsigned char* __restrict__ outb8,
                                                            unsigned short* __restrict__ outb,
                                                            float* __restrict__ outf) {
    static_assert(SB ? (NBUF >= DEPTH + 2) : (NBUF >= DEPTH + 1), "ring too small");
    __shared__ unsigned char As[NBUF][128 * 64];   // 8 KB each
    __shared__ unsigned char Bs[NBUF][128 * 64];
    const int tid = threadIdx.x;
    const int wid = tid >> 6, lane = tid & 63;
    const int ntile = N >> 7;

    int bid = blockIdx.x;
    int nwg = gridDim.x;
    int swb = ((nwg & 7) == 0) ? ((bid & 7) * (nwg >> 3) + (bid >> 3)) : bid;
    const int mt = swb / ntile, nt = swb - mt * ntile;
    const int wr = wid >> 1, wc = wid & 1;

    f32x4 acc[4][4] = {};

    const int srow = tid >> 2;                       // 0..63
    const unsigned char* Abase = A  + (size_t)(mt * 128) * K;
    const unsigned char* Bbase = Bt + (size_t)(nt * 128) * K;

    auto stage = [&](int buf, int k0) {
#pragma unroll
        for (int j = 0; j < 2; ++j) {
            int r  = j * 64 + srow;
            int gp = (tid & 3) ^ ((r >> 1) & 3);     // pre-swizzled global pair
            gload_lds16(Abase + (size_t)r * K + k0 + gp * 16, &As[buf][j * 4096 + tid * 16]);
            gload_lds16(Bbase + (size_t)r * K + k0 + gp * 16, &Bs[buf][j * 4096 + tid * 16]);
        }
    };

    const int fr = lane & 15, kq = lane >> 4;
    const int rowA = wr * 64 + fr;
    const int rowB = wc * 64 + fr;
    auto ldf8 = [&](const unsigned char* base, int row, int ks) -> long {
        int slot = ks * 4 + kq;
        int phys = ((((slot >> 1) ^ ((row >> 1) & 3)) << 1) | (slot & 1));
        return *(const long*)(base + row * 64 + phys * 8);
    };

    const int nk = K >> 6;   // BK=64
    stage(0, 0);
    if (DEPTH >= 2 && nk > 1) stage(1, 64);

    for (int t = 0; t < nk; ++t) {
        const int cur = t % NBUF;
        if (t + DEPTH < nk) {
            stage((t + DEPTH) % NBUF, (t + DEPTH) << 6);
            if constexpr (DEPTH == 1) {
                asm volatile("s_waitcnt vmcnt(4)" ::: "memory");
            } else {
                asm volatile("s_waitcnt vmcnt(8)" ::: "memory");
            }
        } else if (DEPTH >= 2 && t + 1 < nk) {
            asm volatile("s_waitcnt vmcnt(4)" ::: "memory");
        } else {
            asm volatile("s_waitcnt vmcnt(0)" ::: "memory");
        }
        __builtin_amdgcn_s_barrier();   // tile t resident for every wave

        long a[4][2], b[4][2];
#pragma unroll
        for (int m = 0; m < 4; ++m) {
            a[m][0] = ldf8(As[cur], rowA + m * 16, 0);
            a[m][1] = ldf8(As[cur], rowA + m * 16, 1);
        }
#pragma unroll
        for (int n = 0; n < 4; ++n) {
            b[n][0] = ldf8(Bs[cur], rowB + n * 16, 0);
            b[n][1] = ldf8(Bs[cur], rowB + n * 16, 1);
        }
#pragma unroll
        for (int ks = 0; ks < 2; ++ks)
#pragma unroll
            for (int m = 0; m < 4; ++m)
#pragma unroll
                for (int n = 0; n < 4; ++n)
                    acc[m][n] = __builtin_amdgcn_mfma_f32_16x16x32_fp8_fp8(b[n][ks], a[m][ks], acc[m][n], 0, 0, 0);

        asm volatile("s_waitcnt lgkmcnt(0)" ::: "memory");
        if constexpr (SB == 0) __builtin_amdgcn_s_barrier();
    }

    const int row0 = mt * 128 + wr * 64;
    const int col0 = nt * 128 + wc * 64;
    const int rl = lane & 15;
    const int cq = (lane >> 4) << 2;
#pragma unroll
    for (int m = 0; m < 4; ++m) {
        int row = row0 + m * 16 + rl;
        size_t tok = 0;
        if constexpr (MODE == 1) tok = win_to_tok(row);
#pragma unroll
        for (int n = 0; n < 4; ++n) {
            int col = col0 + n * 16 + cq;
            f32x4 v = acc[m][n];
            if constexpr (MODE == 0) {
                u16x4 pk;
#pragma unroll
                for (int r = 0; r < 4; ++r) pk[r] = f2b(v[r]);
                *(u16x4*)&outb[(size_t)row * N + col] = pk;
            } else if constexpr (MODE == 1) {
                size_t o = tok * 384 + col;
                f32x4 rv = *(const f32x4*)&resid[o];
                f32x4 bb = *(const f32x4*)&bias[col];
                f32x4 ov = rv + v + bb;
                *(f32x4*)&outf[o] = ov;
            } else if constexpr (MODE == 2) {
                f32x4 bb = *(const f32x4*)&bias[col];
                float g4[4];
#pragma unroll
                for (int r = 0; r < 4; ++r) {
                    float t2 = v[r] + bb[r];
                    // sigmoid-form GELU: x * sigma(1.702 x)  (max err ~0.02, << budget)
                    g4[r] = t2 / (1.f + __expf(-1.702f * t2));
                }
                int pk = 0;
                pk = __builtin_amdgcn_cvt_pk_fp8_f32(g4[0], g4[1], pk, false);
                pk = __builtin_amdgcn_cvt_pk_fp8_f32(g4[2], g4[3], pk, true);
                *(int*)(outb8 + (size_t)row * N + col) = pk;
            } else {
                size_t o = (size_t)row * N + col;
                f32x4 rv = *(const f32x4*)&resid[o];
                f32x4 bb = *(const f32x4*)&bias[col];
                f32x4 ov = rv + v + bb;
                *(f32x4*)&outf[o] = ov;
            }
        }
    }
}

// ---------------- MFMA attention (swapped operands; O out fp8) ----------------
__global__ __launch_bounds__(256, 2) void attn_kernel(const unsigned short* __restrict__ QKV,
                                                      const float* __restrict__ Btab,
                                                      unsigned char* __restrict__ O8) {
    __shared__ char lds[65536];
    char* Kl = lds;              // [hh][m 64][4 chunks x16B]
    char* Vl = lds + 16384;      // [hh][d 32][8 chunks x16B] (V^T)
    char* Pl = lds + 32768;      // [wave][row 64][8 chunks]

    const int w   = blockIdx.x;
    const int tid = threadIdx.x, wid = tid >> 6, lane = tid & 63;
    const int fr  = lane & 15, kq = lane >> 4;
    const size_t base = (size_t)w * 49 * 1152;
    const int widx = w & 63, wi = widx >> 3, wj = widx & 7;
    const int cls = ((wi == 7) ? 2 : 0) | ((wj == 7) ? 1 : 0);
    const float* tb = Btab + (size_t)cls * 12 * 4096;
    constexpr float SCL = 0.17677669529663687f;

    for (int R = 0; R < 3; ++R) {
        if (R) __syncthreads();
        {
            f32x4 z = {};
#pragma unroll
            for (int j = 0; j < 8; ++j) *(f32x4*)(lds + j * 4096 + tid * 16) = z;
        }
        __syncthreads();
        {
            int hh = tid >> 6, h = R * 4 + hh;
#pragma unroll
            for (int it = 0; it < 4; ++it) {
                int i = (tid & 63) + it * 64;
                if (i < 196) {
                    int m = i >> 2, c = i & 3;
                    u16x8 kv = *(const u16x8*)&QKV[base + (size_t)m * 1152 + 384 + h * 32 + c * 8];
                    *(u16x8*)(Kl + hh * 4096 + m * 64 + (c ^ ((m >> 1) & 3)) * 16) = kv;
                    u16x8 vv = *(const u16x8*)&QKV[base + (size_t)m * 1152 + 768 + h * 32 + c * 8];
#pragma unroll
                    for (int j = 0; j < 8; ++j) {
                        int d = c * 8 + j;
                        *(unsigned short*)(Vl + hh * 4096 + d * 128 +
                                           (((m >> 3) ^ (d & 7)) * 16) + (m & 7) * 2) = vv[j];
                    }
                }
            }
        }
        __syncthreads();

        const int h = R * 4 + wid;
        const float* tbh = tb + h * 4096;

        bf16x8 aq[4], bk[4];
#pragma unroll
        for (int mi = 0; mi < 4; ++mi) {
            int row = mi * 16 + fr; if (row > 48) row = 48;
            aq[mi] = *(const bf16x8*)&QKV[base + (size_t)row * 1152 + h * 32 + kq * 8];
        }
#pragma unroll
        for (int ni = 0; ni < 4; ++ni) {
            int rk = ni * 16 + fr;
            bk[ni] = *(const bf16x8*)(Kl + wid * 4096 + rk * 64 + ((kq ^ ((rk >> 1) & 3)) * 16));
        }
        f32x4 s[4][4] = {};
#pragma unroll
        for (int mi = 0; mi < 4; ++mi)
#pragma unroll
            for (int ni = 0; ni < 4; ++ni)
                s[mi][ni] = __builtin_amdgcn_mfma_f32_16x16x32_bf16(bk[ni], aq[mi], s[mi][ni], 0, 0, 0);

        float linv_[4];
#pragma unroll
        for (int mi = 0; mi < 4; ++mi) {
            int row = mi * 16 + fr;
            const float* tr = tbh + row * 64 + kq * 4;
            f32x4 sv[4];
            float mx = -1e30f;
#pragma unroll
            for (int ni = 0; ni < 4; ++ni) {
                f32x4 bb = *(const f32x4*)&tr[ni * 16];
                sv[ni] = s[mi][ni] * SCL + bb;
                mx = fmaxf(mx, fmaxf(fmaxf(sv[ni][0], sv[ni][1]), fmaxf(sv[ni][2], sv[ni][3])));
            }
            mx = fmaxf(mx, __shfl_xor(mx, 16, 64));
            mx = fmaxf(mx, __shfl_xor(mx, 32, 64));
            float sm = 0.f;
#pragma unroll
            for (int ni = 0; ni < 4; ++ni)
#pragma unroll
                for (int r = 0; r < 4; ++r) { sv[ni][r] = __expf(sv[ni][r] - mx); sm += sv[ni][r]; }
            sm += __shfl_xor(sm, 16, 64);
            sm += __shfl_xor(sm, 32, 64);
            linv_[mi] = 1.f / sm;
#pragma unroll
            for (int ni = 0; ni < 4; ++ni) {
                int colb = ni * 16 + kq * 4;
                int phys = (colb >> 3) ^ (row & 7);
                u16x4 pk;
#pragma unroll
                for (int r = 0; r < 4; ++r) pk[r] = f2b(sv[ni][r]);
                *(u16x4*)(Pl + wid * 8192 + row * 128 + phys * 16 + (colb & 7) * 2) = pk;
            }
        }
        asm volatile("s_waitcnt lgkmcnt(0)" ::: "memory");
        __builtin_amdgcn_sched_barrier(0);

        f32x4 oacc[4][2] = {};
#pragma unroll
        for (int sl = 0; sl < 2; ++sl) {
            bf16x8 bv[2];
#pragma unroll
            for (int ni = 0; ni < 2; ++ni) {
                int d = ni * 16 + fr;
                bv[ni] = *(const bf16x8*)(Vl + wid * 4096 + d * 128 + (((sl * 4 + kq) ^ (d & 7)) * 16));
            }
#pragma unroll
            for (int mi = 0; mi < 4; ++mi) {
                int row = mi * 16 + fr;
                bf16x8 ap = *(const bf16x8*)(Pl + wid * 8192 + row * 128 + (((sl * 4 + kq) ^ (row & 7)) * 16));
#pragma unroll
                for (int ni = 0; ni < 2; ++ni)
                    oacc[mi][ni] = __builtin_amdgcn_mfma_f32_16x16x32_bf16(bv[ni], ap, oacc[mi][ni], 0, 0, 0);
            }
        }

#pragma unroll
        for (int mi = 0; mi < 4; ++mi) {
            int row = mi * 16 + fr;
            if (row < 49) {
                float li = linv_[mi];
                unsigned char* op = O8 + (size_t)(w * 49 + row) * 384 + h * 32 + kq * 4;
#pragma unroll
                for (int ni = 0; ni < 2; ++ni) {
                    int pk = 0;
                    pk = __builtin_amdgcn_cvt_pk_fp8_f32(oacc[mi][ni][0] * li, oacc[mi][ni][1] * li, pk, false);
                    pk = __builtin_amdgcn_cvt_pk_fp8_f32(oacc[mi][ni][2] * li, oacc[mi][ni][3] * li, pk, true);
                    *(int*)(op + ni * 16) = pk;
                }
            }
        }
    }
}

extern "C" void kernel_launch(void* const* d_in, const int* in_sizes, int n_in,
                              void* d_out, int out_size, void* d_ws, size_t ws_size,
                              hipStream_t stream) {
    const float* x     = (const float*)d_in[0];
    const int*   rel   = (const int*)  d_in[3];
    const float* rpb   = (const float*)d_in[4];
    const float* qkvw  = (const float*)d_in[5];
    const float* projw = (const float*)d_in[6];
    const float* projb = (const float*)d_in[7];
    const float* n1g   = (const float*)d_in[8];
    const float* n1b   = (const float*)d_in[9];
    const float* n2g   = (const float*)d_in[10];
    const float* n2b   = (const float*)d_in[11];
    const float* w1    = (const float*)d_in[12];
    const float* b1    = (const float*)d_in[13];
    const float* w2    = (const float*)d_in[14];
    const float* b2    = (const float*)d_in[15];
    float* out = (float*)d_out;

    const int T = in_sizes[0] / 384;   // 100352

    char* ws = (char*)d_ws;
    size_t off = 0;
    auto alloc = [&](size_t bytes) {
        char* p = ws + off;
        off += (bytes + 255) & ~(size_t)255;
        return p;
    };
    unsigned char* Wq8  = (unsigned char*)alloc((size_t)1152 * 384);
    unsigned char* Wp8  = (unsigned char*)alloc((size_t)384 * 384);
    unsigned char* W18  = (unsigned char*)alloc((size_t)1536 * 384);
    unsigned char* W28  = (unsigned char*)alloc((size_t)384 * 1536);
    float*         Btab = (float*)       alloc((size_t)4 * 12 * 4096 * 4);
    unsigned char* slotA = (unsigned char*)alloc((size_t)T * 384);        // X1_8 -> O8 -> X2_8
    unsigned char* slotB = (unsigned char*)alloc((size_t)T * 1152 * 2);   // QKV bf16 -> F8

    unsigned char*  X1  = slotA;
    unsigned char*  O8  = slotA;
    unsigned char*  X2  = slotA;
    unsigned short* QKV = (unsigned short*)slotB;
    unsigned char*  F8  = slotB;
    float*          Hh  = out;

    wprep8<<<dim3((1152 * 384 + 255) / 256), 256, 0, stream>>>(qkvw, Wq8, 384, 1152);
    wprep8<<<dim3((384 * 384 + 255) / 256),  256, 0, stream>>>(projw, Wp8, 384, 384);
    wprep8<<<dim3((384 * 1536 + 255) / 256), 256, 0, stream>>>(w1, W18, 384, 1536);
    wprep8<<<dim3((1536 * 384 + 255) / 256), 256, 0, stream>>>(w2, W28, 1536, 384);
    btab_build<<<dim3((4 * 12 * 4096 + 255) / 256), 256, 0, stream>>>(rel, rpb, Btab);

    // LN1 + shifted-window gather -> X1 (fp8, window-token order)
    ln_kernel<1><<<dim3(T / 4), 256, 0, stream>>>(x, n1g, n1b, X1, T);
    // QKV projection (fp8 in, bf16 out; two-barrier, DEPTH=1)
    gemm_f8_kernel<0, 2, 1, 0, 4><<<dim3((T / 128) * (1152 / 128)), 256, 0, stream>>>(
        X1, Wq8, T, 1152, 384, nullptr, nullptr, nullptr, QKV, nullptr);
    // MFMA windowed attention (reads QKV bf16, writes O8 fp8)
    attn_kernel<<<dim3(T / 49), 256, 0, stream>>>(QKV, Btab, O8);
    // proj + bias + un-window/un-roll + residual -> Hh (= d_out, fp32)
    gemm_f8_kernel<1, 2, 1, 0, 4><<<dim3((T / 128) * (384 / 128)), 256, 0, stream>>>(
        O8, Wp8, T, 384, 384, projb, x, nullptr, nullptr, Hh);
    // LN2 -> X2 (fp8, overwrites slotA)
    ln_kernel<0><<<dim3(T / 4), 256, 0, stream>>>(Hh, n2g, n2b, X2, T);
    // FFN1 + bias + sigmoid-GELU -> F8 (fp8, overwrites slotB)
    gemm_f8_kernel<2, 2, 1, 0, 4><<<dim3((T / 128) * (1536 / 128)), 256, 0, stream>>>(
        X2, W18, T, 1536, 384, b1, nullptr, F8, nullptr, nullptr);
    // FFN2 + bias + residual -> out (fp32, in-place RMW; single-barrier NBUF=4/DEPTH=2)
    gemm_f8_kernel<3, 4, 2, 1, 2><<<dim3((T / 128) * (384 / 128)), 256, 0, stream>>>(
        F8, W28, T, 384, 1536, b2, Hh, nullptr, nullptr, out);
}

// Round 17
// 678.950 us; speedup vs baseline: 1.4803x; 1.0254x over previous
//
#include <hip/hip_runtime.h>

#define DEV __device__ __forceinline__

typedef __bf16 bf16x8 __attribute__((ext_vector_type(8)));
typedef float  f32x4  __attribute__((ext_vector_type(4)));
typedef unsigned short u16x8 __attribute__((ext_vector_type(8)));
typedef unsigned short u16x4 __attribute__((ext_vector_type(4)));
typedef long  longx2 __attribute__((ext_vector_type(2)));

DEV float b2f(unsigned short u) {
    unsigned int t = ((unsigned int)u) << 16;
    return __uint_as_float(t);
}
DEV unsigned short f2b(float f) {
    unsigned int u = __float_as_uint(f);
    unsigned int r = (u + 0x7FFFu + ((u >> 16) & 1u)) >> 16;
    return (unsigned short)r;
}
DEV unsigned char f2f8(float f) {
    return (unsigned char)(__builtin_amdgcn_cvt_pk_fp8_f32(f, f, 0, false) & 0xff);
}

// k-interleaved fp8 file layout: within each 64B K-block, slot order {0,4,1,5,2,6,3,7}
// -> file 16B chunk c holds k-slots {c, c+4} (ks=0/ks=1 operands for lane kq).
DEV int kpos(int c) {
    int s = (c >> 3) & 7;
    return (c & ~63) | ((((s & 3) << 1) | (s >> 2)) << 3) | (c & 7);
}

DEV void gload_lds16(const void* g, void* l) {
    __builtin_amdgcn_global_load_lds(
        (const __attribute__((address_space(1))) void*)g,
        (__attribute__((address_space(3))) void*)l, 16, 0, 0);
}

// dest window-row -> source/dest token index (roll by SS=3, window 7x7, 56x56, 64 win/batch)
DEV size_t win_to_tok(int row) {
    int w = row / 49, t = row - w * 49;
    int b  = w >> 6, widx = w & 63;
    int wi = widx >> 3, wj = widx & 7;
    int ti = t / 7, tj = t - ti * 7;
    int hh = wi * 7 + ti + 3; if (hh >= 56) hh -= 56;
    int ww = wj * 7 + tj + 3; if (ww >= 56) ww -= 56;
    return (size_t)b * 3136 + (size_t)hh * 56 + ww;
}

// ---------------- weight prep: fp32 [K][N] -> fp8 e4m3 [N][K] (k-interleaved) ----------------
__global__ void wprep8(const float* __restrict__ src, unsigned char* __restrict__ dst,
                       int K, int N) {
    int idx = blockIdx.x * 256 + threadIdx.x;
    if (idx >= K * N) return;
    int k = idx / N, n = idx - k * N;
    dst[(size_t)n * K + kpos(k)] = f2f8(src[idx]);
}

// ---------------- bias table: [cls 4][h 12][row 64][col 64] fp32 ----------------
__global__ void btab_build(const int* __restrict__ rel_idx, const float* __restrict__ rpb,
                           float* __restrict__ tab) {
    int idx = blockIdx.x * 256 + threadIdx.x;
    if (idx >= 4 * 12 * 64 * 64) return;
    int col = idx & 63, row = (idx >> 6) & 63;
    int h = (idx >> 12) % 12, cls = idx / (12 * 4096);
    float v;
    if (row >= 49 || col >= 49) {
        v = -10000.f;
    } else {
        v = rpb[rel_idx[row * 49 + col] * 12 + h];
        int ti = row / 7, tj = row - (row / 7) * 7;
        int si = col / 7, sj = col - (col / 7) * 7;
        int lq = ((cls & 2) ? (ti < 4 ? 1 : 2) : 0) * 3 + ((cls & 1) ? (tj < 4 ? 1 : 2) : 0);
        int lk = ((cls & 2) ? (si < 4 ? 1 : 2) : 0) * 3 + ((cls & 1) ? (sj < 4 ? 1 : 2) : 0);
        if (lq != lk) v -= 100.f;
    }
    tab[idx] = v;
}

// ---------------- LayerNorm (+optional gather), fp32 -> fp8 (k-interleaved) ----------------
template <int REMAP>
__global__ __launch_bounds__(256) void ln_kernel(const float* __restrict__ x,
                                                 const float* __restrict__ g,
                                                 const float* __restrict__ b,
                                                 unsigned char* __restrict__ out,
                                                 int rows) {
    int r = blockIdx.x * 4 + (threadIdx.x >> 6);
    int lane = threadIdx.x & 63;
    if (r >= rows) return;
    size_t src = REMAP ? win_to_tok(r) : (size_t)r;
    const float* xp = x + src * 384;
    float v[6];
    float s = 0.f;
#pragma unroll
    for (int i = 0; i < 6; ++i) { v[i] = xp[i * 64 + lane]; s += v[i]; }
#pragma unroll
    for (int off = 32; off; off >>= 1) s += __shfl_xor(s, off, 64);
    float mu = s * (1.f / 384.f);
    float q = 0.f;
#pragma unroll
    for (int i = 0; i < 6; ++i) { float d = v[i] - mu; q += d * d; }
#pragma unroll
    for (int off = 32; off; off >>= 1) q += __shfl_xor(q, off, 64);
    float inv = rsqrtf(q * (1.f / 384.f) + 1e-5f);
    unsigned char* op = out + (size_t)r * 384;
#pragma unroll
    for (int i = 0; i < 6; ++i) {
        int c = i * 64 + lane;
        op[kpos(c)] = f2f8((v[i] - mu) * inv * g[c] + b[c]);
    }
}

// ---------------- fp8 GEMM: C[M][N] = A8[M][K] x Bt8[N][K], BK=64, b128 fragments ----------------
// A/Bt in k-interleaved layout; stage = 16B chunk-XOR (phys chunk = c ^ ((row>>1)&3), linear dest);
// read = ONE ds_read_b128 per fragment at chunk (kq ^ ((row>>1)&3)) -> proven-zero-conflict pattern.
// SB=0: two-barrier ring | SB=1: single-barrier ring (NBUF>=DEPTH+2).
// MODE 0: out bf16 (QKV) | 1: resid+C+bias remap fp32 (proj)
// MODE 2: fp8 k-interleaved = gelu_sigmoid(C+bias) (FFN1) | 3: resid+C+bias fp32 (FFN2)
template <int MODE, int NBUF, int DEPTH, int SB, int MINW>
__global__ __launch_bounds__(256, MINW) void gemm_f8_kernel(const unsigned char* __restrict__ A,
                                                            const unsigned char* __restrict__ Bt,
                                                            int M, int N, int K,
                                                            const float* __restrict__ bias,
                                                            const float* __restrict__ resid,
                                                            unsigned char* __restrict__ outb8,
                                                            unsigned short* __restrict__ outb,
                                                            float* __restrict__ outf) {
    static_assert(SB ? (NBUF >= DEPTH + 2) : (NBUF >= DEPTH + 1), "ring too small");
    __shared__ unsigned char As[NBUF][128 * 64];   // 8 KB each
    __shared__ unsigned char Bs[NBUF][128 * 64];
    const int tid = threadIdx.x;
    const int wid = tid >> 6, lane = tid & 63;
    const int ntile = N >> 7;

    int bid = blockIdx.x;
    int nwg = gridDim.x;
    int swb = ((nwg & 7) == 0) ? ((bid & 7) * (nwg >> 3) + (bid >> 3)) : bid;
    const int mt = swb / ntile, nt = swb - mt * ntile;
    const int wr = wid >> 1, wc = wid & 1;

    f32x4 acc[4][4] = {};

    const unsigned char* Abase = A  + (size_t)(mt * 128) * K;
    const unsigned char* Bbase = Bt + (size_t)(nt * 128) * K;

    auto stage = [&](int buf, int k0) {
#pragma unroll
        for (int j = 0; j < 2; ++j) {
            int r  = j * 64 + (tid >> 2);
            int gp = (tid & 3) ^ ((r >> 1) & 3);     // pre-swizzled global 16B chunk
            gload_lds16(Abase + (size_t)r * K + k0 + gp * 16, &As[buf][j * 4096 + tid * 16]);
            gload_lds16(Bbase + (size_t)r * K + k0 + gp * 16, &Bs[buf][j * 4096 + tid * 16]);
        }
    };

    const int fr = lane & 15, kq = lane >> 4;
    const int rowA = wr * 64 + fr;
    const int rowB = wc * 64 + fr;
    const int cb = (kq ^ ((fr >> 1) & 3)) << 4;      // physical chunk byte offset

    const int nk = K >> 6;   // BK=64
    stage(0, 0);
    if (DEPTH >= 2 && nk > 1) stage(1, 64);

    for (int t = 0; t < nk; ++t) {
        const int cur = t % NBUF;
        if (t + DEPTH < nk) {
            stage((t + DEPTH) % NBUF, (t + DEPTH) << 6);
            if constexpr (DEPTH == 1) {
                asm volatile("s_waitcnt vmcnt(4)" ::: "memory");
            } else {
                asm volatile("s_waitcnt vmcnt(8)" ::: "memory");
            }
        } else if (DEPTH >= 2 && t + 1 < nk) {
            asm volatile("s_waitcnt vmcnt(4)" ::: "memory");
        } else {
            asm volatile("s_waitcnt vmcnt(0)" ::: "memory");
        }
        __builtin_amdgcn_s_barrier();   // tile t resident for every wave

        longx2 a[4], b[4];
#pragma unroll
        for (int m = 0; m < 4; ++m)
            a[m] = *(const longx2*)(&As[cur][(rowA + m * 16) * 64 + cb]);
#pragma unroll
        for (int n = 0; n < 4; ++n)
            b[n] = *(const longx2*)(&Bs[cur][(rowB + n * 16) * 64 + cb]);
#pragma unroll
        for (int ks = 0; ks < 2; ++ks)
#pragma unroll
            for (int m = 0; m < 4; ++m)
#pragma unroll
                for (int n = 0; n < 4; ++n)
                    acc[m][n] = __builtin_amdgcn_mfma_f32_16x16x32_fp8_fp8(b[n][ks], a[m][ks], acc[m][n], 0, 0, 0);

        asm volatile("s_waitcnt lgkmcnt(0)" ::: "memory");
        if constexpr (SB == 0) __builtin_amdgcn_s_barrier();
    }

    const int row0 = mt * 128 + wr * 64;
    const int col0 = nt * 128 + wc * 64;
    const int rl = lane & 15;
    const int cq = (lane >> 4) << 2;
#pragma unroll
    for (int m = 0; m < 4; ++m) {
        int row = row0 + m * 16 + rl;
        size_t tok = 0;
        if constexpr (MODE == 1) tok = win_to_tok(row);
#pragma unroll
        for (int n = 0; n < 4; ++n) {
            int col = col0 + n * 16 + cq;
            f32x4 v = acc[m][n];
            if constexpr (MODE == 0) {
                u16x4 pk;
#pragma unroll
                for (int r = 0; r < 4; ++r) pk[r] = f2b(v[r]);
                *(u16x4*)&outb[(size_t)row * N + col] = pk;
            } else if constexpr (MODE == 1) {
                size_t o = tok * 384 + col;
                f32x4 rv = *(const f32x4*)&resid[o];
                f32x4 bb = *(const f32x4*)&bias[col];
                f32x4 ov = rv + v + bb;
                *(f32x4*)&outf[o] = ov;
            } else if constexpr (MODE == 2) {
                f32x4 bb = *(const f32x4*)&bias[col];
                float g4[4];
#pragma unroll
                for (int r = 0; r < 4; ++r) {
                    float t2 = v[r] + bb[r];
                    g4[r] = t2 / (1.f + __expf(-1.702f * t2));   // sigmoid-GELU
                }
                int pk = 0;
                pk = __builtin_amdgcn_cvt_pk_fp8_f32(g4[0], g4[1], pk, false);
                pk = __builtin_amdgcn_cvt_pk_fp8_f32(g4[2], g4[3], pk, true);
                *(int*)(outb8 + (size_t)row * N + kpos(col)) = pk;   // k-interleaved store
            } else {
                size_t o = (size_t)row * N + col;
                f32x4 rv = *(const f32x4*)&resid[o];
                f32x4 bb = *(const f32x4*)&bias[col];
                f32x4 ov = rv + v + bb;
                *(f32x4*)&outf[o] = ov;
            }
        }
    }
}

// ---------------- MFMA attention (swapped operands; O out fp8 k-interleaved) ----------------
__global__ __launch_bounds__(256, 2) void attn_kernel(const unsigned short* __restrict__ QKV,
                                                      const float* __restrict__ Btab,
                                                      unsigned char* __restrict__ O8) {
    __shared__ char lds[65536];
    char* Kl = lds;              // [hh][m 64][4 chunks x16B]
    char* Vl = lds + 16384;      // [hh][d 32][8 chunks x16B] (V^T)
    char* Pl = lds + 32768;      // [wave][row 64][8 chunks]

    const int w   = blockIdx.x;
    const int tid = threadIdx.x, wid = tid >> 6, lane = tid & 63;
    const int fr  = lane & 15, kq = lane >> 4;
    const size_t base = (size_t)w * 49 * 1152;
    const int widx = w & 63, wi = widx >> 3, wj = widx & 7;
    const int cls = ((wi == 7) ? 2 : 0) | ((wj == 7) ? 1 : 0);
    const float* tb = Btab + (size_t)cls * 12 * 4096;
    constexpr float SCL = 0.17677669529663687f;

    for (int R = 0; R < 3; ++R) {
        if (R) __syncthreads();
        {
            f32x4 z = {};
#pragma unroll
            for (int j = 0; j < 8; ++j) *(f32x4*)(lds + j * 4096 + tid * 16) = z;
        }
        __syncthreads();
        {
            int hh = tid >> 6, h = R * 4 + hh;
#pragma unroll
            for (int it = 0; it < 4; ++it) {
                int i = (tid & 63) + it * 64;
                if (i < 196) {
                    int m = i >> 2, c = i & 3;
                    u16x8 kv = *(const u16x8*)&QKV[base + (size_t)m * 1152 + 384 + h * 32 + c * 8];
                    *(u16x8*)(Kl + hh * 4096 + m * 64 + (c ^ ((m >> 1) & 3)) * 16) = kv;
                    u16x8 vv = *(const u16x8*)&QKV[base + (size_t)m * 1152 + 768 + h * 32 + c * 8];
#pragma unroll
                    for (int j = 0; j < 8; ++j) {
                        int d = c * 8 + j;
                        *(unsigned short*)(Vl + hh * 4096 + d * 128 +
                                           (((m >> 3) ^ (d & 7)) * 16) + (m & 7) * 2) = vv[j];
                    }
                }
            }
        }
        __syncthreads();

        const int h = R * 4 + wid;
        const float* tbh = tb + h * 4096;

        bf16x8 aq[4], bk[4];
#pragma unroll
        for (int mi = 0; mi < 4; ++mi) {
            int row = mi * 16 + fr; if (row > 48) row = 48;
            aq[mi] = *(const bf16x8*)&QKV[base + (size_t)row * 1152 + h * 32 + kq * 8];
        }
#pragma unroll
        for (int ni = 0; ni < 4; ++ni) {
            int rk = ni * 16 + fr;
            bk[ni] = *(const bf16x8*)(Kl + wid * 4096 + rk * 64 + ((kq ^ ((rk >> 1) & 3)) * 16));
        }
        f32x4 s[4][4] = {};
#pragma unroll
        for (int mi = 0; mi < 4; ++mi)
#pragma unroll
            for (int ni = 0; ni < 4; ++ni)
                s[mi][ni] = __builtin_amdgcn_mfma_f32_16x16x32_bf16(bk[ni], aq[mi], s[mi][ni], 0, 0, 0);

        float linv_[4];
#pragma unroll
        for (int mi = 0; mi < 4; ++mi) {
            int row = mi * 16 + fr;
            const float* tr = tbh + row * 64 + kq * 4;
            f32x4 sv[4];
            float mx = -1e30f;
#pragma unroll
            for (int ni = 0; ni < 4; ++ni) {
                f32x4 bb = *(const f32x4*)&tr[ni * 16];
                sv[ni] = s[mi][ni] * SCL + bb;
                mx = fmaxf(mx, fmaxf(fmaxf(sv[ni][0], sv[ni][1]), fmaxf(sv[ni][2], sv[ni][3])));
            }
            mx = fmaxf(mx, __shfl_xor(mx, 16, 64));
            mx = fmaxf(mx, __shfl_xor(mx, 32, 64));
            float sm = 0.f;
#pragma unroll
            for (int ni = 0; ni < 4; ++ni)
#pragma unroll
                for (int r = 0; r < 4; ++r) { sv[ni][r] = __expf(sv[ni][r] - mx); sm += sv[ni][r]; }
            sm += __shfl_xor(sm, 16, 64);
            sm += __shfl_xor(sm, 32, 64);
            linv_[mi] = 1.f / sm;
#pragma unroll
            for (int ni = 0; ni < 4; ++ni) {
                int colb = ni * 16 + kq * 4;
                int phys = (colb >> 3) ^ (row & 7);
                u16x4 pk;
#pragma unroll
                for (int r = 0; r < 4; ++r) pk[r] = f2b(sv[ni][r]);
                *(u16x4*)(Pl + wid * 8192 + row * 128 + phys * 16 + (colb & 7) * 2) = pk;
            }
        }
        asm volatile("s_waitcnt lgkmcnt(0)" ::: "memory");
        __builtin_amdgcn_sched_barrier(0);

        f32x4 oacc[4][2] = {};
#pragma unroll
        for (int sl = 0; sl < 2; ++sl) {
            bf16x8 bv[2];
#pragma unroll
            for (int ni = 0; ni < 2; ++ni) {
                int d = ni * 16 + fr;
                bv[ni] = *(const bf16x8*)(Vl + wid * 4096 + d * 128 + (((sl * 4 + kq) ^ (d & 7)) * 16));
            }
#pragma unroll
            for (int mi = 0; mi < 4; ++mi) {
                int row = mi * 16 + fr;
                bf16x8 ap = *(const bf16x8*)(Pl + wid * 8192 + row * 128 + (((sl * 4 + kq) ^ (row & 7)) * 16));
#pragma unroll
                for (int ni = 0; ni < 2; ++ni)
                    oacc[mi][ni] = __builtin_amdgcn_mfma_f32_16x16x32_bf16(bv[ni], ap, oacc[mi][ni], 0, 0, 0);
            }
        }

#pragma unroll
        for (int mi = 0; mi < 4; ++mi) {
            int row = mi * 16 + fr;
            if (row < 49) {
                float li = linv_[mi];
                unsigned char* opb = O8 + (size_t)(w * 49 + row) * 384;
#pragma unroll
                for (int ni = 0; ni < 2; ++ni) {
                    int c = h * 32 + ni * 16 + kq * 4;
                    int pk = 0;
                    pk = __builtin_amdgcn_cvt_pk_fp8_f32(oacc[mi][ni][0] * li, oacc[mi][ni][1] * li, pk, false);
                    pk = __builtin_amdgcn_cvt_pk_fp8_f32(oacc[mi][ni][2] * li, oacc[mi][ni][3] * li, pk, true);
                    *(int*)(opb + kpos(c)) = pk;   // k-interleaved store
                }
            }
        }
    }
}

extern "C" void kernel_launch(void* const* d_in, const int* in_sizes, int n_in,
                              void* d_out, int out_size, void* d_ws, size_t ws_size,
                              hipStream_t stream) {
    const float* x     = (const float*)d_in[0];
    const int*   rel   = (const int*)  d_in[3];
    const float* rpb   = (const float*)d_in[4];
    const float* qkvw  = (const float*)d_in[5];
    const float* projw = (const float*)d_in[6];
    const float* projb = (const float*)d_in[7];
    const float* n1g   = (const float*)d_in[8];
    const float* n1b   = (const float*)d_in[9];
    const float* n2g   = (const float*)d_in[10];
    const float* n2b   = (const float*)d_in[11];
    const float* w1    = (const float*)d_in[12];
    const float* b1    = (const float*)d_in[13];
    const float* w2    = (const float*)d_in[14];
    const float* b2    = (const float*)d_in[15];
    float* out = (float*)d_out;

    const int T = in_sizes[0] / 384;   // 100352

    char* ws = (char*)d_ws;
    size_t off = 0;
    auto alloc = [&](size_t bytes) {
        char* p = ws + off;
        off += (bytes + 255) & ~(size_t)255;
        return p;
    };
    unsigned char* Wq8  = (unsigned char*)alloc((size_t)1152 * 384);
    unsigned char* Wp8  = (unsigned char*)alloc((size_t)384 * 384);
    unsigned char* W18  = (unsigned char*)alloc((size_t)1536 * 384);
    unsigned char* W28  = (unsigned char*)alloc((size_t)384 * 1536);
    float*         Btab = (float*)       alloc((size_t)4 * 12 * 4096 * 4);
    unsigned char* slotA = (unsigned char*)alloc((size_t)T * 384);        // X1_8 -> O8 -> X2_8
    unsigned char* slotB = (unsigned char*)alloc((size_t)T * 1152 * 2);   // QKV bf16 -> F8

    unsigned char*  X1  = slotA;
    unsigned char*  O8  = slotA;
    unsigned char*  X2  = slotA;
    unsigned short* QKV = (unsigned short*)slotB;
    unsigned char*  F8  = slotB;
    float*          Hh  = out;

    wprep8<<<dim3((1152 * 384 + 255) / 256), 256, 0, stream>>>(qkvw, Wq8, 384, 1152);
    wprep8<<<dim3((384 * 384 + 255) / 256),  256, 0, stream>>>(projw, Wp8, 384, 384);
    wprep8<<<dim3((384 * 1536 + 255) / 256), 256, 0, stream>>>(w1, W18, 384, 1536);
    wprep8<<<dim3((1536 * 384 + 255) / 256), 256, 0, stream>>>(w2, W28, 1536, 384);
    btab_build<<<dim3((4 * 12 * 4096 + 255) / 256), 256, 0, stream>>>(rel, rpb, Btab);

    // LN1 + shifted-window gather -> X1 (fp8 k-interleaved, window-token order)
    ln_kernel<1><<<dim3(T / 4), 256, 0, stream>>>(x, n1g, n1b, X1, T);
    // QKV projection (fp8 in, bf16 out; two-barrier, DEPTH=1)
    gemm_f8_kernel<0, 2, 1, 0, 4><<<dim3((T / 128) * (1152 / 128)), 256, 0, stream>>>(
        X1, Wq8, T, 1152, 384, nullptr, nullptr, nullptr, QKV, nullptr);
    // MFMA windowed attention (reads QKV bf16, writes O8 fp8 k-interleaved)
    attn_kernel<<<dim3(T / 49), 256, 0, stream>>>(QKV, Btab, O8);
    // proj + bias + un-window/un-roll + residual -> Hh (= d_out, fp32)
    gemm_f8_kernel<1, 2, 1, 0, 4><<<dim3((T / 128) * (384 / 128)), 256, 0, stream>>>(
        O8, Wp8, T, 384, 384, projb, x, nullptr, nullptr, Hh);
    // LN2 -> X2 (fp8 k-interleaved, overwrites slotA)
    ln_kernel<0><<<dim3(T / 4), 256, 0, stream>>>(Hh, n2g, n2b, X2, T);
    // FFN1 + bias + sigmoid-GELU -> F8 (fp8 k-interleaved, overwrites slotB)
    gemm_f8_kernel<2, 2, 1, 0, 4><<<dim3((T / 128) * (1536 / 128)), 256, 0, stream>>>(
        X2, W18, T, 1536, 384, b1, nullptr, F8, nullptr, nullptr);
    // FFN2 + bias + residual -> out (fp32, in-place RMW; single-barrier NBUF=4/DEPTH=2)
    gemm_f8_kernel<3, 4, 2, 1, 2><<<dim3((T / 128) * (384 / 128)), 256, 0, stream>>>(
        F8, W28, T, 384, 1536, b2, Hh, nullptr, nullptr, out);
}

// Round 19
// 662.129 us; speedup vs baseline: 1.5179x; 1.0254x over previous
//
#include <hip/hip_runtime.h>

#define DEV __device__ __forceinline__

typedef __bf16 bf16x8 __attribute__((ext_vector_type(8)));
typedef float  f32x4  __attribute__((ext_vector_type(4)));
typedef unsigned short u16x8 __attribute__((ext_vector_type(8)));
typedef unsigned short u16x4 __attribute__((ext_vector_type(4)));
typedef long  longx2 __attribute__((ext_vector_type(2)));

DEV float b2f(unsigned short u) {
    unsigned int t = ((unsigned int)u) << 16;
    return __uint_as_float(t);
}
DEV unsigned short f2b(float f) {
    unsigned int u = __float_as_uint(f);
    unsigned int r = (u + 0x7FFFu + ((u >> 16) & 1u)) >> 16;
    return (unsigned short)r;
}
DEV unsigned char f2f8(float f) {
    return (unsigned char)(__builtin_amdgcn_cvt_pk_fp8_f32(f, f, 0, false) & 0xff);
}

// k-interleaved fp8 file layout (for BK=64 GEMM inputs): within each 64B K-block,
// slot order {0,4,1,5,2,6,3,7} -> file 16B chunk c holds k-slots {c, c+4}.
DEV int kpos(int c) {
    int s = (c >> 3) & 7;
    return (c & ~63) | ((((s & 3) << 1) | (s >> 2)) << 3) | (c & 7);
}

DEV void gload_lds16(const void* g, void* l) {
    __builtin_amdgcn_global_load_lds(
        (const __attribute__((address_space(1))) void*)g,
        (__attribute__((address_space(3))) void*)l, 16, 0, 0);
}

// dest window-row -> source/dest token index (roll by SS=3, window 7x7, 56x56, 64 win/batch)
DEV size_t win_to_tok(int row) {
    int w = row / 49, t = row - w * 49;
    int b  = w >> 6, widx = w & 63;
    int wi = widx >> 3, wj = widx & 7;
    int ti = t / 7, tj = t - ti * 7;
    int hh = wi * 7 + ti + 3; if (hh >= 56) hh -= 56;
    int ww = wj * 7 + tj + 3; if (ww >= 56) ww -= 56;
    return (size_t)b * 3136 + (size_t)hh * 56 + ww;
}

// ---------------- row -> token map (for proj epilogue) ----------------
__global__ void tokmap_build(int* __restrict__ tm, int T) {
    int i = blockIdx.x * 256 + threadIdx.x;
    if (i < T) tm[i] = (int)win_to_tok(i);
}

// ---------------- weight prep: fp32 [K][N] -> fp8 e4m3 [N][K] (k-interleaved) ----------------
__global__ void wprep8(const float* __restrict__ src, unsigned char* __restrict__ dst,
                       int K, int N) {
    int idx = blockIdx.x * 256 + threadIdx.x;
    if (idx >= K * N) return;
    int k = idx / N, n = idx - k * N;
    dst[(size_t)n * K + kpos(k)] = f2f8(src[idx]);
}

// ---------------- bias table: [cls 4][h 12][row 64][col 64] fp32 ----------------
__global__ void btab_build(const int* __restrict__ rel_idx, const float* __restrict__ rpb,
                           float* __restrict__ tab) {
    int idx = blockIdx.x * 256 + threadIdx.x;
    if (idx >= 4 * 12 * 64 * 64) return;
    int col = idx & 63, row = (idx >> 6) & 63;
    int h = (idx >> 12) % 12, cls = idx / (12 * 4096);
    float v;
    if (row >= 49 || col >= 49) {
        v = -10000.f;
    } else {
        v = rpb[rel_idx[row * 49 + col] * 12 + h];
        int ti = row / 7, tj = row - (row / 7) * 7;
        int si = col / 7, sj = col - (col / 7) * 7;
        int lq = ((cls & 2) ? (ti < 4 ? 1 : 2) : 0) * 3 + ((cls & 1) ? (tj < 4 ? 1 : 2) : 0);
        int lk = ((cls & 2) ? (si < 4 ? 1 : 2) : 0) * 3 + ((cls & 1) ? (sj < 4 ? 1 : 2) : 0);
        if (lq != lk) v -= 100.f;
    }
    tab[idx] = v;
}

// ---------------- LayerNorm (+optional gather), fp32 -> fp8 (k-interleaved) ----------------
template <int REMAP>
__global__ __launch_bounds__(256) void ln_kernel(const float* __restrict__ x,
                                                 const float* __restrict__ g,
                                                 const float* __restrict__ b,
                                                 unsigned char* __restrict__ out,
                                                 int rows) {
    int r = blockIdx.x * 4 + (threadIdx.x >> 6);
    int lane = threadIdx.x & 63;
    if (r >= rows) return;
    size_t src = REMAP ? win_to_tok(r) : (size_t)r;
    const float* xp = x + src * 384;
    float v[6];
    float s = 0.f;
#pragma unroll
    for (int i = 0; i < 6; ++i) { v[i] = xp[i * 64 + lane]; s += v[i]; }
#pragma unroll
    for (int off = 32; off; off >>= 1) s += __shfl_xor(s, off, 64);
    float mu = s * (1.f / 384.f);
    float q = 0.f;
#pragma unroll
    for (int i = 0; i < 6; ++i) { float d = v[i] - mu; q += d * d; }
#pragma unroll
    for (int off = 32; off; off >>= 1) q += __shfl_xor(q, off, 64);
    float inv = rsqrtf(q * (1.f / 384.f) + 1e-5f);
    unsigned char* op = out + (size_t)r * 384;
#pragma unroll
    for (int i = 0; i < 6; ++i) {
        int c = i * 64 + lane;
        op[kpos(c)] = f2f8((v[i] - mu) * inv * g[c] + b[c]);
    }
}

// ---------------- fp8 GEMM: C[M][N] = A8[M][K] x Bt8[N][K], BK=64, b128 fragments ----------------
// A/Bt k-interleaved; stage = 16B chunk-XOR (linear dest); read = 1 ds_read_b128/fragment.
// SB=0: two-barrier ring | SB=1: single-barrier ring (NBUF>=DEPTH+2).
// MODE 0: out fp8 PLAIN layout (QKV -> attention) | 1: resid+C+bias via tokmap, fp32 (proj)
// MODE 2: fp8 k-interleaved = gelu(C+bias) (FFN1)  | 3: resid+C+bias fp32 (FFN2)
template <int MODE, int NBUF, int DEPTH, int SB, int MINW>
__global__ __launch_bounds__(256, MINW) void gemm_f8_kernel(const unsigned char* __restrict__ A,
                                                            const unsigned char* __restrict__ Bt,
                                                            int M, int N, int K,
                                                            const float* __restrict__ bias,
                                                            const float* __restrict__ resid,
                                                            const int* __restrict__ tokmap,
                                                            unsigned char* __restrict__ outb8,
                                                            float* __restrict__ outf) {
    static_assert(SB ? (NBUF >= DEPTH + 2) : (NBUF >= DEPTH + 1), "ring too small");
    __shared__ unsigned char As[NBUF][128 * 64];   // 8 KB each
    __shared__ unsigned char Bs[NBUF][128 * 64];
    const int tid = threadIdx.x;
    const int wid = tid >> 6, lane = tid & 63;
    const int ntile = N >> 7;

    int bid = blockIdx.x;
    int nwg = gridDim.x;
    int swb = ((nwg & 7) == 0) ? ((bid & 7) * (nwg >> 3) + (bid >> 3)) : bid;
    const int mt = swb / ntile, nt = swb - mt * ntile;
    const int wr = wid >> 1, wc = wid & 1;

    f32x4 acc[4][4] = {};

    const unsigned char* Abase = A  + (size_t)(mt * 128) * K;
    const unsigned char* Bbase = Bt + (size_t)(nt * 128) * K;

    auto stage = [&](int buf, int k0) {
#pragma unroll
        for (int j = 0; j < 2; ++j) {
            int r  = j * 64 + (tid >> 2);
            int gp = (tid & 3) ^ ((r >> 1) & 3);     // pre-swizzled global 16B chunk
            gload_lds16(Abase + (size_t)r * K + k0 + gp * 16, &As[buf][j * 4096 + tid * 16]);
            gload_lds16(Bbase + (size_t)r * K + k0 + gp * 16, &Bs[buf][j * 4096 + tid * 16]);
        }
    };

    const int fr = lane & 15, kq = lane >> 4;
    const int rowA = wr * 64 + fr;
    const int rowB = wc * 64 + fr;
    const int cb = (kq ^ ((fr >> 1) & 3)) << 4;      // physical chunk byte offset

    const int nk = K >> 6;   // BK=64
    stage(0, 0);
    if (DEPTH >= 2 && nk > 1) stage(1, 64);

    for (int t = 0; t < nk; ++t) {
        const int cur = t % NBUF;
        if (t + DEPTH < nk) {
            stage((t + DEPTH) % NBUF, (t + DEPTH) << 6);
            if constexpr (DEPTH == 1) {
                asm volatile("s_waitcnt vmcnt(4)" ::: "memory");
            } else {
                asm volatile("s_waitcnt vmcnt(8)" ::: "memory");
            }
        } else if (DEPTH >= 2 && t + 1 < nk) {
            asm volatile("s_waitcnt vmcnt(4)" ::: "memory");
        } else {
            asm volatile("s_waitcnt vmcnt(0)" ::: "memory");
        }
        __builtin_amdgcn_s_barrier();   // tile t resident for every wave

        longx2 a[4], b[4];
#pragma unroll
        for (int m = 0; m < 4; ++m)
            a[m] = *(const longx2*)(&As[cur][(rowA + m * 16) * 64 + cb]);
#pragma unroll
        for (int n = 0; n < 4; ++n)
            b[n] = *(const longx2*)(&Bs[cur][(rowB + n * 16) * 64 + cb]);
#pragma unroll
        for (int ks = 0; ks < 2; ++ks)
#pragma unroll
            for (int m = 0; m < 4; ++m)
#pragma unroll
                for (int n = 0; n < 4; ++n)
                    acc[m][n] = __builtin_amdgcn_mfma_f32_16x16x32_fp8_fp8(b[n][ks], a[m][ks], acc[m][n], 0, 0, 0);

        asm volatile("s_waitcnt lgkmcnt(0)" ::: "memory");
        if constexpr (SB == 0) __builtin_amdgcn_s_barrier();
    }

    const int row0 = mt * 128 + wr * 64;
    const int col0 = nt * 128 + wc * 64;
    const int rl = lane & 15;
    const int cq = (lane >> 4) << 2;
#pragma unroll
    for (int m = 0; m < 4; ++m) {
        int row = row0 + m * 16 + rl;
        size_t tok = 0;
        if constexpr (MODE == 1) tok = (size_t)tokmap[row];
#pragma unroll
        for (int n = 0; n < 4; ++n) {
            int col = col0 + n * 16 + cq;
            f32x4 v = acc[m][n];
            if constexpr (MODE == 0) {
                int pk = 0;
                pk = __builtin_amdgcn_cvt_pk_fp8_f32(v[0], v[1], pk, false);
                pk = __builtin_amdgcn_cvt_pk_fp8_f32(v[2], v[3], pk, true);
                *(int*)(outb8 + (size_t)row * N + col) = pk;     // plain layout
            } else if constexpr (MODE == 1) {
                size_t o = tok * 384 + col;
                f32x4 rv = *(const f32x4*)&resid[o];
                f32x4 bb = *(const f32x4*)&bias[col];
                f32x4 ov = rv + v + bb;
                *(f32x4*)&outf[o] = ov;
            } else if constexpr (MODE == 2) {
                f32x4 bb = *(const f32x4*)&bias[col];
                float g4[4];
#pragma unroll
                for (int r = 0; r < 4; ++r) {
                    float t2 = v[r] + bb[r];
                    float e  = __expf(-1.702f * t2);
                    g4[r] = t2 * __builtin_amdgcn_rcpf(1.f + e);   // sigmoid-GELU, rcp not div
                }
                int pk = 0;
                pk = __builtin_amdgcn_cvt_pk_fp8_f32(g4[0], g4[1], pk, false);
                pk = __builtin_amdgcn_cvt_pk_fp8_f32(g4[2], g4[3], pk, true);
                *(int*)(outb8 + (size_t)row * N + kpos(col)) = pk;   // k-interleaved store
            } else {
                size_t o = (size_t)row * N + col;
                f32x4 rv = *(const f32x4*)&resid[o];
                f32x4 bb = *(const f32x4*)&bias[col];
                f32x4 ov = rv + v + bb;
                *(f32x4*)&outf[o] = ov;
            }
        }
    }
}

// ---------------- MFMA attention: fp8 QK^T, bf16 PV; O out fp8 k-interleaved ----------------
__global__ __launch_bounds__(256, 2) void attn_kernel(const unsigned char* __restrict__ QKV8,
                                                      const float* __restrict__ Btab,
                                                      unsigned char* __restrict__ O8) {
    __shared__ char lds[8192 + 16384 + 32768];   // Kl 8K | Vl 16K | Pl 32K = 56 KB
    char* Kl = lds;              // [hh][m 64][4 slots x8B] fp8: hh*2048 + m*32 + slot*8
    char* Vl = lds + 8192;       // [hh][d 32][8 chunks x16B] bf16 V^T
    char* Pl = lds + 24576;      // [wave][row 64][8 chunks x16B] bf16

    const int w   = blockIdx.x;
    const int tid = threadIdx.x, wid = tid >> 6, lane = tid & 63;
    const int fr  = lane & 15, kq = lane >> 4;
    const size_t base = (size_t)w * 49 * 1152;   // byte offset into QKV8
    const int widx = w & 63, wi = widx >> 3, wj = widx & 7;
    const int cls = ((wi == 7) ? 2 : 0) | ((wj == 7) ? 1 : 0);
    const float* tb = Btab + (size_t)cls * 12 * 4096;
    constexpr float SCL = 0.17677669529663687f;

    for (int R = 0; R < 3; ++R) {
        if (R) __syncthreads();
        {   // zero K (8 KB) + V (16 KB) regions
            f32x4 z = {};
#pragma unroll
            for (int j = 0; j < 6; ++j) *(f32x4*)(lds + j * 4096 + tid * 16) = z;
        }
        __syncthreads();
        {   // stage K fp8 (XOR slots) + V as bf16 V^T (constant-selector fp8 unpack)
            int hh = tid >> 6, h = R * 4 + hh;
#pragma unroll
            for (int it = 0; it < 4; ++it) {
                int i = (tid & 63) + it * 64;
                if (i < 196) {
                    int m = i >> 2, c = i & 3;
                    long k8 = *(const long*)(QKV8 + base + (size_t)m * 1152 + 384 + h * 32 + c * 8);
                    int s = c ^ (m & 3) ^ ((m >> 2) & 3);
                    *(long*)(Kl + hh * 2048 + m * 32 + s * 8) = k8;
                    long v8 = *(const long*)(QKV8 + base + (size_t)m * 1152 + 768 + h * 32 + c * 8);
                    int lo = (int)v8, hi = (int)(v8 >> 32);
                    float vf[8];
                    vf[0] = __builtin_amdgcn_cvt_f32_fp8(lo, 0);
                    vf[1] = __builtin_amdgcn_cvt_f32_fp8(lo, 1);
                    vf[2] = __builtin_amdgcn_cvt_f32_fp8(lo, 2);
                    vf[3] = __builtin_amdgcn_cvt_f32_fp8(lo, 3);
                    vf[4] = __builtin_amdgcn_cvt_f32_fp8(hi, 0);
                    vf[5] = __builtin_amdgcn_cvt_f32_fp8(hi, 1);
                    vf[6] = __builtin_amdgcn_cvt_f32_fp8(hi, 2);
                    vf[7] = __builtin_amdgcn_cvt_f32_fp8(hi, 3);
#pragma unroll
                    for (int j = 0; j < 8; ++j) {
                        int d = c * 8 + j;
                        *(unsigned short*)(Vl + hh * 4096 + d * 128 +
                                           (((m >> 3) ^ (d & 7)) * 16) + (m & 7) * 2) = f2b(vf[j]);
                    }
                }
            }
        }
        __syncthreads();

        const int h = R * 4 + wid;
        const float* tbh = tb + h * 4096;

        long aq[4], bk[4];
#pragma unroll
        for (int mi = 0; mi < 4; ++mi) {
            int row = mi * 16 + fr; if (row > 48) row = 48;
            aq[mi] = *(const long*)(QKV8 + base + (size_t)row * 1152 + h * 32 + kq * 8);
        }
#pragma unroll
        for (int ni = 0; ni < 4; ++ni) {
            int rk = ni * 16 + fr;
            bk[ni] = *(const long*)(Kl + wid * 2048 + rk * 32 +
                                    ((kq ^ (rk & 3) ^ ((rk >> 2) & 3)) * 8));
        }
        f32x4 s[4][4] = {};
#pragma unroll
        for (int mi = 0; mi < 4; ++mi)
#pragma unroll
            for (int ni = 0; ni < 4; ++ni)
                s[mi][ni] = __builtin_amdgcn_mfma_f32_16x16x32_fp8_fp8(bk[ni], aq[mi], s[mi][ni], 0, 0, 0);

        float linv_[4];
#pragma unroll
        for (int mi = 0; mi < 4; ++mi) {
            int row = mi * 16 + fr;
            const float* tr = tbh + row * 64 + kq * 4;
            f32x4 sv[4];
            float mx = -1e30f;
#pragma unroll
            for (int ni = 0; ni < 4; ++ni) {
                f32x4 bb = *(const f32x4*)&tr[ni * 16];
                sv[ni] = s[mi][ni] * SCL + bb;
                mx = fmaxf(mx, fmaxf(fmaxf(sv[ni][0], sv[ni][1]), fmaxf(sv[ni][2], sv[ni][3])));
            }
            mx = fmaxf(mx, __shfl_xor(mx, 16, 64));
            mx = fmaxf(mx, __shfl_xor(mx, 32, 64));
            float sm = 0.f;
#pragma unroll
            for (int ni = 0; ni < 4; ++ni)
#pragma unroll
                for (int r = 0; r < 4; ++r) { sv[ni][r] = __expf(sv[ni][r] - mx); sm += sv[ni][r]; }
            sm += __shfl_xor(sm, 16, 64);
            sm += __shfl_xor(sm, 32, 64);
            linv_[mi] = __builtin_amdgcn_rcpf(sm);
#pragma unroll
            for (int ni = 0; ni < 4; ++ni) {
                int colb = ni * 16 + kq * 4;
                int phys = (colb >> 3) ^ (row & 7);
                u16x4 pk;
#pragma unroll
                for (int r = 0; r < 4; ++r) pk[r] = f2b(sv[ni][r]);
                *(u16x4*)(Pl + wid * 8192 + row * 128 + phys * 16 + (colb & 7) * 2) = pk;
            }
        }
        asm volatile("s_waitcnt lgkmcnt(0)" ::: "memory");
        __builtin_amdgcn_sched_barrier(0);

        f32x4 oacc[4][2] = {};
#pragma unroll
        for (int sl = 0; sl < 2; ++sl) {
            bf16x8 bv[2];
#pragma unroll
            for (int ni = 0; ni < 2; ++ni) {
                int d = ni * 16 + fr;
                bv[ni] = *(const bf16x8*)(Vl + wid * 4096 + d * 128 + (((sl * 4 + kq) ^ (d & 7)) * 16));
            }
#pragma unroll
            for (int mi = 0; mi < 4; ++mi) {
                int row = mi * 16 + fr;
                bf16x8 ap = *(const bf16x8*)(Pl + wid * 8192 + row * 128 + (((sl * 4 + kq) ^ (row & 7)) * 16));
#pragma unroll
                for (int ni = 0; ni < 2; ++ni)
                    oacc[mi][ni] = __builtin_amdgcn_mfma_f32_16x16x32_bf16(bv[ni], ap, oacc[mi][ni], 0, 0, 0);
            }
        }

#pragma unroll
        for (int mi = 0; mi < 4; ++mi) {
            int row = mi * 16 + fr;
            if (row < 49) {
                float li = linv_[mi];
                unsigned char* opb = O8 + (size_t)(w * 49 + row) * 384;
#pragma unroll
                for (int ni = 0; ni < 2; ++ni) {
                    int c = h * 32 + ni * 16 + kq * 4;
                    int pk = 0;
                    pk = __builtin_amdgcn_cvt_pk_fp8_f32(oacc[mi][ni][0] * li, oacc[mi][ni][1] * li, pk, false);
                    pk = __builtin_amdgcn_cvt_pk_fp8_f32(oacc[mi][ni][2] * li, oacc[mi][ni][3] * li, pk, true);
                    *(int*)(opb + kpos(c)) = pk;   // k-interleaved store
                }
            }
        }
    }
}

extern "C" void kernel_launch(void* const* d_in, const int* in_sizes, int n_in,
                              void* d_out, int out_size, void* d_ws, size_t ws_size,
                              hipStream_t stream) {
    const float* x     = (const float*)d_in[0];
    const int*   rel   = (const int*)  d_in[3];
    const float* rpb   = (const float*)d_in[4];
    const float* qkvw  = (const float*)d_in[5];
    const float* projw = (const float*)d_in[6];
    const float* projb = (const float*)d_in[7];
    const float* n1g   = (const float*)d_in[8];
    const float* n1b   = (const float*)d_in[9];
    const float* n2g   = (const float*)d_in[10];
    const float* n2b   = (const float*)d_in[11];
    const float* w1    = (const float*)d_in[12];
    const float* b1    = (const float*)d_in[13];
    const float* w2    = (const float*)d_in[14];
    const float* b2    = (const float*)d_in[15];
    float* out = (float*)d_out;

    const int T = in_sizes[0] / 384;   // 100352

    char* ws = (char*)d_ws;
    size_t off = 0;
    auto alloc = [&](size_t bytes) {
        char* p = ws + off;
        off += (bytes + 255) & ~(size_t)255;
        return p;
    };
    unsigned char* Wq8  = (unsigned char*)alloc((size_t)1152 * 384);
    unsigned char* Wp8  = (unsigned char*)alloc((size_t)384 * 384);
    unsigned char* W18  = (unsigned char*)alloc((size_t)1536 * 384);
    unsigned char* W28  = (unsigned char*)alloc((size_t)384 * 1536);
    float*         Btab = (float*)       alloc((size_t)4 * 12 * 4096 * 4);
    int*           Tmap = (int*)         alloc((size_t)T * 4);
    unsigned char* slotA = (unsigned char*)alloc((size_t)T * 384);    // X1_8 -> O8 -> X2_8
    unsigned char* slotB = (unsigned char*)alloc((size_t)T * 1536);   // QKV8 -> F8

    unsigned char* X1   = slotA;
    unsigned char* O8   = slotA;
    unsigned char* X2   = slotA;
    unsigned char* QKV8 = slotB;
    unsigned char* F8   = slotB;
    float*         Hh   = out;

    wprep8<<<dim3((1152 * 384 + 255) / 256), 256, 0, stream>>>(qkvw, Wq8, 384, 1152);
    wprep8<<<dim3((384 * 384 + 255) / 256),  256, 0, stream>>>(projw, Wp8, 384, 384);
    wprep8<<<dim3((384 * 1536 + 255) / 256), 256, 0, stream>>>(w1, W18, 384, 1536);
    wprep8<<<dim3((1536 * 384 + 255) / 256), 256, 0, stream>>>(w2, W28, 1536, 384);
    btab_build<<<dim3((4 * 12 * 4096 + 255) / 256), 256, 0, stream>>>(rel, rpb, Btab);
    tokmap_build<<<dim3((T + 255) / 256), 256, 0, stream>>>(Tmap, T);

    // LN1 + shifted-window gather -> X1 (fp8 k-interleaved)
    ln_kernel<1><<<dim3(T / 4), 256, 0, stream>>>(x, n1g, n1b, X1, T);
    // QKV projection -> QKV8 (fp8, PLAIN layout)
    gemm_f8_kernel<0, 2, 1, 0, 4><<<dim3((T / 128) * (1152 / 128)), 256, 0, stream>>>(
        X1, Wq8, T, 1152, 384, nullptr, nullptr, nullptr, QKV8, nullptr);
    // MFMA windowed attention (fp8 QK^T, bf16 PV) -> O8 (fp8 k-interleaved)
    attn_kernel<<<dim3(T / 49), 256, 0, stream>>>(QKV8, Btab, O8);
    // proj + bias + tokmap remap + residual -> Hh (= d_out, fp32)
    gemm_f8_kernel<1, 2, 1, 0, 4><<<dim3((T / 128) * (384 / 128)), 256, 0, stream>>>(
        O8, Wp8, T, 384, 384, projb, x, Tmap, nullptr, Hh);
    // LN2 -> X2 (fp8 k-interleaved)
    ln_kernel<0><<<dim3(T / 4), 256, 0, stream>>>(Hh, n2g, n2b, X2, T);
    // FFN1 + bias + sigmoid-GELU (rcp) -> F8 (fp8 k-interleaved)
    gemm_f8_kernel<2, 2, 1, 0, 4><<<dim3((T / 128) * (1536 / 128)), 256, 0, stream>>>(
        X2, W18, T, 1536, 384, b1, nullptr, nullptr, F8, nullptr);
    // FFN2 + bias + residual -> out (fp32, in-place RMW; single-barrier NBUF=4/DEPTH=2)
    gemm_f8_kernel<3, 4, 2, 1, 2><<<dim3((T / 128) * (384 / 128)), 256, 0, stream>>>(
        F8, W28, T, 384, 1536, b2, Hh, nullptr, nullptr, out);
}

// Round 20
// 656.402 us; speedup vs baseline: 1.5311x; 1.0087x over previous
//
#include <hip/hip_runtime.h>

#define DEV __device__ __forceinline__

typedef __bf16 bf16x8 __attribute__((ext_vector_type(8)));
typedef float  f32x4  __attribute__((ext_vector_type(4)));
typedef unsigned short u16x8 __attribute__((ext_vector_type(8)));
typedef unsigned short u16x4 __attribute__((ext_vector_type(4)));
typedef long  longx2 __attribute__((ext_vector_type(2)));

DEV float b2f(unsigned short u) {
    unsigned int t = ((unsigned int)u) << 16;
    return __uint_as_float(t);
}
DEV unsigned short f2b(float f) {
    unsigned int u = __float_as_uint(f);
    unsigned int r = (u + 0x7FFFu + ((u >> 16) & 1u)) >> 16;
    return (unsigned short)r;
}
DEV unsigned char f2f8(float f) {
    return (unsigned char)(__builtin_amdgcn_cvt_pk_fp8_f32(f, f, 0, false) & 0xff);
}

// k-interleaved fp8 file layout (for BK=64 GEMM inputs): within each 64B K-block,
// slot order {0,4,1,5,2,6,3,7} -> file 16B chunk c holds k-slots {c, c+4}.
DEV int kpos(int c) {
    int s = (c >> 3) & 7;
    return (c & ~63) | ((((s & 3) << 1) | (s >> 2)) << 3) | (c & 7);
}

DEV void gload_lds16(const void* g, void* l) {
    __builtin_amdgcn_global_load_lds(
        (const __attribute__((address_space(1))) void*)g,
        (__attribute__((address_space(3))) void*)l, 16, 0, 0);
}

// dest window-row -> source/dest token index (roll by SS=3, window 7x7, 56x56, 64 win/batch)
DEV size_t win_to_tok(int row) {
    int w = row / 49, t = row - w * 49;
    int b  = w >> 6, widx = w & 63;
    int wi = widx >> 3, wj = widx & 7;
    int ti = t / 7, tj = t - ti * 7;
    int hh = wi * 7 + ti + 3; if (hh >= 56) hh -= 56;
    int ww = wj * 7 + tj + 3; if (ww >= 56) ww -= 56;
    return (size_t)b * 3136 + (size_t)hh * 56 + ww;
}

// ---------------- row -> token map (for proj epilogue) ----------------
__global__ void tokmap_build(int* __restrict__ tm, int T) {
    int i = blockIdx.x * 256 + threadIdx.x;
    if (i < T) tm[i] = (int)win_to_tok(i);
}

// ---------------- weight prep: fp32 [K][N] -> fp8 e4m3 [N][K] (k-interleaved) ----------------
__global__ void wprep8(const float* __restrict__ src, unsigned char* __restrict__ dst,
                       int K, int N) {
    int idx = blockIdx.x * 256 + threadIdx.x;
    if (idx >= K * N) return;
    int k = idx / N, n = idx - k * N;
    dst[(size_t)n * K + kpos(k)] = f2f8(src[idx]);
}

// ---------------- bias table: [cls 4][h 12][row 64][col 64] fp32 ----------------
__global__ void btab_build(const int* __restrict__ rel_idx, const float* __restrict__ rpb,
                           float* __restrict__ tab) {
    int idx = blockIdx.x * 256 + threadIdx.x;
    if (idx >= 4 * 12 * 64 * 64) return;
    int col = idx & 63, row = (idx >> 6) & 63;
    int h = (idx >> 12) % 12, cls = idx / (12 * 4096);
    float v;
    if (row >= 49 || col >= 49) {
        v = -10000.f;
    } else {
        v = rpb[rel_idx[row * 49 + col] * 12 + h];
        int ti = row / 7, tj = row - (row / 7) * 7;
        int si = col / 7, sj = col - (col / 7) * 7;
        int lq = ((cls & 2) ? (ti < 4 ? 1 : 2) : 0) * 3 + ((cls & 1) ? (tj < 4 ? 1 : 2) : 0);
        int lk = ((cls & 2) ? (si < 4 ? 1 : 2) : 0) * 3 + ((cls & 1) ? (sj < 4 ? 1 : 2) : 0);
        if (lq != lk) v -= 100.f;
    }
    tab[idx] = v;
}

// ---------------- LayerNorm (+optional gather), fp32 -> fp8 (k-interleaved) ----------------
template <int REMAP>
__global__ __launch_bounds__(256) void ln_kernel(const float* __restrict__ x,
                                                 const float* __restrict__ g,
                                                 const float* __restrict__ b,
                                                 unsigned char* __restrict__ out,
                                                 int rows) {
    int r = blockIdx.x * 4 + (threadIdx.x >> 6);
    int lane = threadIdx.x & 63;
    if (r >= rows) return;
    size_t src = REMAP ? win_to_tok(r) : (size_t)r;
    const float* xp = x + src * 384;
    float v[6];
    float s = 0.f;
#pragma unroll
    for (int i = 0; i < 6; ++i) { v[i] = xp[i * 64 + lane]; s += v[i]; }
#pragma unroll
    for (int off = 32; off; off >>= 1) s += __shfl_xor(s, off, 64);
    float mu = s * (1.f / 384.f);
    float q = 0.f;
#pragma unroll
    for (int i = 0; i < 6; ++i) { float d = v[i] - mu; q += d * d; }
#pragma unroll
    for (int off = 32; off; off >>= 1) q += __shfl_xor(q, off, 64);
    float inv = rsqrtf(q * (1.f / 384.f) + 1e-5f);
    unsigned char* op = out + (size_t)r * 384;
#pragma unroll
    for (int i = 0; i < 6; ++i) {
        int c = i * 64 + lane;
        op[kpos(c)] = f2f8((v[i] - mu) * inv * g[c] + b[c]);
    }
}

// ---------------- full-K fp8 GEMM (K=384): 64x128 tile, whole K staged, ZERO intra-loop syncs ----
// A 64x384 (24 KB) + B 128x384 (48 KB) in LDS; 18 gload_lds -> one vmcnt(0)+barrier ->
// barrier-free K-loop (6 K-blocks x 16 MFMA/wave). 4 waves, each owns 32 output cols.
// MODE 0: out fp8 PLAIN (QKV) | 1: resid+C+bias via tokmap, fp32 (proj) | 2: fp8 k-int gelu (FFN1)
template <int MODE>
__global__ __launch_bounds__(256, 2) void gemm_f8_fullk(const unsigned char* __restrict__ A,
                                                        const unsigned char* __restrict__ Bt,
                                                        int M, int N, int K,
                                                        const float* __restrict__ bias,
                                                        const float* __restrict__ resid,
                                                        const int* __restrict__ tokmap,
                                                        unsigned char* __restrict__ outb8,
                                                        float* __restrict__ outf) {
    __shared__ unsigned char Als[64 * 384];    // 24 KB: [kb 0..5][row 0..63][64B]
    __shared__ unsigned char Bls[128 * 384];   // 48 KB: [kb 0..5][row 0..127][64B]
    const int tid = threadIdx.x;
    const int wid = tid >> 6, lane = tid & 63;
    const int ntile = N >> 7;

    int bid = blockIdx.x;
    int nwg = gridDim.x;
    int swb = ((nwg & 7) == 0) ? ((bid & 7) * (nwg >> 3) + (bid >> 3)) : bid;
    const int mt = swb / ntile, nt = swb - mt * ntile;

    const unsigned char* Abase = A  + (size_t)(mt * 64) * K;
    const unsigned char* Bbase = Bt + (size_t)(nt * 128) * K;

    // one-shot staging: 6 A-issues + 12 B-issues per thread, pre-swizzled 16B chunks
    {
        int rA = tid >> 2;
        int gpA = (tid & 3) ^ ((rA >> 1) & 3);
#pragma unroll
        for (int kb = 0; kb < 6; ++kb)
            gload_lds16(Abase + (size_t)rA * K + kb * 64 + gpA * 16, &Als[kb * 4096 + tid * 16]);
#pragma unroll
        for (int kb = 0; kb < 6; ++kb)
#pragma unroll
            for (int j = 0; j < 2; ++j) {
                int r = j * 64 + (tid >> 2);
                int gp = (tid & 3) ^ ((r >> 1) & 3);
                gload_lds16(Bbase + (size_t)r * K + kb * 64 + gp * 16,
                            &Bls[kb * 8192 + j * 4096 + tid * 16]);
            }
    }
    asm volatile("s_waitcnt vmcnt(0)" ::: "memory");
    __builtin_amdgcn_s_barrier();

    const int fr = lane & 15, kq = lane >> 4;
    const int cb = (kq ^ ((fr >> 1) & 3)) << 4;

    f32x4 acc[4][2] = {};
#pragma unroll
    for (int kb = 0; kb < 6; ++kb) {
        longx2 a[4], b[2];
#pragma unroll
        for (int m = 0; m < 4; ++m)
            a[m] = *(const longx2*)(&Als[kb * 4096 + (m * 16 + fr) * 64 + cb]);
#pragma unroll
        for (int n = 0; n < 2; ++n)
            b[n] = *(const longx2*)(&Bls[kb * 8192 + (wid * 32 + n * 16 + fr) * 64 + cb]);
#pragma unroll
        for (int ks = 0; ks < 2; ++ks)
#pragma unroll
            for (int m = 0; m < 4; ++m)
#pragma unroll
                for (int n = 0; n < 2; ++n)
                    acc[m][n] = __builtin_amdgcn_mfma_f32_16x16x32_fp8_fp8(b[n][ks], a[m][ks], acc[m][n], 0, 0, 0);
    }

    const int row0 = mt * 64;
    const int col0 = nt * 128 + wid * 32;
    const int rl = lane & 15;
    const int cq = (lane >> 4) << 2;
#pragma unroll
    for (int m = 0; m < 4; ++m) {
        int row = row0 + m * 16 + rl;
        size_t tok = 0;
        if constexpr (MODE == 1) tok = (size_t)tokmap[row];
#pragma unroll
        for (int n = 0; n < 2; ++n) {
            int col = col0 + n * 16 + cq;
            f32x4 v = acc[m][n];
            if constexpr (MODE == 0) {
                int pk = 0;
                pk = __builtin_amdgcn_cvt_pk_fp8_f32(v[0], v[1], pk, false);
                pk = __builtin_amdgcn_cvt_pk_fp8_f32(v[2], v[3], pk, true);
                *(int*)(outb8 + (size_t)row * N + col) = pk;
            } else if constexpr (MODE == 1) {
                size_t o = tok * 384 + col;
                f32x4 rv = *(const f32x4*)&resid[o];
                f32x4 bb = *(const f32x4*)&bias[col];
                f32x4 ov = rv + v + bb;
                *(f32x4*)&outf[o] = ov;
            } else {
                f32x4 bb = *(const f32x4*)&bias[col];
                float g4[4];
#pragma unroll
                for (int r = 0; r < 4; ++r) {
                    float t2 = v[r] + bb[r];
                    float e  = __expf(-1.702f * t2);
                    g4[r] = t2 * __builtin_amdgcn_rcpf(1.f + e);
                }
                int pk = 0;
                pk = __builtin_amdgcn_cvt_pk_fp8_f32(g4[0], g4[1], pk, false);
                pk = __builtin_amdgcn_cvt_pk_fp8_f32(g4[2], g4[3], pk, true);
                *(int*)(outb8 + (size_t)row * N + kpos(col)) = pk;
            }
        }
    }
}

// ---------------- fp8 ring GEMM (FFN2, K=1536): single-barrier ring NBUF=4/DEPTH=2 ----------------
template <int NBUF, int DEPTH, int MINW>
__global__ __launch_bounds__(256, MINW) void gemm_f8_ring(const unsigned char* __restrict__ A,
                                                          const unsigned char* __restrict__ Bt,
                                                          int M, int N, int K,
                                                          const float* __restrict__ bias,
                                                          const float* __restrict__ resid,
                                                          float* __restrict__ outf) {
    static_assert(NBUF >= DEPTH + 2, "ring too small");
    __shared__ unsigned char As[NBUF][128 * 64];
    __shared__ unsigned char Bs[NBUF][128 * 64];
    const int tid = threadIdx.x;
    const int wid = tid >> 6, lane = tid & 63;
    const int ntile = N >> 7;

    int bid = blockIdx.x;
    int nwg = gridDim.x;
    int swb = ((nwg & 7) == 0) ? ((bid & 7) * (nwg >> 3) + (bid >> 3)) : bid;
    const int mt = swb / ntile, nt = swb - mt * ntile;
    const int wr = wid >> 1, wc = wid & 1;

    f32x4 acc[4][4] = {};

    const unsigned char* Abase = A  + (size_t)(mt * 128) * K;
    const unsigned char* Bbase = Bt + (size_t)(nt * 128) * K;

    auto stage = [&](int buf, int k0) {
#pragma unroll
        for (int j = 0; j < 2; ++j) {
            int r  = j * 64 + (tid >> 2);
            int gp = (tid & 3) ^ ((r >> 1) & 3);
            gload_lds16(Abase + (size_t)r * K + k0 + gp * 16, &As[buf][j * 4096 + tid * 16]);
            gload_lds16(Bbase + (size_t)r * K + k0 + gp * 16, &Bs[buf][j * 4096 + tid * 16]);
        }
    };

    const int fr = lane & 15, kq = lane >> 4;
    const int rowA = wr * 64 + fr;
    const int rowB = wc * 64 + fr;
    const int cb = (kq ^ ((fr >> 1) & 3)) << 4;

    const int nk = K >> 6;
    stage(0, 0);
    if (nk > 1) stage(1, 64);

    for (int t = 0; t < nk; ++t) {
        const int cur = t % NBUF;
        if (t + DEPTH < nk) {
            stage((t + DEPTH) % NBUF, (t + DEPTH) << 6);
            asm volatile("s_waitcnt vmcnt(8)" ::: "memory");
        } else if (t + 1 < nk) {
            asm volatile("s_waitcnt vmcnt(4)" ::: "memory");
        } else {
            asm volatile("s_waitcnt vmcnt(0)" ::: "memory");
        }
        __builtin_amdgcn_s_barrier();

        longx2 a[4], b[4];
#pragma unroll
        for (int m = 0; m < 4; ++m)
            a[m] = *(const longx2*)(&As[cur][(rowA + m * 16) * 64 + cb]);
#pragma unroll
        for (int n = 0; n < 4; ++n)
            b[n] = *(const longx2*)(&Bs[cur][(rowB + n * 16) * 64 + cb]);
#pragma unroll
        for (int ks = 0; ks < 2; ++ks)
#pragma unroll
            for (int m = 0; m < 4; ++m)
#pragma unroll
                for (int n = 0; n < 4; ++n)
                    acc[m][n] = __builtin_amdgcn_mfma_f32_16x16x32_fp8_fp8(b[n][ks], a[m][ks], acc[m][n], 0, 0, 0);

        asm volatile("s_waitcnt lgkmcnt(0)" ::: "memory");
    }

    const int row0 = mt * 128 + wr * 64;
    const int col0 = nt * 128 + wc * 64;
    const int rl = lane & 15;
    const int cq = (lane >> 4) << 2;
#pragma unroll
    for (int m = 0; m < 4; ++m) {
        int row = row0 + m * 16 + rl;
#pragma unroll
        for (int n = 0; n < 4; ++n) {
            int col = col0 + n * 16 + cq;
            f32x4 v = acc[m][n];
            size_t o = (size_t)row * N + col;
            f32x4 rv = *(const f32x4*)&resid[o];
            f32x4 bb = *(const f32x4*)&bias[col];
            f32x4 ov = rv + v + bb;
            *(f32x4*)&outf[o] = ov;
        }
    }
}

// ---------------- MFMA attention: fp8 QK^T, bf16 PV; O out fp8 k-interleaved ----------------
__global__ __launch_bounds__(256, 2) void attn_kernel(const unsigned char* __restrict__ QKV8,
                                                      const float* __restrict__ Btab,
                                                      unsigned char* __restrict__ O8) {
    __shared__ char lds[8192 + 16384 + 32768];   // Kl 8K | Vl 16K | Pl 32K = 56 KB
    char* Kl = lds;
    char* Vl = lds + 8192;
    char* Pl = lds + 24576;

    const int w   = blockIdx.x;
    const int tid = threadIdx.x, wid = tid >> 6, lane = tid & 63;
    const int fr  = lane & 15, kq = lane >> 4;
    const size_t base = (size_t)w * 49 * 1152;
    const int widx = w & 63, wi = widx >> 3, wj = widx & 7;
    const int cls = ((wi == 7) ? 2 : 0) | ((wj == 7) ? 1 : 0);
    const float* tb = Btab + (size_t)cls * 12 * 4096;
    constexpr float SCL = 0.17677669529663687f;

    for (int R = 0; R < 3; ++R) {
        if (R) __syncthreads();
        {
            f32x4 z = {};
#pragma unroll
            for (int j = 0; j < 6; ++j) *(f32x4*)(lds + j * 4096 + tid * 16) = z;
        }
        __syncthreads();
        {
            int hh = tid >> 6, h = R * 4 + hh;
#pragma unroll
            for (int it = 0; it < 4; ++it) {
                int i = (tid & 63) + it * 64;
                if (i < 196) {
                    int m = i >> 2, c = i & 3;
                    long k8 = *(const long*)(QKV8 + base + (size_t)m * 1152 + 384 + h * 32 + c * 8);
                    int s = c ^ (m & 3) ^ ((m >> 2) & 3);
                    *(long*)(Kl + hh * 2048 + m * 32 + s * 8) = k8;
                    long v8 = *(const long*)(QKV8 + base + (size_t)m * 1152 + 768 + h * 32 + c * 8);
                    int lo = (int)v8, hi = (int)(v8 >> 32);
                    float vf[8];
                    vf[0] = __builtin_amdgcn_cvt_f32_fp8(lo, 0);
                    vf[1] = __builtin_amdgcn_cvt_f32_fp8(lo, 1);
                    vf[2] = __builtin_amdgcn_cvt_f32_fp8(lo, 2);
                    vf[3] = __builtin_amdgcn_cvt_f32_fp8(lo, 3);
                    vf[4] = __builtin_amdgcn_cvt_f32_fp8(hi, 0);
                    vf[5] = __builtin_amdgcn_cvt_f32_fp8(hi, 1);
                    vf[6] = __builtin_amdgcn_cvt_f32_fp8(hi, 2);
                    vf[7] = __builtin_amdgcn_cvt_f32_fp8(hi, 3);
#pragma unroll
                    for (int j = 0; j < 8; ++j) {
                        int d = c * 8 + j;
                        *(unsigned short*)(Vl + hh * 4096 + d * 128 +
                                           (((m >> 3) ^ (d & 7)) * 16) + (m & 7) * 2) = f2b(vf[j]);
                    }
                }
            }
        }
        __syncthreads();

        const int h = R * 4 + wid;
        const float* tbh = tb + h * 4096;

        long aq[4], bk[4];
#pragma unroll
        for (int mi = 0; mi < 4; ++mi) {
            int row = mi * 16 + fr; if (row > 48) row = 48;
            aq[mi] = *(const long*)(QKV8 + base + (size_t)row * 1152 + h * 32 + kq * 8);
        }
#pragma unroll
        for (int ni = 0; ni < 4; ++ni) {
            int rk = ni * 16 + fr;
            bk[ni] = *(const long*)(Kl + wid * 2048 + rk * 32 +
                                    ((kq ^ (rk & 3) ^ ((rk >> 2) & 3)) * 8));
        }
        f32x4 s[4][4] = {};
#pragma unroll
        for (int mi = 0; mi < 4; ++mi)
#pragma unroll
            for (int ni = 0; ni < 4; ++ni)
                s[mi][ni] = __builtin_amdgcn_mfma_f32_16x16x32_fp8_fp8(bk[ni], aq[mi], s[mi][ni], 0, 0, 0);

        float linv_[4];
#pragma unroll
        for (int mi = 0; mi < 4; ++mi) {
            int row = mi * 16 + fr;
            const float* tr = tbh + row * 64 + kq * 4;
            f32x4 sv[4];
            float mx = -1e30f;
#pragma unroll
            for (int ni = 0; ni < 4; ++ni) {
                f32x4 bb = *(const f32x4*)&tr[ni * 16];
                sv[ni] = s[mi][ni] * SCL + bb;
                mx = fmaxf(mx, fmaxf(fmaxf(sv[ni][0], sv[ni][1]), fmaxf(sv[ni][2], sv[ni][3])));
            }
            mx = fmaxf(mx, __shfl_xor(mx, 16, 64));
            mx = fmaxf(mx, __shfl_xor(mx, 32, 64));
            float sm = 0.f;
#pragma unroll
            for (int ni = 0; ni < 4; ++ni)
#pragma unroll
                for (int r = 0; r < 4; ++r) { sv[ni][r] = __expf(sv[ni][r] - mx); sm += sv[ni][r]; }
            sm += __shfl_xor(sm, 16, 64);
            sm += __shfl_xor(sm, 32, 64);
            linv_[mi] = __builtin_amdgcn_rcpf(sm);
#pragma unroll
            for (int ni = 0; ni < 4; ++ni) {
                int colb = ni * 16 + kq * 4;
                int phys = (colb >> 3) ^ (row & 7);
                u16x4 pk;
#pragma unroll
                for (int r = 0; r < 4; ++r) pk[r] = f2b(sv[ni][r]);
                *(u16x4*)(Pl + wid * 8192 + row * 128 + phys * 16 + (colb & 7) * 2) = pk;
            }
        }
        asm volatile("s_waitcnt lgkmcnt(0)" ::: "memory");
        __builtin_amdgcn_sched_barrier(0);

        f32x4 oacc[4][2] = {};
#pragma unroll
        for (int sl = 0; sl < 2; ++sl) {
            bf16x8 bv[2];
#pragma unroll
            for (int ni = 0; ni < 2; ++ni) {
                int d = ni * 16 + fr;
                bv[ni] = *(const bf16x8*)(Vl + wid * 4096 + d * 128 + (((sl * 4 + kq) ^ (d & 7)) * 16));
            }
#pragma unroll
            for (int mi = 0; mi < 4; ++mi) {
                int row = mi * 16 + fr;
                bf16x8 ap = *(const bf16x8*)(Pl + wid * 8192 + row * 128 + (((sl * 4 + kq) ^ (row & 7)) * 16));
#pragma unroll
                for (int ni = 0; ni < 2; ++ni)
                    oacc[mi][ni] = __builtin_amdgcn_mfma_f32_16x16x32_bf16(bv[ni], ap, oacc[mi][ni], 0, 0, 0);
            }
        }

#pragma unroll
        for (int mi = 0; mi < 4; ++mi) {
            int row = mi * 16 + fr;
            if (row < 49) {
                float li = linv_[mi];
                unsigned char* opb = O8 + (size_t)(w * 49 + row) * 384;
#pragma unroll
                for (int ni = 0; ni < 2; ++ni) {
                    int c = h * 32 + ni * 16 + kq * 4;
                    int pk = 0;
                    pk = __builtin_amdgcn_cvt_pk_fp8_f32(oacc[mi][ni][0] * li, oacc[mi][ni][1] * li, pk, false);
                    pk = __builtin_amdgcn_cvt_pk_fp8_f32(oacc[mi][ni][2] * li, oacc[mi][ni][3] * li, pk, true);
                    *(int*)(opb + kpos(c)) = pk;
                }
            }
        }
    }
}

extern "C" void kernel_launch(void* const* d_in, const int* in_sizes, int n_in,
                              void* d_out, int out_size, void* d_ws, size_t ws_size,
                              hipStream_t stream) {
    const float* x     = (const float*)d_in[0];
    const int*   rel   = (const int*)  d_in[3];
    const float* rpb   = (const float*)d_in[4];
    const float* qkvw  = (const float*)d_in[5];
    const float* projw = (const float*)d_in[6];
    const float* projb = (const float*)d_in[7];
    const float* n1g   = (const float*)d_in[8];
    const float* n1b   = (const float*)d_in[9];
    const float* n2g   = (const float*)d_in[10];
    const float* n2b   = (const float*)d_in[11];
    const float* w1    = (const float*)d_in[12];
    const float* b1    = (const float*)d_in[13];
    const float* w2    = (const float*)d_in[14];
    const float* b2    = (const float*)d_in[15];
    float* out = (float*)d_out;

    const int T = in_sizes[0] / 384;   // 100352

    char* ws = (char*)d_ws;
    size_t off = 0;
    auto alloc = [&](size_t bytes) {
        char* p = ws + off;
        off += (bytes + 255) & ~(size_t)255;
        return p;
    };
    unsigned char* Wq8  = (unsigned char*)alloc((size_t)1152 * 384);
    unsigned char* Wp8  = (unsigned char*)alloc((size_t)384 * 384);
    unsigned char* W18  = (unsigned char*)alloc((size_t)1536 * 384);
    unsigned char* W28  = (unsigned char*)alloc((size_t)384 * 1536);
    float*         Btab = (float*)       alloc((size_t)4 * 12 * 4096 * 4);
    int*           Tmap = (int*)         alloc((size_t)T * 4);
    unsigned char* slotA = (unsigned char*)alloc((size_t)T * 384);    // X1_8 -> O8 -> X2_8
    unsigned char* slotB = (unsigned char*)alloc((size_t)T * 1536);   // QKV8 -> F8

    unsigned char* X1   = slotA;
    unsigned char* O8   = slotA;
    unsigned char* X2   = slotA;
    unsigned char* QKV8 = slotB;
    unsigned char* F8   = slotB;
    float*         Hh   = out;

    wprep8<<<dim3((1152 * 384 + 255) / 256), 256, 0, stream>>>(qkvw, Wq8, 384, 1152);
    wprep8<<<dim3((384 * 384 + 255) / 256),  256, 0, stream>>>(projw, Wp8, 384, 384);
    wprep8<<<dim3((384 * 1536 + 255) / 256), 256, 0, stream>>>(w1, W18, 384, 1536);
    wprep8<<<dim3((1536 * 384 + 255) / 256), 256, 0, stream>>>(w2, W28, 1536, 384);
    btab_build<<<dim3((4 * 12 * 4096 + 255) / 256), 256, 0, stream>>>(rel, rpb, Btab);
    tokmap_build<<<dim3((T + 255) / 256), 256, 0, stream>>>(Tmap, T);

    // LN1 + shifted-window gather -> X1 (fp8 k-interleaved)
    ln_kernel<1><<<dim3(T / 4), 256, 0, stream>>>(x, n1g, n1b, X1, T);
    // QKV projection -> QKV8 (fp8 PLAIN; full-K single-stage)
    gemm_f8_fullk<0><<<dim3((T / 64) * (1152 / 128)), 256, 0, stream>>>(
        X1, Wq8, T, 1152, 384, nullptr, nullptr, nullptr, QKV8, nullptr);
    // MFMA windowed attention (fp8 QK^T, bf16 PV) -> O8 (fp8 k-interleaved)
    attn_kernel<<<dim3(T / 49), 256, 0, stream>>>(QKV8, Btab, O8);
    // proj + bias + tokmap remap + residual -> Hh (= d_out, fp32; full-K single-stage)
    gemm_f8_fullk<1><<<dim3((T / 64) * (384 / 128)), 256, 0, stream>>>(
        O8, Wp8, T, 384, 384, projb, x, Tmap, nullptr, Hh);
    // LN2 -> X2 (fp8 k-interleaved)
    ln_kernel<0><<<dim3(T / 4), 256, 0, stream>>>(Hh, n2g, n2b, X2, T);
    // FFN1 + bias + sigmoid-GELU -> F8 (fp8 k-interleaved; full-K single-stage)
    gemm_f8_fullk<2><<<dim3((T / 64) * (1536 / 128)), 256, 0, stream>>>(
        X2, W18, T, 1536, 384, b1, nullptr, nullptr, F8, nullptr);
    // FFN2 + bias + residual -> out (fp32, in-place RMW; single-barrier ring)
    gemm_f8_ring<4, 2, 2><<<dim3((T / 128) * (384 / 128)), 256, 0, stream>>>(
        F8, W28, T, 384, 1536, b2, Hh, out);
}

// Round 21
// 636.117 us; speedup vs baseline: 1.5799x; 1.0319x over previous
//
#include <hip/hip_runtime.h>

#define DEV __device__ __forceinline__

typedef __bf16 bf16x8 __attribute__((ext_vector_type(8)));
typedef float  f32x4  __attribute__((ext_vector_type(4)));
typedef unsigned short u16x8 __attribute__((ext_vector_type(8)));
typedef unsigned short u16x4 __attribute__((ext_vector_type(4)));
typedef long  longx2 __attribute__((ext_vector_type(2)));

DEV float b2f(unsigned short u) {
    unsigned int t = ((unsigned int)u) << 16;
    return __uint_as_float(t);
}
DEV unsigned short f2b(float f) {
    unsigned int u = __float_as_uint(f);
    unsigned int r = (u + 0x7FFFu + ((u >> 16) & 1u)) >> 16;
    return (unsigned short)r;
}
DEV unsigned char f2f8(float f) {
    return (unsigned char)(__builtin_amdgcn_cvt_pk_fp8_f32(f, f, 0, false) & 0xff);
}

// k-interleaved fp8 file layout (for BK=64 GEMM inputs): within each 64B K-block,
// slot order {0,4,1,5,2,6,3,7} -> file 16B chunk c holds k-slots {c, c+4}.
DEV int kpos(int c) {
    int s = (c >> 3) & 7;
    return (c & ~63) | ((((s & 3) << 1) | (s >> 2)) << 3) | (c & 7);
}

DEV void gload_lds16(const void* g, void* l) {
    __builtin_amdgcn_global_load_lds(
        (const __attribute__((address_space(1))) void*)g,
        (__attribute__((address_space(3))) void*)l, 16, 0, 0);
}

// dest window-row -> source/dest token index (roll by SS=3, window 7x7, 56x56, 64 win/batch)
DEV size_t win_to_tok(int row) {
    int w = row / 49, t = row - w * 49;
    int b  = w >> 6, widx = w & 63;
    int wi = widx >> 3, wj = widx & 7;
    int ti = t / 7, tj = t - ti * 7;
    int hh = wi * 7 + ti + 3; if (hh >= 56) hh -= 56;
    int ww = wj * 7 + tj + 3; if (ww >= 56) ww -= 56;
    return (size_t)b * 3136 + (size_t)hh * 56 + ww;
}

// ---------------- row -> token map (for proj epilogue) ----------------
__global__ void tokmap_build(int* __restrict__ tm, int T) {
    int i = blockIdx.x * 256 + threadIdx.x;
    if (i < T) tm[i] = (int)win_to_tok(i);
}

// ---------------- weight prep: fp32 [K][N] -> fp8 e4m3 [N][K] (k-interleaved) ----------------
__global__ void wprep8(const float* __restrict__ src, unsigned char* __restrict__ dst,
                       int K, int N) {
    int idx = blockIdx.x * 256 + threadIdx.x;
    if (idx >= K * N) return;
    int k = idx / N, n = idx - k * N;
    dst[(size_t)n * K + kpos(k)] = f2f8(src[idx]);
}

// ---------------- bias table: [cls 4][h 12][row 64][col 64] fp32 ----------------
__global__ void btab_build(const int* __restrict__ rel_idx, const float* __restrict__ rpb,
                           float* __restrict__ tab) {
    int idx = blockIdx.x * 256 + threadIdx.x;
    if (idx >= 4 * 12 * 64 * 64) return;
    int col = idx & 63, row = (idx >> 6) & 63;
    int h = (idx >> 12) % 12, cls = idx / (12 * 4096);
    float v;
    if (row >= 49 || col >= 49) {
        v = -10000.f;
    } else {
        v = rpb[rel_idx[row * 49 + col] * 12 + h];
        int ti = row / 7, tj = row - (row / 7) * 7;
        int si = col / 7, sj = col - (col / 7) * 7;
        int lq = ((cls & 2) ? (ti < 4 ? 1 : 2) : 0) * 3 + ((cls & 1) ? (tj < 4 ? 1 : 2) : 0);
        int lk = ((cls & 2) ? (si < 4 ? 1 : 2) : 0) * 3 + ((cls & 1) ? (sj < 4 ? 1 : 2) : 0);
        if (lq != lk) v -= 100.f;
    }
    tab[idx] = v;
}

// ---------------- LayerNorm (+optional gather), fp32 -> fp8 (k-interleaved) ----------------
template <int REMAP>
__global__ __launch_bounds__(256) void ln_kernel(const float* __restrict__ x,
                                                 const float* __restrict__ g,
                                                 const float* __restrict__ b,
                                                 unsigned char* __restrict__ out,
                                                 int rows) {
    int r = blockIdx.x * 4 + (threadIdx.x >> 6);
    int lane = threadIdx.x & 63;
    if (r >= rows) return;
    size_t src = REMAP ? win_to_tok(r) : (size_t)r;
    const float* xp = x + src * 384;
    float v[6];
    float s = 0.f;
#pragma unroll
    for (int i = 0; i < 6; ++i) { v[i] = xp[i * 64 + lane]; s += v[i]; }
#pragma unroll
    for (int off = 32; off; off >>= 1) s += __shfl_xor(s, off, 64);
    float mu = s * (1.f / 384.f);
    float q = 0.f;
#pragma unroll
    for (int i = 0; i < 6; ++i) { float d = v[i] - mu; q += d * d; }
#pragma unroll
    for (int off = 32; off; off >>= 1) q += __shfl_xor(q, off, 64);
    float inv = rsqrtf(q * (1.f / 384.f) + 1e-5f);
    unsigned char* op = out + (size_t)r * 384;
#pragma unroll
    for (int i = 0; i < 6; ++i) {
        int c = i * 64 + lane;
        op[kpos(c)] = f2f8((v[i] - mu) * inv * g[c] + b[c]);
    }
}

// ---------------- full-K fp8 GEMM (K=384): 64x128 tile, 8 waves, ZERO intra-loop syncs ----------
// A 64x384 (24 KB) + B 128x384 (48 KB) in LDS; one vmcnt(0)+barrier; each of 8 waves owns
// 16 output cols (acc 4x1). 2 blocks/CU x 8 waves = 4 waves/SIMD -> MFMA||VALU cross-wave overlap.
// MODE 0: out fp8 PLAIN (QKV) | 1: resid+C+bias via tokmap, fp32 (proj) | 2: fp8 k-int gelu (FFN1)
template <int MODE>
__global__ __launch_bounds__(512, 2) void gemm_f8_fullk(const unsigned char* __restrict__ A,
                                                        const unsigned char* __restrict__ Bt,
                                                        int M, int N, int K,
                                                        const float* __restrict__ bias,
                                                        const float* __restrict__ resid,
                                                        const int* __restrict__ tokmap,
                                                        unsigned char* __restrict__ outb8,
                                                        float* __restrict__ outf) {
    __shared__ unsigned char Als[64 * 384];    // 24 KB: [kb 0..5][row 0..63][64B]
    __shared__ unsigned char Bls[128 * 384];   // 48 KB: [kb 0..5][row 0..127][64B]
    const int tid = threadIdx.x;               // 0..511
    const int wid = tid >> 6, lane = tid & 63;
    const int ntile = N >> 7;

    int bid = blockIdx.x;
    int nwg = gridDim.x;
    int swb = ((nwg & 7) == 0) ? ((bid & 7) * (nwg >> 3) + (bid >> 3)) : bid;
    const int mt = swb / ntile, nt = swb - mt * ntile;

    const unsigned char* Abase = A  + (size_t)(mt * 64) * K;
    const unsigned char* Bbase = Bt + (size_t)(nt * 128) * K;

    // one-shot staging: B = 1 chunk/thread/kb (512 chunks = 8 KB); A = threads<256, 1 chunk/kb
    {
        int rB = tid >> 2;
        int gpB = (tid & 3) ^ ((rB >> 1) & 3);
#pragma unroll
        for (int kb = 0; kb < 6; ++kb)
            gload_lds16(Bbase + (size_t)rB * K + kb * 64 + gpB * 16, &Bls[kb * 8192 + tid * 16]);
        if (tid < 256) {
            int rA = tid >> 2;
            int gpA = (tid & 3) ^ ((rA >> 1) & 3);
#pragma unroll
            for (int kb = 0; kb < 6; ++kb)
                gload_lds16(Abase + (size_t)rA * K + kb * 64 + gpA * 16, &Als[kb * 4096 + tid * 16]);
        }
    }
    asm volatile("s_waitcnt vmcnt(0)" ::: "memory");
    __builtin_amdgcn_s_barrier();

    const int fr = lane & 15, kq = lane >> 4;
    const int cb = (kq ^ ((fr >> 1) & 3)) << 4;

    f32x4 acc[4] = {};
#pragma unroll
    for (int kb = 0; kb < 6; ++kb) {
        longx2 a[4], b;
        b = *(const longx2*)(&Bls[kb * 8192 + (wid * 16 + fr) * 64 + cb]);
#pragma unroll
        for (int m = 0; m < 4; ++m)
            a[m] = *(const longx2*)(&Als[kb * 4096 + (m * 16 + fr) * 64 + cb]);
#pragma unroll
        for (int ks = 0; ks < 2; ++ks)
#pragma unroll
            for (int m = 0; m < 4; ++m)
                acc[m] = __builtin_amdgcn_mfma_f32_16x16x32_fp8_fp8(b[ks], a[m][ks], acc[m], 0, 0, 0);
    }

    const int row0 = mt * 64;
    const int col0 = nt * 128 + wid * 16;
    const int rl = lane & 15;
    const int cq = (lane >> 4) << 2;
    const int col = col0 + cq;
#pragma unroll
    for (int m = 0; m < 4; ++m) {
        int row = row0 + m * 16 + rl;
        f32x4 v = acc[m];
        if constexpr (MODE == 0) {
            int pk = 0;
            pk = __builtin_amdgcn_cvt_pk_fp8_f32(v[0], v[1], pk, false);
            pk = __builtin_amdgcn_cvt_pk_fp8_f32(v[2], v[3], pk, true);
            *(int*)(outb8 + (size_t)row * N + col) = pk;
        } else if constexpr (MODE == 1) {
            size_t o = (size_t)tokmap[row] * 384 + col;
            f32x4 rv = *(const f32x4*)&resid[o];
            f32x4 bb = *(const f32x4*)&bias[col];
            f32x4 ov = rv + v + bb;
            *(f32x4*)&outf[o] = ov;
        } else {
            f32x4 bb = *(const f32x4*)&bias[col];
            float g4[4];
#pragma unroll
            for (int r = 0; r < 4; ++r) {
                float t2 = v[r] + bb[r];
                float e  = __expf(-1.702f * t2);
                g4[r] = t2 * __builtin_amdgcn_rcpf(1.f + e);
            }
            int pk = 0;
            pk = __builtin_amdgcn_cvt_pk_fp8_f32(g4[0], g4[1], pk, false);
            pk = __builtin_amdgcn_cvt_pk_fp8_f32(g4[2], g4[3], pk, true);
            *(int*)(outb8 + (size_t)row * N + kpos(col)) = pk;
        }
    }
}

// ---------------- fp8 ring GEMM (FFN2, K=1536): single-barrier ring NBUF=4/DEPTH=2 ----------------
template <int NBUF, int DEPTH, int MINW>
__global__ __launch_bounds__(256, MINW) void gemm_f8_ring(const unsigned char* __restrict__ A,
                                                          const unsigned char* __restrict__ Bt,
                                                          int M, int N, int K,
                                                          const float* __restrict__ bias,
                                                          const float* __restrict__ resid,
                                                          float* __restrict__ outf) {
    static_assert(NBUF >= DEPTH + 2, "ring too small");
    __shared__ unsigned char As[NBUF][128 * 64];
    __shared__ unsigned char Bs[NBUF][128 * 64];
    const int tid = threadIdx.x;
    const int wid = tid >> 6, lane = tid & 63;
    const int ntile = N >> 7;

    int bid = blockIdx.x;
    int nwg = gridDim.x;
    int swb = ((nwg & 7) == 0) ? ((bid & 7) * (nwg >> 3) + (bid >> 3)) : bid;
    const int mt = swb / ntile, nt = swb - mt * ntile;
    const int wr = wid >> 1, wc = wid & 1;

    f32x4 acc[4][4] = {};

    const unsigned char* Abase = A  + (size_t)(mt * 128) * K;
    const unsigned char* Bbase = Bt + (size_t)(nt * 128) * K;

    auto stage = [&](int buf, int k0) {
#pragma unroll
        for (int j = 0; j < 2; ++j) {
            int r  = j * 64 + (tid >> 2);
            int gp = (tid & 3) ^ ((r >> 1) & 3);
            gload_lds16(Abase + (size_t)r * K + k0 + gp * 16, &As[buf][j * 4096 + tid * 16]);
            gload_lds16(Bbase + (size_t)r * K + k0 + gp * 16, &Bs[buf][j * 4096 + tid * 16]);
        }
    };

    const int fr = lane & 15, kq = lane >> 4;
    const int rowA = wr * 64 + fr;
    const int rowB = wc * 64 + fr;
    const int cb = (kq ^ ((fr >> 1) & 3)) << 4;

    const int nk = K >> 6;
    stage(0, 0);
    if (nk > 1) stage(1, 64);

    for (int t = 0; t < nk; ++t) {
        const int cur = t % NBUF;
        if (t + DEPTH < nk) {
            stage((t + DEPTH) % NBUF, (t + DEPTH) << 6);
            asm volatile("s_waitcnt vmcnt(8)" ::: "memory");
        } else if (t + 1 < nk) {
            asm volatile("s_waitcnt vmcnt(4)" ::: "memory");
        } else {
            asm volatile("s_waitcnt vmcnt(0)" ::: "memory");
        }
        __builtin_amdgcn_s_barrier();

        longx2 a[4], b[4];
#pragma unroll
        for (int m = 0; m < 4; ++m)
            a[m] = *(const longx2*)(&As[cur][(rowA + m * 16) * 64 + cb]);
#pragma unroll
        for (int n = 0; n < 4; ++n)
            b[n] = *(const longx2*)(&Bs[cur][(rowB + n * 16) * 64 + cb]);
#pragma unroll
        for (int ks = 0; ks < 2; ++ks)
#pragma unroll
            for (int m = 0; m < 4; ++m)
#pragma unroll
                for (int n = 0; n < 4; ++n)
                    acc[m][n] = __builtin_amdgcn_mfma_f32_16x16x32_fp8_fp8(b[n][ks], a[m][ks], acc[m][n], 0, 0, 0);

        asm volatile("s_waitcnt lgkmcnt(0)" ::: "memory");
    }

    const int row0 = mt * 128 + wr * 64;
    const int col0 = nt * 128 + wc * 64;
    const int rl = lane & 15;
    const int cq = (lane >> 4) << 2;
#pragma unroll
    for (int m = 0; m < 4; ++m) {
        int row = row0 + m * 16 + rl;
#pragma unroll
        for (int n = 0; n < 4; ++n) {
            int col = col0 + n * 16 + cq;
            f32x4 v = acc[m][n];
            size_t o = (size_t)row * N + col;
            f32x4 rv = *(const f32x4*)&resid[o];
            f32x4 bb = *(const f32x4*)&bias[col];
            f32x4 ov = rv + v + bb;
            *(f32x4*)&outf[o] = ov;
        }
    }
}

// ---------------- MFMA attention: fp8 QK^T, bf16 PV; O out fp8 k-interleaved ----------------
__global__ __launch_bounds__(256, 2) void attn_kernel(const unsigned char* __restrict__ QKV8,
                                                      const float* __restrict__ Btab,
                                                      unsigned char* __restrict__ O8) {
    __shared__ char lds[8192 + 16384 + 32768];   // Kl 8K | Vl 16K | Pl 32K = 56 KB
    char* Kl = lds;
    char* Vl = lds + 8192;
    char* Pl = lds + 24576;

    const int w   = blockIdx.x;
    const int tid = threadIdx.x, wid = tid >> 6, lane = tid & 63;
    const int fr  = lane & 15, kq = lane >> 4;
    const size_t base = (size_t)w * 49 * 1152;
    const int widx = w & 63, wi = widx >> 3, wj = widx & 7;
    const int cls = ((wi == 7) ? 2 : 0) | ((wj == 7) ? 1 : 0);
    const float* tb = Btab + (size_t)cls * 12 * 4096;
    constexpr float SCL = 0.17677669529663687f;

    for (int R = 0; R < 3; ++R) {
        if (R) __syncthreads();
        {
            f32x4 z = {};
#pragma unroll
            for (int j = 0; j < 6; ++j) *(f32x4*)(lds + j * 4096 + tid * 16) = z;
        }
        __syncthreads();
        {
            int hh = tid >> 6, h = R * 4 + hh;
#pragma unroll
            for (int it = 0; it < 4; ++it) {
                int i = (tid & 63) + it * 64;
                if (i < 196) {
                    int m = i >> 2, c = i & 3;
                    long k8 = *(const long*)(QKV8 + base + (size_t)m * 1152 + 384 + h * 32 + c * 8);
                    int s = c ^ (m & 3) ^ ((m >> 2) & 3);
                    *(long*)(Kl + hh * 2048 + m * 32 + s * 8) = k8;
                    long v8 = *(const long*)(QKV8 + base + (size_t)m * 1152 + 768 + h * 32 + c * 8);
                    int lo = (int)v8, hi = (int)(v8 >> 32);
                    float vf[8];
                    vf[0] = __builtin_amdgcn_cvt_f32_fp8(lo, 0);
                    vf[1] = __builtin_amdgcn_cvt_f32_fp8(lo, 1);
                    vf[2] = __builtin_amdgcn_cvt_f32_fp8(lo, 2);
                    vf[3] = __builtin_amdgcn_cvt_f32_fp8(lo, 3);
                    vf[4] = __builtin_amdgcn_cvt_f32_fp8(hi, 0);
                    vf[5] = __builtin_amdgcn_cvt_f32_fp8(hi, 1);
                    vf[6] = __builtin_amdgcn_cvt_f32_fp8(hi, 2);
                    vf[7] = __builtin_amdgcn_cvt_f32_fp8(hi, 3);
#pragma unroll
                    for (int j = 0; j < 8; ++j) {
                        int d = c * 8 + j;
                        *(unsigned short*)(Vl + hh * 4096 + d * 128 +
                                           (((m >> 3) ^ (d & 7)) * 16) + (m & 7) * 2) = f2b(vf[j]);
                    }
                }
            }
        }
        __syncthreads();

        const int h = R * 4 + wid;
        const float* tbh = tb + h * 4096;

        long aq[4], bk[4];
#pragma unroll
        for (int mi = 0; mi < 4; ++mi) {
            int row = mi * 16 + fr; if (row > 48) row = 48;
            aq[mi] = *(const long*)(QKV8 + base + (size_t)row * 1152 + h * 32 + kq * 8);
        }
#pragma unroll
        for (int ni = 0; ni < 4; ++ni) {
            int rk = ni * 16 + fr;
            bk[ni] = *(const long*)(Kl + wid * 2048 + rk * 32 +
                                    ((kq ^ (rk & 3) ^ ((rk >> 2) & 3)) * 8));
        }
        f32x4 s[4][4] = {};
#pragma unroll
        for (int mi = 0; mi < 4; ++mi)
#pragma unroll
            for (int ni = 0; ni < 4; ++ni)
                s[mi][ni] = __builtin_amdgcn_mfma_f32_16x16x32_fp8_fp8(bk[ni], aq[mi], s[mi][ni], 0, 0, 0);

        float linv_[4];
#pragma unroll
        for (int mi = 0; mi < 4; ++mi) {
            int row = mi * 16 + fr;
            const float* tr = tbh + row * 64 + kq * 4;
            f32x4 sv[4];
            float mx = -1e30f;
#pragma unroll
            for (int ni = 0; ni < 4; ++ni) {
                f32x4 bb = *(const f32x4*)&tr[ni * 16];
                sv[ni] = s[mi][ni] * SCL + bb;
                mx = fmaxf(mx, fmaxf(fmaxf(sv[ni][0], sv[ni][1]), fmaxf(sv[ni][2], sv[ni][3])));
            }
            mx = fmaxf(mx, __shfl_xor(mx, 16, 64));
            mx = fmaxf(mx, __shfl_xor(mx, 32, 64));
            float sm = 0.f;
#pragma unroll
            for (int ni = 0; ni < 4; ++ni)
#pragma unroll
                for (int r = 0; r < 4; ++r) { sv[ni][r] = __expf(sv[ni][r] - mx); sm += sv[ni][r]; }
            sm += __shfl_xor(sm, 16, 64);
            sm += __shfl_xor(sm, 32, 64);
            linv_[mi] = __builtin_amdgcn_rcpf(sm);
#pragma unroll
            for (int ni = 0; ni < 4; ++ni) {
                int colb = ni * 16 + kq * 4;
                int phys = (colb >> 3) ^ (row & 7);
                u16x4 pk;
#pragma unroll
                for (int r = 0; r < 4; ++r) pk[r] = f2b(sv[ni][r]);
                *(u16x4*)(Pl + wid * 8192 + row * 128 + phys * 16 + (colb & 7) * 2) = pk;
            }
        }
        asm volatile("s_waitcnt lgkmcnt(0)" ::: "memory");
        __builtin_amdgcn_sched_barrier(0);

        f32x4 oacc[4][2] = {};
#pragma unroll
        for (int sl = 0; sl < 2; ++sl) {
            bf16x8 bv[2];
#pragma unroll
            for (int ni = 0; ni < 2; ++ni) {
                int d = ni * 16 + fr;
                bv[ni] = *(const bf16x8*)(Vl + wid * 4096 + d * 128 + (((sl * 4 + kq) ^ (d & 7)) * 16));
            }
#pragma unroll
            for (int mi = 0; mi < 4; ++mi) {
                int row = mi * 16 + fr;
                bf16x8 ap = *(const bf16x8*)(Pl + wid * 8192 + row * 128 + (((sl * 4 + kq) ^ (row & 7)) * 16));
#pragma unroll
                for (int ni = 0; ni < 2; ++ni)
                    oacc[mi][ni] = __builtin_amdgcn_mfma_f32_16x16x32_bf16(bv[ni], ap, oacc[mi][ni], 0, 0, 0);
            }
        }

#pragma unroll
        for (int mi = 0; mi < 4; ++mi) {
            int row = mi * 16 + fr;
            if (row < 49) {
                float li = linv_[mi];
                unsigned char* opb = O8 + (size_t)(w * 49 + row) * 384;
#pragma unroll
                for (int ni = 0; ni < 2; ++ni) {
                    int c = h * 32 + ni * 16 + kq * 4;
                    int pk = 0;
                    pk = __builtin_amdgcn_cvt_pk_fp8_f32(oacc[mi][ni][0] * li, oacc[mi][ni][1] * li, pk, false);
                    pk = __builtin_amdgcn_cvt_pk_fp8_f32(oacc[mi][ni][2] * li, oacc[mi][ni][3] * li, pk, true);
                    *(int*)(opb + kpos(c)) = pk;
                }
            }
        }
    }
}

extern "C" void kernel_launch(void* const* d_in, const int* in_sizes, int n_in,
                              void* d_out, int out_size, void* d_ws, size_t ws_size,
                              hipStream_t stream) {
    const float* x     = (const float*)d_in[0];
    const int*   rel   = (const int*)  d_in[3];
    const float* rpb   = (const float*)d_in[4];
    const float* qkvw  = (const float*)d_in[5];
    const float* projw = (const float*)d_in[6];
    const float* projb = (const float*)d_in[7];
    const float* n1g   = (const float*)d_in[8];
    const float* n1b   = (const float*)d_in[9];
    const float* n2g   = (const float*)d_in[10];
    const float* n2b   = (const float*)d_in[11];
    const float* w1    = (const float*)d_in[12];
    const float* b1    = (const float*)d_in[13];
    const float* w2    = (const float*)d_in[14];
    const float* b2    = (const float*)d_in[15];
    float* out = (float*)d_out;

    const int T = in_sizes[0] / 384;   // 100352

    char* ws = (char*)d_ws;
    size_t off = 0;
    auto alloc = [&](size_t bytes) {
        char* p = ws + off;
        off += (bytes + 255) & ~(size_t)255;
        return p;
    };
    unsigned char* Wq8  = (unsigned char*)alloc((size_t)1152 * 384);
    unsigned char* Wp8  = (unsigned char*)alloc((size_t)384 * 384);
    unsigned char* W18  = (unsigned char*)alloc((size_t)1536 * 384);
    unsigned char* W28  = (unsigned char*)alloc((size_t)384 * 1536);
    float*         Btab = (float*)       alloc((size_t)4 * 12 * 4096 * 4);
    int*           Tmap = (int*)         alloc((size_t)T * 4);
    unsigned char* slotA = (unsigned char*)alloc((size_t)T * 384);    // X1_8 -> O8 -> X2_8
    unsigned char* slotB = (unsigned char*)alloc((size_t)T * 1536);   // QKV8 -> F8

    unsigned char* X1   = slotA;
    unsigned char* O8   = slotA;
    unsigned char* X2   = slotA;
    unsigned char* QKV8 = slotB;
    unsigned char* F8   = slotB;
    float*         Hh   = out;

    wprep8<<<dim3((1152 * 384 + 255) / 256), 256, 0, stream>>>(qkvw, Wq8, 384, 1152);
    wprep8<<<dim3((384 * 384 + 255) / 256),  256, 0, stream>>>(projw, Wp8, 384, 384);
    wprep8<<<dim3((384 * 1536 + 255) / 256), 256, 0, stream>>>(w1, W18, 384, 1536);
    wprep8<<<dim3((1536 * 384 + 255) / 256), 256, 0, stream>>>(w2, W28, 1536, 384);
    btab_build<<<dim3((4 * 12 * 4096 + 255) / 256), 256, 0, stream>>>(rel, rpb, Btab);
    tokmap_build<<<dim3((T + 255) / 256), 256, 0, stream>>>(Tmap, T);

    // LN1 + shifted-window gather -> X1 (fp8 k-interleaved)
    ln_kernel<1><<<dim3(T / 4), 256, 0, stream>>>(x, n1g, n1b, X1, T);
    // QKV projection -> QKV8 (fp8 PLAIN; full-K 8-wave)
    gemm_f8_fullk<0><<<dim3((T / 64) * (1152 / 128)), 512, 0, stream>>>(
        X1, Wq8, T, 1152, 384, nullptr, nullptr, nullptr, QKV8, nullptr);
    // MFMA windowed attention (fp8 QK^T, bf16 PV) -> O8 (fp8 k-interleaved)
    attn_kernel<<<dim3(T / 49), 256, 0, stream>>>(QKV8, Btab, O8);
    // proj + bias + tokmap remap + residual -> Hh (= d_out, fp32; full-K 8-wave)
    gemm_f8_fullk<1><<<dim3((T / 64) * (384 / 128)), 512, 0, stream>>>(
        O8, Wp8, T, 384, 384, projb, x, Tmap, nullptr, Hh);
    // LN2 -> X2 (fp8 k-interleaved)
    ln_kernel<0><<<dim3(T / 4), 256, 0, stream>>>(Hh, n2g, n2b, X2, T);
    // FFN1 + bias + sigmoid-GELU -> F8 (fp8 k-interleaved; full-K 8-wave)
    gemm_f8_fullk<2><<<dim3((T / 64) * (1536 / 128)), 512, 0, stream>>>(
        X2, W18, T, 1536, 384, b1, nullptr, nullptr, F8, nullptr);
    // FFN2 + bias + residual -> out (fp32, in-place RMW; single-barrier ring)
    gemm_f8_ring<4, 2, 2><<<dim3((T / 128) * (384 / 128)), 256, 0, stream>>>(
        F8, W28, T, 384, 1536, b2, Hh, out);
}